// Round 2
// baseline (1473.966 us; speedup 1.0000x reference)
//
#include <hip/hip_runtime.h>
#include <hip/hip_bf16.h>
#include <math.h>

#define Bv 2
#define Nv 2048
#define Cv 128
#define Dv 256
#define PHv 64
#define AHv 1024
#define Kv 16
#define NSAMP (Bv*Nv*Kv)   // 65536

typedef unsigned short ushortt;

__device__ __forceinline__ float bf2f(ushortt h){
  union { unsigned int u; float f; } v; v.u = ((unsigned int)h) << 16; return v.f;
}
__device__ __forceinline__ ushortt f2bf(float f){
  union { unsigned int u; float f; } v; v.f = f;
  unsigned int r = v.u + 0x7FFFu + ((v.u >> 16) & 1u);
  return (ushortt)(r >> 16);
}

// ---------------- weight transposes / casts ----------------
__global__ __launch_bounds__(256) void prep_weights(
    const float* __restrict__ wk, const float* __restrict__ wq,
    const float* __restrict__ wv, const float* __restrict__ endw,
    const float* __restrict__ mw1, const float* __restrict__ mw2,
    const float* __restrict__ mwsc, const float* __restrict__ aw2,
    const float* __restrict__ pw2,
    float* __restrict__ wkT, float* __restrict__ wqT, float* __restrict__ wvT,
    float* __restrict__ endwT, float* __restrict__ mw1T, float* __restrict__ mw2T,
    float* __restrict__ mwscT, ushortt* __restrict__ w2T, ushortt* __restrict__ w2posT)
{
  int tid = blockIdx.x*256 + threadIdx.x;
  int stride = gridDim.x*256;
  for (int i = tid; i < 256*128; i += stride){ int d = i>>7, c = i&127;
    wkT[c*256+d] = wk[i]; wqT[c*256+d] = wq[i]; wvT[c*256+d] = wv[i]; }
  for (int i = tid; i < 128*256; i += stride){ int co = i>>8, d = i&255; endwT[d*128+co] = endw[i]; }
  for (int i = tid; i < 128*256; i += stride){ int h = i>>8, c = i&255; mw1T[c*128+h] = mw1[i]; }
  for (int i = tid; i < 128*128; i += stride){ int o = i>>7, c = i&127; mw2T[c*128+o] = mw2[i]; }
  for (int i = tid; i < 128*256; i += stride){ int o = i>>8, c = i&255; mwscT[c*128+o] = mwsc[i]; }
  for (int i = tid; i < 256*1024; i += stride){ int d = i>>10, ah = i&1023; w2T[ah*256+d] = f2bf(aw2[i]); }
  for (int i = tid; i < 256*64; i += stride){ int d = i>>6, c = i&63; w2posT[c*256+d] = f2bf(pw2[i]); }
}

// ---------------- value = MLP_Res(cat(key,query)) ----------------
__global__ __launch_bounds__(256) void mlpres_kernel(
    const float* __restrict__ key, const float* __restrict__ query,
    const float* __restrict__ mw1T, const float* __restrict__ b1,
    const float* __restrict__ mw2T, const float* __restrict__ b2,
    const float* __restrict__ mwscT, const float* __restrict__ bsc,
    float* __restrict__ value)
{
  __shared__ float xs[256*32];
  __shared__ float hs[128*32];
  int t = threadIdx.x;
  int tile = blockIdx.x & 63, b = blockIdx.x >> 6;
  int n0 = tile*32;
  for (int e = t; e < 256*32; e += 256){
    int c = e >> 5, nn = e & 31;
    xs[e] = (c < 128) ? key[(size_t)(b*128+c)*Nv + n0+nn]
                      : query[(size_t)(b*128+(c-128))*Nv + n0+nn];
  }
  __syncthreads();
  int hg = t >> 2, ng = t & 3;
  int hd0 = hg*2, nb = ng*8;
  float acc[2][8];
  for (int i=0;i<2;i++){ float bb = b1[hd0+i]; for(int j=0;j<8;j++) acc[i][j]=bb; }
  for (int c = 0; c < 256; c++){
    float w0 = mw1T[c*128 + hd0], w1 = mw1T[c*128 + hd0+1];
    const float* xr = &xs[c*32 + nb];
    #pragma unroll
    for (int j=0;j<8;j++){ float xv = xr[j]; acc[0][j] += w0*xv; acc[1][j] += w1*xv; }
  }
  for (int i=0;i<2;i++) for (int j=0;j<8;j++){
    float v = acc[i][j]; hs[(hd0+i)*32 + nb + j] = v > 0.f ? v : 0.f;
  }
  __syncthreads();
  float out[2][8];
  for (int i=0;i<2;i++){ float bb = b2[hd0+i] + bsc[hd0+i]; for(int j=0;j<8;j++) out[i][j]=bb; }
  for (int c = 0; c < 128; c++){
    float w0 = mw2T[c*128 + hd0], w1 = mw2T[c*128 + hd0+1];
    const float* hr = &hs[c*32 + nb];
    #pragma unroll
    for (int j=0;j<8;j++){ float hv = hr[j]; out[0][j] += w0*hv; out[1][j] += w1*hv; }
  }
  for (int c = 0; c < 256; c++){
    float w0 = mwscT[c*128 + hd0], w1 = mwscT[c*128 + hd0+1];
    const float* xr = &xs[c*32 + nb];
    #pragma unroll
    for (int j=0;j<8;j++){ float xv = xr[j]; out[0][j] += w0*xv; out[1][j] += w1*xv; }
  }
  for (int i=0;i<2;i++) for (int j=0;j<8;j++)
    value[(size_t)(b*128 + hd0+i)*Nv + n0 + nb + j] = out[i][j];
}

// ---------------- conv1d (Cin=128 -> Dout=256), output transposed (B,N,256) ----------------
__global__ __launch_bounds__(256) void proj_kernel(
    const float* __restrict__ x, const float* __restrict__ wT,
    const float* __restrict__ bias, float* __restrict__ outT)
{
  __shared__ float xs[128*32];
  int t = threadIdx.x;
  int tile = blockIdx.x & 63, b = blockIdx.x >> 6;
  int n0 = tile*32;
  for (int e = t; e < 128*32; e += 256){
    int c = e >> 5, nn = e & 31;
    xs[e] = x[(size_t)(b*128+c)*Nv + n0+nn];
  }
  __syncthreads();
  int dg = t >> 2, ng = t & 3;
  int d0 = dg*4, nb = ng*8;
  float acc[4][8];
  for (int i=0;i<4;i++){ float bb = bias[d0+i]; for(int j=0;j<8;j++) acc[i][j]=bb; }
  for (int c = 0; c < 128; c++){
    float w0 = wT[c*256+d0], w1 = wT[c*256+d0+1], w2 = wT[c*256+d0+2], w3 = wT[c*256+d0+3];
    const float* xr = &xs[c*32+nb];
    #pragma unroll
    for (int j=0;j<8;j++){
      float xv = xr[j];
      acc[0][j] += w0*xv; acc[1][j] += w1*xv; acc[2][j] += w2*xv; acc[3][j] += w3*xv;
    }
  }
  for (int j=0;j<8;j++){
    int n = n0+nb+j;
    float4 v = make_float4(acc[0][j],acc[1][j],acc[2][j],acc[3][j]);
    *(float4*)&outT[(size_t)(b*Nv+n)*256 + d0] = v;
  }
}

// ---------------- KNN (16 smallest d, lowest-index tie-break) ----------------
__global__ __launch_bounds__(256) void knn_kernel(const float* __restrict__ pos, int* __restrict__ idx)
{
  __shared__ float dsm[2048];
  __shared__ float wvs[4];
  __shared__ int wis[4];
  int t = threadIdx.x;
  int i = blockIdx.x & (Nv-1), b = blockIdx.x >> 11;
  const float* px = pos + (size_t)b*3*Nv;
  float pix = px[i], piy = px[Nv+i], piz = px[2*Nv+i];
  float sqi = pix*pix; sqi += piy*piy; sqi += piz*piz;
  for (int jj = 0; jj < 8; jj++){
    int j = t + jj*256;
    float qx = px[j], qy = px[Nv+j], qz = px[2*Nv+j];
    float sqj = qx*qx; sqj += qy*qy; sqj += qz*qz;
    float dot = pix*qx + piy*qy + piz*qz;
    dsm[j] = (sqi + sqj) - 2.0f*dot;
  }
  __syncthreads();
  for (int it = 0; it < 16; it++){
    float bv = 3.4e38f; int bi = 0x7FFFFFFF;
    for (int jj = 0; jj < 8; jj++){
      int j = t + jj*256;
      float v = dsm[j];
      if (v < bv){ bv = v; bi = j; }
    }
    for (int off = 32; off; off >>= 1){
      float ov = __shfl_xor(bv, off);
      int oi = __shfl_xor(bi, off);
      if (ov < bv || (ov == bv && oi < bi)){ bv = ov; bi = oi; }
    }
    if ((t & 63) == 0){ wvs[t>>6] = bv; wis[t>>6] = bi; }
    __syncthreads();
    if (t == 0){
      float fv = wvs[0]; int fi = wis[0];
      for (int q = 1; q < 4; q++){
        if (wvs[q] < fv || (wvs[q] == fv && wis[q] < fi)){ fv = wvs[q]; fi = wis[q]; }
      }
      idx[(size_t)blockIdx.x*16 + it] = fi;
      dsm[fi] = 3.4e38f;
    }
    __syncthreads();
  }
}

// ---------------- pos-BN stats ----------------
__global__ __launch_bounds__(256) void bn1_stats(const float* __restrict__ pos,
    const int* __restrict__ idx, float* __restrict__ rstat)
{
  int tid = blockIdx.x*256 + threadIdx.x;
  int stride = gridDim.x*256;
  float s[9] = {0,0,0,0,0,0,0,0,0};
  for (int e = tid; e < NSAMP; e += stride){
    int b = e >> 15;
    int rem = e & 32767;
    int n = rem >> 4, k = rem & 15;
    int j = idx[(size_t)(b*Nv+n)*16 + k];
    const float* px = pos + (size_t)b*3*Nv;
    float rx = px[n]-px[j], ry = px[Nv+n]-px[Nv+j], rz = px[2*Nv+n]-px[2*Nv+j];
    s[0]+=rx; s[1]+=ry; s[2]+=rz;
    s[3]+=rx*rx; s[4]+=rx*ry; s[5]+=rx*rz; s[6]+=ry*ry; s[7]+=ry*rz; s[8]+=rz*rz;
  }
  for (int off=32; off; off>>=1)
    for (int q=0;q<9;q++) s[q] += __shfl_xor(s[q], off);
  if ((threadIdx.x & 63) == 0)
    for (int q=0;q<9;q++) atomicAdd(&rstat[q], s[q]);
}

// ---------------- fold pos BN ----------------
__global__ void bn1_final(const float* __restrict__ rstat,
    const float* __restrict__ pw1,
    const float* __restrict__ pg, const float* __restrict__ pbeta,
    float* __restrict__ w1eff, float* __restrict__ b1eff)
{
  int c = threadIdx.x; // 64
  float inv = 1.0f/(float)NSAMP;
  float mux = rstat[0]*inv, muy = rstat[1]*inv, muz = rstat[2]*inv;
  float xx = rstat[3]*inv, xy = rstat[4]*inv, xz = rstat[5]*inv;
  float yy = rstat[6]*inv, yz = rstat[7]*inv, zz = rstat[8]*inv;
  float w0 = pw1[c*3], w1 = pw1[c*3+1], w2 = pw1[c*3+2];
  float dot = w0*mux + w1*muy + w2*muz;
  float quad = w0*w0*xx + w1*w1*yy + w2*w2*zz + 2.f*(w0*w1*xy + w0*w2*xz + w1*w2*yz);
  float var = quad - dot*dot;
  float s = pg[c] * rsqrtf(var + 1e-5f);
  w1eff[c*3]   = w0*s;
  w1eff[c*3+1] = w1*s;
  w1eff[c*3+2] = w2*s;
  b1eff[c] = pbeta[c] - dot*s;
}

// ---------------- pass A: u = qk_rel + pos_emb -> U (f32), mu_u sums ----------------
#define PTSA 4
__global__ __launch_bounds__(256) void passA_kernel(
    const float* __restrict__ pos, const int* __restrict__ idx,
    const float* __restrict__ qT, const float* __restrict__ kT,
    const float* __restrict__ w1eff, const float* __restrict__ b1eff,
    const ushortt* __restrict__ w2posT, const float* __restrict__ pb2,
    float* __restrict__ U, float* __restrict__ mu_sum)
{
  __shared__ float hs[64*16];
  __shared__ float rs[3*16];
  __shared__ int idxs[16];
  __shared__ float mpart[256][4];
  int t = threadIdx.x;
  int dg = t >> 2, kg = t & 3;
  int d0 = dg*4, ks = kg*4;
  float msum[4] = {0,0,0,0};
  __align__(16) float pb2v[4];
  *(float4*)pb2v = *(const float4*)&pb2[d0];
  for (int p = 0; p < PTSA; p++){
    int pt = blockIdx.x*PTSA + p;
    int n = pt & (Nv-1), b = pt >> 11;
    if (p) __syncthreads();
    if (t < 16){
      int j = idx[(size_t)pt*16 + t];
      idxs[t] = j;
      const float* px = pos + (size_t)b*3*Nv;
      rs[t]    = px[n]      - px[j];
      rs[16+t] = px[Nv+n]   - px[Nv+j];
      rs[32+t] = px[2*Nv+n] - px[2*Nv+j];
    }
    __syncthreads();
    {
      int c = t & 63, kgr = t >> 6;
      float w0 = w1eff[c*3], w1 = w1eff[c*3+1], w2 = w1eff[c*3+2], bb = b1eff[c];
      #pragma unroll
      for (int kk = 0; kk < 4; kk++){
        int k = kgr*4 + kk;
        float v = bb + w0*rs[k] + w1*rs[16+k] + w2*rs[32+k];
        hs[c*16+k] = v > 0.f ? v : 0.f;
      }
    }
    __syncthreads();
    float pe[4][4];
    for (int i=0;i<4;i++) for(int kk=0;kk<4;kk++) pe[i][kk] = pb2v[i];
    for (int c = 0; c < 64; c++){
      __align__(8) ushortt wraw[4];
      *(uint2*)wraw = *(const uint2*)&w2posT[c*256 + d0];
      __align__(16) float hv[4];
      *(float4*)hv = *(const float4*)&hs[c*16 + ks];
      #pragma unroll
      for (int i=0;i<4;i++){
        float w = bf2f(wraw[i]);
        #pragma unroll
        for (int kk=0;kk<4;kk++) pe[i][kk] += w*hv[kk];
      }
    }
    __align__(16) float qv[4];
    *(float4*)qv = *(const float4*)&qT[(size_t)pt*256 + d0];
    #pragma unroll
    for (int kk = 0; kk < 4; kk++){
      int k = ks + kk;
      int j = idxs[k];
      __align__(16) float kv[4];
      *(float4*)kv = *(const float4*)&kT[(size_t)(b*Nv+j)*256 + d0];
      __align__(16) float ur[4];
      #pragma unroll
      for (int i=0;i<4;i++){
        float u = qv[i] - kv[i] + pe[i][kk];
        ur[i] = u;
        msum[i] += u;
      }
      *(float4*)&U[((size_t)pt*16 + k)*256 + d0] = *(float4*)ur;
    }
  }
  for (int i=0;i<4;i++) mpart[t][i] = msum[i];
  __syncthreads();
  {
    int d = t;
    float ssum = 0.f;
    for (int kg2 = 0; kg2 < 4; kg2++) ssum += mpart[(d>>2)*4 + kg2][d&3];
    atomicAdd(&mu_sum[d], ssum);
  }
}

// ---------------- M = sum_s u u^T ----------------
__global__ __launch_bounds__(256) void M_kernel(const float* __restrict__ U, float* __restrict__ Mm)
{
  __shared__ float As[64*64];
  __shared__ float Bs2[64*64];
  int t = threadIdx.x;
  int tile = blockIdx.x & 15, chunk = blockIdx.x >> 4;
  int tR = (tile >> 2)*64, tC = (tile & 3)*64;
  int ty = t >> 4, tx = t & 15;
  float acc[4][4] = {};
  int s0 = chunk*2048;
  for (int sb = 0; sb < 2048; sb += 64){
    for (int e = t; e < 1024; e += 256){
      int row = e >> 4, seg = e & 15;
      *(float4*)&As[row*64 + seg*4]  = *(const float4*)&U[((size_t)(s0+sb+row))*256 + tR + seg*4];
      *(float4*)&Bs2[row*64 + seg*4] = *(const float4*)&U[((size_t)(s0+sb+row))*256 + tC + seg*4];
    }
    __syncthreads();
    for (int ss = 0; ss < 64; ss++){
      __align__(16) float a[4], bb[4];
      *(float4*)a  = *(const float4*)&As[ss*64 + ty*4];
      *(float4*)bb = *(const float4*)&Bs2[ss*64 + tx*4];
      #pragma unroll
      for (int i=0;i<4;i++)
        #pragma unroll
        for(int j=0;j<4;j++) acc[i][j] += a[i]*bb[j];
    }
    __syncthreads();
  }
  for (int i=0;i<4;i++) for (int j=0;j<4;j++)
    atomicAdd(&Mm[(size_t)(tR + ty*4 + i)*256 + tC + tx*4 + j], acc[i][j]);
}

// ---------------- fold attn BN into w1effT (bf16) + b1eff2 ----------------
__global__ __launch_bounds__(256) void bn2_final(
    const float* __restrict__ Mm, const float* __restrict__ mu_sum,
    const float* __restrict__ aw1,
    const float* __restrict__ ag, const float* __restrict__ abeta,
    ushortt* __restrict__ w1effT, float* __restrict__ b1eff2)
{
  __shared__ float wrow[256];
  __shared__ float red[8];
  __shared__ float s2s;
  int t = threadIdx.x;
  int ch = blockIdx.x;
  wrow[t] = aw1[(size_t)ch*256 + t];
  __syncthreads();
  float colacc = 0.f;
  for (int r = 0; r < 256; r++) colacc += wrow[r] * Mm[(size_t)r*256 + t];
  float inv = 1.0f/(float)NSAMP;
  float qpart = colacc * wrow[t] * inv;
  float dpart = wrow[t] * mu_sum[t] * inv;
  for (int off=32; off; off>>=1){ qpart += __shfl_xor(qpart, off); dpart += __shfl_xor(dpart, off); }
  if ((t&63)==0){ red[t>>6] = qpart; red[4 + (t>>6)] = dpart; }
  __syncthreads();
  if (t == 0){
    float quad = red[0]+red[1]+red[2]+red[3];
    float dot  = red[4]+red[5]+red[6]+red[7];
    float var = quad - dot*dot;
    float s2 = ag[ch] * rsqrtf(var + 1e-5f);
    b1eff2[ch] = abeta[ch] - dot*s2;
    s2s = s2;
  }
  __syncthreads();
  w1effT[(size_t)t*1024 + ch] = f2bf(wrow[t]*s2s);
}

// ---------------- pass B: attn MLP + softmax + aggregation ----------------
__global__ __launch_bounds__(256) void passB_kernel(
    const int* __restrict__ idx, const float* __restrict__ U,
    const float* __restrict__ qT, const float* __restrict__ kT, const float* __restrict__ vT,
    const ushortt* __restrict__ w1effT, const float* __restrict__ b1eff2,
    const ushortt* __restrict__ w2T, const float* __restrict__ ab2,
    float* __restrict__ aggT)
{
  __shared__ float us[16*256];       // 16 KB (f32 u)
  __shared__ ushortt as_[16*1024];   // 32 KB; lg (16 KB f32) aliases it after GEMM2
  __shared__ int idxs[16];
  int t = threadIdx.x;
  int pt = blockIdx.x;
  int b = pt >> 11;
  if (t < 16) idxs[t] = idx[(size_t)pt*16 + t];
  {
    const float4* g = (const float4*)&U[(size_t)pt*16*256];
    float4* sh = (float4*)us;
    for (int e = t; e < 1024; e += 256) sh[e] = g[e];
  }
  __syncthreads();
  // GEMM1: a = relu(w1effT^T u + b1eff2)  -> as_ [k][1024] bf16
  {
    int ahg = t >> 2, kg = t & 3;
    int ah0 = ahg*16;
    float acc[16][4] = {};
    for (int c0 = 0; c0 < 256; c0 += 8){
      __align__(16) float uu[4][8];
      #pragma unroll
      for (int kk=0;kk<4;kk++){
        *(float4*)&uu[kk][0] = *(const float4*)&us[(kg*4+kk)*256 + c0];
        *(float4*)&uu[kk][4] = *(const float4*)&us[(kg*4+kk)*256 + c0 + 4];
      }
      #pragma unroll
      for (int cc = 0; cc < 8; cc++){
        __align__(16) ushortt wr[16];
        *(uint4*)&wr[0] = *(const uint4*)&w1effT[(size_t)(c0+cc)*1024 + ah0];
        *(uint4*)&wr[8] = *(const uint4*)&w1effT[(size_t)(c0+cc)*1024 + ah0 + 8];
        #pragma unroll
        for (int i=0;i<16;i++){
          float wv = bf2f(wr[i]);
          #pragma unroll
          for (int kk=0;kk<4;kk++) acc[i][kk] += wv*uu[kk][cc];
        }
      }
    }
    __align__(16) float bvv[16];
    *(float4*)&bvv[0]  = *(const float4*)&b1eff2[ah0];
    *(float4*)&bvv[4]  = *(const float4*)&b1eff2[ah0+4];
    *(float4*)&bvv[8]  = *(const float4*)&b1eff2[ah0+8];
    *(float4*)&bvv[12] = *(const float4*)&b1eff2[ah0+12];
    #pragma unroll
    for (int kk=0;kk<4;kk++){
      __align__(16) ushortt outr[16];
      #pragma unroll
      for (int i=0;i<16;i++){
        float v = acc[i][kk] + bvv[i];
        outr[i] = f2bf(v > 0.f ? v : 0.f);
      }
      *(uint4*)&as_[(kg*4+kk)*1024 + ah0]     = *(uint4*)&outr[0];
      *(uint4*)&as_[(kg*4+kk)*1024 + ah0 + 8] = *(uint4*)&outr[8];
    }
  }
  __syncthreads();
  // GEMM2: logits = w2T^T a + ab2 -> regs, then write to lg (aliased on as_)
  float acc2[4][4];
  int dg2 = t >> 2, kg2 = t & 3;
  int d02 = dg2*4;
  {
    __align__(16) float bb[4];
    *(float4*)bb = *(const float4*)&ab2[d02];
    for (int i=0;i<4;i++) for(int kk=0;kk<4;kk++) acc2[i][kk] = bb[i];
    for (int a0 = 0; a0 < 1024; a0 += 8){
      __align__(16) ushortt aa[4][8];
      #pragma unroll
      for (int kk=0;kk<4;kk++)
        *(uint4*)&aa[kk][0] = *(const uint4*)&as_[(kg2*4+kk)*1024 + a0];
      #pragma unroll
      for (int cc = 0; cc < 8; cc++){
        __align__(8) ushortt wr[4];
        *(uint2*)wr = *(const uint2*)&w2T[(size_t)(a0+cc)*256 + d02];
        float af[4];
        #pragma unroll
        for (int kk=0;kk<4;kk++) af[kk] = bf2f(aa[kk][cc]);
        #pragma unroll
        for (int i=0;i<4;i++){
          float wv = bf2f(wr[i]);
          #pragma unroll
          for (int kk=0;kk<4;kk++) acc2[i][kk] += wv*af[kk];
        }
      }
    }
  }
  __syncthreads();
  float* lg = (float*)as_;   // as_ is dead now
  #pragma unroll
  for (int i=0;i<4;i++)
    #pragma unroll
    for (int kk=0;kk<4;kk++)
      lg[(d02+i)*16 + kg2*4 + kk] = acc2[i][kk];
  __syncthreads();
  // softmax over k + aggregate
  {
    int d = t;
    float l[16];
    for (int q=0;q<4;q++) *(float4*)&l[q*4] = *(const float4*)&lg[d*16 + q*4];
    float m = l[0];
    #pragma unroll
    for (int q=1;q<16;q++) m = fmaxf(m, l[q]);
    float e[16], ssum = 0.f;
    #pragma unroll
    for (int q=0;q<16;q++){ e[q] = __expf(l[q]-m); ssum += e[q]; }
    float invs = 1.0f/ssum;
    float qv = qT[(size_t)pt*256 + d];
    float vv = vT[(size_t)pt*256 + d];
    float agg = 0.f;
    #pragma unroll
    for (int q=0;q<16;q++){
      int j = idxs[q];
      float kv = kT[(size_t)(b*Nv+j)*256 + d];
      float pe = us[q*256 + d] - qv + kv;   // exact pos_emb recovery (f32)
      agg += e[q]*invs * (vv + pe);
    }
    aggT[(size_t)pt*256 + d] = agg;
  }
}

// ---------------- final: out = end_w @ agg + end_b + value ----------------
__global__ __launch_bounds__(256) void final_kernel(
    const float* __restrict__ aggT, const float* __restrict__ endwT,
    const float* __restrict__ endb, const float* __restrict__ value,
    float* __restrict__ out)
{
  __shared__ float ags[32*257];
  int t = threadIdx.x;
  int tile = blockIdx.x & 63, b = blockIdx.x >> 6;
  int n0 = tile*32;
  for (int e = t; e < 32*256; e += 256){
    int nn = e >> 8, d = e & 255;
    ags[nn*257 + d] = aggT[(size_t)(b*Nv + n0 + nn)*256 + d];
  }
  __syncthreads();
  int cg = t >> 2, ng = t & 3;
  int co0 = cg*2, nb = ng*8;
  float acc[2][8];
  for (int i=0;i<2;i++){ float bb = endb[co0+i]; for (int j=0;j<8;j++) acc[i][j]=bb; }
  for (int d = 0; d < 256; d++){
    float w0 = endwT[d*128 + co0], w1 = endwT[d*128 + co0 + 1];
    #pragma unroll
    for (int j=0;j<8;j++){
      float av = ags[(nb+j)*257 + d];
      acc[0][j] += w0*av; acc[1][j] += w1*av;
    }
  }
  for (int i=0;i<2;i++){
    for (int j=0;j<8;j++){
      size_t o = (size_t)(b*128 + co0 + i)*Nv + n0 + nb + j;
      out[o] = acc[i][j] + value[o];
    }
  }
}

extern "C" void kernel_launch(void* const* d_in, const int* in_sizes, int n_in,
                              void* d_out, int out_size, void* d_ws, size_t ws_size,
                              hipStream_t stream)
{
  (void)in_sizes; (void)n_in; (void)out_size; (void)ws_size;
  const float* pos   = (const float*)d_in[0];
  const float* key   = (const float*)d_in[1];
  const float* query = (const float*)d_in[2];
  const float* mw1   = (const float*)d_in[3];
  const float* mb1   = (const float*)d_in[4];
  const float* mw2   = (const float*)d_in[5];
  const float* mb2   = (const float*)d_in[6];
  const float* mwsc  = (const float*)d_in[7];
  const float* mbsc  = (const float*)d_in[8];
  const float* wk    = (const float*)d_in[9];
  const float* bk    = (const float*)d_in[10];
  const float* wq    = (const float*)d_in[11];
  const float* bq    = (const float*)d_in[12];
  const float* wv    = (const float*)d_in[13];
  const float* bv    = (const float*)d_in[14];
  const float* pw1   = (const float*)d_in[15];
  const float* pg    = (const float*)d_in[17];
  const float* pbeta = (const float*)d_in[18];
  const float* pw2   = (const float*)d_in[19];
  const float* pb2   = (const float*)d_in[20];
  const float* aw1   = (const float*)d_in[21];
  const float* ag    = (const float*)d_in[23];
  const float* abeta = (const float*)d_in[24];
  const float* aw2   = (const float*)d_in[25];
  const float* ab2   = (const float*)d_in[26];
  const float* endw  = (const float*)d_in[27];
  const float* endb  = (const float*)d_in[28];
  float* out = (float*)d_out;

  char* wsb = (char*)d_ws;
  size_t off = 0;
  auto take = [&](size_t bytes)->char*{
    char* p = wsb + off; off += (bytes + 255) & ~(size_t)255; return p;
  };
  float* Mm      = (float*)take(65536*4);   // zeroed
  float* mu_sum  = (float*)take(256*4);     // zeroed
  float* rstat   = (float*)take(12*4);      // zeroed
  size_t zero_bytes = off;
  float* w1eff   = (float*)take(192*4);
  float* b1eff   = (float*)take(64*4);
  float* b1eff2  = (float*)take(1024*4);
  float* value   = (float*)take((size_t)524288*4);
  float* qT      = (float*)take((size_t)1048576*4);
  float* kT      = (float*)take((size_t)1048576*4);
  float* vT      = (float*)take((size_t)1048576*4);
  float* aggT    = (float*)take((size_t)1048576*4);
  float* wkT     = (float*)take(32768*4);
  float* wqT     = (float*)take(32768*4);
  float* wvT     = (float*)take(32768*4);
  float* endwT   = (float*)take(32768*4);
  float* mw1T    = (float*)take(32768*4);
  float* mw2T    = (float*)take(16384*4);
  float* mwscT   = (float*)take(32768*4);
  int*   idxb    = (int*)take(65536*4);
  float* U       = (float*)take((size_t)16777216*4);   // f32 now
  ushortt* w1effT= (ushortt*)take((size_t)262144*2);
  ushortt* w2T   = (ushortt*)take((size_t)262144*2);
  ushortt* w2posT= (ushortt*)take(16384*2);

  hipMemsetAsync(d_ws, 0, zero_bytes, stream);
  prep_weights<<<512,256,0,stream>>>(wk,wq,wv,endw,mw1,mw2,mwsc,aw2,pw2,
                                     wkT,wqT,wvT,endwT,mw1T,mw2T,mwscT,w2T,w2posT);
  mlpres_kernel<<<128,256,0,stream>>>(key,query,mw1T,mb1,mw2T,mb2,mwscT,mbsc,value);
  proj_kernel<<<128,256,0,stream>>>(query,wqT,bq,qT);
  proj_kernel<<<128,256,0,stream>>>(key,wkT,bk,kT);
  proj_kernel<<<128,256,0,stream>>>(value,wvT,bv,vT);
  knn_kernel<<<4096,256,0,stream>>>(pos,idxb);
  bn1_stats<<<64,256,0,stream>>>(pos,idxb,rstat);
  bn1_final<<<1,64,0,stream>>>(rstat,pw1,pg,pbeta,w1eff,b1eff);
  passA_kernel<<<1024,256,0,stream>>>(pos,idxb,qT,kT,w1eff,b1eff,w2posT,pb2,U,mu_sum);
  M_kernel<<<512,256,0,stream>>>(U,Mm);
  bn2_final<<<1024,256,0,stream>>>(Mm,mu_sum,aw1,ag,abeta,w1effT,b1eff2);
  passB_kernel<<<4096,256,0,stream>>>(idxb,U,qT,kT,vT,w1effT,b1eff2,w2T,ab2,aggT);
  final_kernel<<<128,256,0,stream>>>(aggT,endwT,endb,value,out);
}

// Round 3
// 879.185 us; speedup vs baseline: 1.6765x; 1.6765x over previous
//
#include <hip/hip_runtime.h>
#include <hip/hip_bf16.h>
#include <math.h>

#define Bv 2
#define Nv 2048
#define Cv 128
#define Dv 256
#define PHv 64
#define AHv 1024
#define Kv 16
#define NSAMP (Bv*Nv*Kv)   // 65536

typedef unsigned short ushortt;
typedef __attribute__((ext_vector_type(8))) short bf16x8;
typedef __attribute__((ext_vector_type(4))) float f32x4;

__device__ __forceinline__ float bf2f(ushortt h){
  union { unsigned int u; float f; } v; v.u = ((unsigned int)h) << 16; return v.f;
}
__device__ __forceinline__ ushortt f2bf(float f){
  union { unsigned int u; float f; } v; v.f = f;
  unsigned int r = v.u + 0x7FFFu + ((v.u >> 16) & 1u);
  return (ushortt)(r >> 16);
}

// ---------------- weight transposes / casts ----------------
__global__ __launch_bounds__(256) void prep_weights(
    const float* __restrict__ wk, const float* __restrict__ wq,
    const float* __restrict__ wv, const float* __restrict__ endw,
    const float* __restrict__ mw1, const float* __restrict__ mw2,
    const float* __restrict__ mwsc, const float* __restrict__ aw2,
    const float* __restrict__ pw2,
    float* __restrict__ wkT, float* __restrict__ wqT, float* __restrict__ wvT,
    float* __restrict__ endwT, float* __restrict__ mw1T, float* __restrict__ mw2T,
    float* __restrict__ mwscT, ushortt* __restrict__ w2R, ushortt* __restrict__ w2posT)
{
  int tid = blockIdx.x*256 + threadIdx.x;
  int stride = gridDim.x*256;
  for (int i = tid; i < 256*128; i += stride){ int d = i>>7, c = i&127;
    wkT[c*256+d] = wk[i]; wqT[c*256+d] = wq[i]; wvT[c*256+d] = wv[i]; }
  for (int i = tid; i < 128*256; i += stride){ int co = i>>8, d = i&255; endwT[d*128+co] = endw[i]; }
  for (int i = tid; i < 128*256; i += stride){ int h = i>>8, c = i&255; mw1T[c*128+h] = mw1[i]; }
  for (int i = tid; i < 128*128; i += stride){ int o = i>>7, c = i&127; mw2T[c*128+o] = mw2[i]; }
  for (int i = tid; i < 128*256; i += stride){ int o = i>>8, c = i&255; mwscT[c*128+o] = mwsc[i]; }
  // attn_w2 (256,1024) row-major direct bf16 cast: w2R[d][ah]
  for (int i = tid; i < 256*1024; i += stride) w2R[i] = f2bf(aw2[i]);
  for (int i = tid; i < 256*64; i += stride){ int d = i>>6, c = i&63; w2posT[c*256+d] = f2bf(pw2[i]); }
}

// ---------------- value = MLP_Res(cat(key,query)) ----------------
__global__ __launch_bounds__(256) void mlpres_kernel(
    const float* __restrict__ key, const float* __restrict__ query,
    const float* __restrict__ mw1T, const float* __restrict__ b1,
    const float* __restrict__ mw2T, const float* __restrict__ b2,
    const float* __restrict__ mwscT, const float* __restrict__ bsc,
    float* __restrict__ value)
{
  __shared__ float xs[256*32];
  __shared__ float hs[128*32];
  int t = threadIdx.x;
  int tile = blockIdx.x & 63, b = blockIdx.x >> 6;
  int n0 = tile*32;
  for (int e = t; e < 256*32; e += 256){
    int c = e >> 5, nn = e & 31;
    xs[e] = (c < 128) ? key[(size_t)(b*128+c)*Nv + n0+nn]
                      : query[(size_t)(b*128+(c-128))*Nv + n0+nn];
  }
  __syncthreads();
  int hg = t >> 2, ng = t & 3;
  int hd0 = hg*2, nb = ng*8;
  float acc[2][8];
  for (int i=0;i<2;i++){ float bb = b1[hd0+i]; for(int j=0;j<8;j++) acc[i][j]=bb; }
  for (int c = 0; c < 256; c++){
    float w0 = mw1T[c*128 + hd0], w1 = mw1T[c*128 + hd0+1];
    const float* xr = &xs[c*32 + nb];
    #pragma unroll
    for (int j=0;j<8;j++){ float xv = xr[j]; acc[0][j] += w0*xv; acc[1][j] += w1*xv; }
  }
  for (int i=0;i<2;i++) for (int j=0;j<8;j++){
    float v = acc[i][j]; hs[(hd0+i)*32 + nb + j] = v > 0.f ? v : 0.f;
  }
  __syncthreads();
  float out[2][8];
  for (int i=0;i<2;i++){ float bb = b2[hd0+i] + bsc[hd0+i]; for(int j=0;j<8;j++) out[i][j]=bb; }
  for (int c = 0; c < 128; c++){
    float w0 = mw2T[c*128 + hd0], w1 = mw2T[c*128 + hd0+1];
    const float* hr = &hs[c*32 + nb];
    #pragma unroll
    for (int j=0;j<8;j++){ float hv = hr[j]; out[0][j] += w0*hv; out[1][j] += w1*hv; }
  }
  for (int c = 0; c < 256; c++){
    float w0 = mwscT[c*128 + hd0], w1 = mwscT[c*128 + hd0+1];
    const float* xr = &xs[c*32 + nb];
    #pragma unroll
    for (int j=0;j<8;j++){ float xv = xr[j]; out[0][j] += w0*xv; out[1][j] += w1*xv; }
  }
  for (int i=0;i<2;i++) for (int j=0;j<8;j++)
    value[(size_t)(b*128 + hd0+i)*Nv + n0 + nb + j] = out[i][j];
}

// ---------------- conv1d (Cin=128 -> Dout=256), output transposed (B,N,256) ----------------
__global__ __launch_bounds__(256) void proj_kernel(
    const float* __restrict__ x, const float* __restrict__ wT,
    const float* __restrict__ bias, float* __restrict__ outT)
{
  __shared__ float xs[128*32];
  int t = threadIdx.x;
  int tile = blockIdx.x & 63, b = blockIdx.x >> 6;
  int n0 = tile*32;
  for (int e = t; e < 128*32; e += 256){
    int c = e >> 5, nn = e & 31;
    xs[e] = x[(size_t)(b*128+c)*Nv + n0+nn];
  }
  __syncthreads();
  int dg = t >> 2, ng = t & 3;
  int d0 = dg*4, nb = ng*8;
  float acc[4][8];
  for (int i=0;i<4;i++){ float bb = bias[d0+i]; for(int j=0;j<8;j++) acc[i][j]=bb; }
  for (int c = 0; c < 128; c++){
    float w0 = wT[c*256+d0], w1 = wT[c*256+d0+1], w2 = wT[c*256+d0+2], w3 = wT[c*256+d0+3];
    const float* xr = &xs[c*32+nb];
    #pragma unroll
    for (int j=0;j<8;j++){
      float xv = xr[j];
      acc[0][j] += w0*xv; acc[1][j] += w1*xv; acc[2][j] += w2*xv; acc[3][j] += w3*xv;
    }
  }
  for (int j=0;j<8;j++){
    int n = n0+nb+j;
    float4 v = make_float4(acc[0][j],acc[1][j],acc[2][j],acc[3][j]);
    *(float4*)&outT[(size_t)(b*Nv+n)*256 + d0] = v;
  }
}

// ---------------- KNN ----------------
__global__ __launch_bounds__(256) void knn_kernel(const float* __restrict__ pos, int* __restrict__ idx)
{
  __shared__ float dsm[2048];
  __shared__ float wvs[4];
  __shared__ int wis[4];
  int t = threadIdx.x;
  int i = blockIdx.x & (Nv-1), b = blockIdx.x >> 11;
  const float* px = pos + (size_t)b*3*Nv;
  float pix = px[i], piy = px[Nv+i], piz = px[2*Nv+i];
  float sqi = pix*pix; sqi += piy*piy; sqi += piz*piz;
  for (int jj = 0; jj < 8; jj++){
    int j = t + jj*256;
    float qx = px[j], qy = px[Nv+j], qz = px[2*Nv+j];
    float sqj = qx*qx; sqj += qy*qy; sqj += qz*qz;
    float dot = pix*qx + piy*qy + piz*qz;
    dsm[j] = (sqi + sqj) - 2.0f*dot;
  }
  __syncthreads();
  for (int it = 0; it < 16; it++){
    float bv = 3.4e38f; int bi = 0x7FFFFFFF;
    for (int jj = 0; jj < 8; jj++){
      int j = t + jj*256;
      float v = dsm[j];
      if (v < bv){ bv = v; bi = j; }
    }
    for (int off = 32; off; off >>= 1){
      float ov = __shfl_xor(bv, off);
      int oi = __shfl_xor(bi, off);
      if (ov < bv || (ov == bv && oi < bi)){ bv = ov; bi = oi; }
    }
    if ((t & 63) == 0){ wvs[t>>6] = bv; wis[t>>6] = bi; }
    __syncthreads();
    if (t == 0){
      float fv = wvs[0]; int fi = wis[0];
      for (int q = 1; q < 4; q++){
        if (wvs[q] < fv || (wvs[q] == fv && wis[q] < fi)){ fv = wvs[q]; fi = wis[q]; }
      }
      idx[(size_t)blockIdx.x*16 + it] = fi;
      dsm[fi] = 3.4e38f;
    }
    __syncthreads();
  }
}

// ---------------- pos-BN stats ----------------
__global__ __launch_bounds__(256) void bn1_stats(const float* __restrict__ pos,
    const int* __restrict__ idx, float* __restrict__ rstat)
{
  int tid = blockIdx.x*256 + threadIdx.x;
  int stride = gridDim.x*256;
  float s[9] = {0,0,0,0,0,0,0,0,0};
  for (int e = tid; e < NSAMP; e += stride){
    int b = e >> 15;
    int rem = e & 32767;
    int n = rem >> 4, k = rem & 15;
    int j = idx[(size_t)(b*Nv+n)*16 + k];
    const float* px = pos + (size_t)b*3*Nv;
    float rx = px[n]-px[j], ry = px[Nv+n]-px[Nv+j], rz = px[2*Nv+n]-px[2*Nv+j];
    s[0]+=rx; s[1]+=ry; s[2]+=rz;
    s[3]+=rx*rx; s[4]+=rx*ry; s[5]+=rx*rz; s[6]+=ry*ry; s[7]+=ry*rz; s[8]+=rz*rz;
  }
  for (int off=32; off; off>>=1)
    for (int q=0;q<9;q++) s[q] += __shfl_xor(s[q], off);
  if ((threadIdx.x & 63) == 0)
    for (int q=0;q<9;q++) atomicAdd(&rstat[q], s[q]);
}

// ---------------- fold pos BN ----------------
__global__ void bn1_final(const float* __restrict__ rstat,
    const float* __restrict__ pw1,
    const float* __restrict__ pg, const float* __restrict__ pbeta,
    float* __restrict__ w1eff, float* __restrict__ b1eff)
{
  int c = threadIdx.x; // 64
  float inv = 1.0f/(float)NSAMP;
  float mux = rstat[0]*inv, muy = rstat[1]*inv, muz = rstat[2]*inv;
  float xx = rstat[3]*inv, xy = rstat[4]*inv, xz = rstat[5]*inv;
  float yy = rstat[6]*inv, yz = rstat[7]*inv, zz = rstat[8]*inv;
  float w0 = pw1[c*3], w1 = pw1[c*3+1], w2 = pw1[c*3+2];
  float dot = w0*mux + w1*muy + w2*muz;
  float quad = w0*w0*xx + w1*w1*yy + w2*w2*zz + 2.f*(w0*w1*xy + w0*w2*xz + w1*w2*yz);
  float var = quad - dot*dot;
  float s = pg[c] * rsqrtf(var + 1e-5f);
  w1eff[c*3]   = w0*s;
  w1eff[c*3+1] = w1*s;
  w1eff[c*3+2] = w2*s;
  b1eff[c] = pbeta[c] - dot*s;
}

// ---------------- pass A: u = qk_rel + pos_emb -> U (f32), mu_u sums ----------------
#define PTSA 4
__global__ __launch_bounds__(256) void passA_kernel(
    const float* __restrict__ pos, const int* __restrict__ idx,
    const float* __restrict__ qT, const float* __restrict__ kT,
    const float* __restrict__ w1eff, const float* __restrict__ b1eff,
    const ushortt* __restrict__ w2posT, const float* __restrict__ pb2,
    float* __restrict__ U, float* __restrict__ mu_sum)
{
  __shared__ float hs[64*16];
  __shared__ float rs[3*16];
  __shared__ int idxs[16];
  __shared__ float mpart[256][4];
  int t = threadIdx.x;
  int dg = t >> 2, kg = t & 3;
  int d0 = dg*4, ks = kg*4;
  float msum[4] = {0,0,0,0};
  __align__(16) float pb2v[4];
  *(float4*)pb2v = *(const float4*)&pb2[d0];
  for (int p = 0; p < PTSA; p++){
    int pt = blockIdx.x*PTSA + p;
    int n = pt & (Nv-1), b = pt >> 11;
    if (p) __syncthreads();
    if (t < 16){
      int j = idx[(size_t)pt*16 + t];
      idxs[t] = j;
      const float* px = pos + (size_t)b*3*Nv;
      rs[t]    = px[n]      - px[j];
      rs[16+t] = px[Nv+n]   - px[Nv+j];
      rs[32+t] = px[2*Nv+n] - px[2*Nv+j];
    }
    __syncthreads();
    {
      int c = t & 63, kgr = t >> 6;
      float w0 = w1eff[c*3], w1 = w1eff[c*3+1], w2 = w1eff[c*3+2], bb = b1eff[c];
      #pragma unroll
      for (int kk = 0; kk < 4; kk++){
        int k = kgr*4 + kk;
        float v = bb + w0*rs[k] + w1*rs[16+k] + w2*rs[32+k];
        hs[c*16+k] = v > 0.f ? v : 0.f;
      }
    }
    __syncthreads();
    float pe[4][4];
    for (int i=0;i<4;i++) for(int kk=0;kk<4;kk++) pe[i][kk] = pb2v[i];
    for (int c = 0; c < 64; c++){
      __align__(8) ushortt wraw[4];
      *(uint2*)wraw = *(const uint2*)&w2posT[c*256 + d0];
      __align__(16) float hv[4];
      *(float4*)hv = *(const float4*)&hs[c*16 + ks];
      #pragma unroll
      for (int i=0;i<4;i++){
        float w = bf2f(wraw[i]);
        #pragma unroll
        for (int kk=0;kk<4;kk++) pe[i][kk] += w*hv[kk];
      }
    }
    __align__(16) float qv[4];
    *(float4*)qv = *(const float4*)&qT[(size_t)pt*256 + d0];
    #pragma unroll
    for (int kk = 0; kk < 4; kk++){
      int k = ks + kk;
      int j = idxs[k];
      __align__(16) float kv[4];
      *(float4*)kv = *(const float4*)&kT[(size_t)(b*Nv+j)*256 + d0];
      __align__(16) float ur[4];
      #pragma unroll
      for (int i=0;i<4;i++){
        float u = qv[i] - kv[i] + pe[i][kk];
        ur[i] = u;
        msum[i] += u;
      }
      *(float4*)&U[((size_t)pt*16 + k)*256 + d0] = *(float4*)ur;
    }
  }
  for (int i=0;i<4;i++) mpart[t][i] = msum[i];
  __syncthreads();
  {
    int d = t;
    float ssum = 0.f;
    for (int kg2 = 0; kg2 < 4; kg2++) ssum += mpart[(d>>2)*4 + kg2][d&3];
    atomicAdd(&mu_sum[d], ssum);
  }
}

// ---------------- M = sum_s u u^T ----------------
__global__ __launch_bounds__(256) void M_kernel(const float* __restrict__ U, float* __restrict__ Mm)
{
  __shared__ float As[64*64];
  __shared__ float Bs2[64*64];
  int t = threadIdx.x;
  int tile = blockIdx.x & 15, chunk = blockIdx.x >> 4;
  int tR = (tile >> 2)*64, tC = (tile & 3)*64;
  int ty = t >> 4, tx = t & 15;
  float acc[4][4] = {};
  int s0 = chunk*2048;
  for (int sb = 0; sb < 2048; sb += 64){
    for (int e = t; e < 1024; e += 256){
      int row = e >> 4, seg = e & 15;
      *(float4*)&As[row*64 + seg*4]  = *(const float4*)&U[((size_t)(s0+sb+row))*256 + tR + seg*4];
      *(float4*)&Bs2[row*64 + seg*4] = *(const float4*)&U[((size_t)(s0+sb+row))*256 + tC + seg*4];
    }
    __syncthreads();
    for (int ss = 0; ss < 64; ss++){
      __align__(16) float a[4], bb[4];
      *(float4*)a  = *(const float4*)&As[ss*64 + ty*4];
      *(float4*)bb = *(const float4*)&Bs2[ss*64 + tx*4];
      #pragma unroll
      for (int i=0;i<4;i++)
        #pragma unroll
        for(int j=0;j<4;j++) acc[i][j] += a[i]*bb[j];
    }
    __syncthreads();
  }
  for (int i=0;i<4;i++) for (int j=0;j<4;j++)
    atomicAdd(&Mm[(size_t)(tR + ty*4 + i)*256 + tC + tx*4 + j], acc[i][j]);
}

// ---------------- fold attn BN into w1R (bf16, row-major [1024][256]) + b1eff2 ----------------
__global__ __launch_bounds__(256) void bn2_final(
    const float* __restrict__ Mm, const float* __restrict__ mu_sum,
    const float* __restrict__ aw1,
    const float* __restrict__ ag, const float* __restrict__ abeta,
    ushortt* __restrict__ w1R, float* __restrict__ b1eff2)
{
  __shared__ float wrow[256];
  __shared__ float red[8];
  __shared__ float s2s;
  int t = threadIdx.x;
  int ch = blockIdx.x;
  wrow[t] = aw1[(size_t)ch*256 + t];
  __syncthreads();
  float colacc = 0.f;
  for (int r = 0; r < 256; r++) colacc += wrow[r] * Mm[(size_t)r*256 + t];
  float inv = 1.0f/(float)NSAMP;
  float qpart = colacc * wrow[t] * inv;
  float dpart = wrow[t] * mu_sum[t] * inv;
  for (int off=32; off; off>>=1){ qpart += __shfl_xor(qpart, off); dpart += __shfl_xor(dpart, off); }
  if ((t&63)==0){ red[t>>6] = qpart; red[4 + (t>>6)] = dpart; }
  __syncthreads();
  if (t == 0){
    float quad = red[0]+red[1]+red[2]+red[3];
    float dot  = red[4]+red[5]+red[6]+red[7];
    float var = quad - dot*dot;
    float s2 = ag[ch] * rsqrtf(var + 1e-5f);
    b1eff2[ch] = abeta[ch] - dot*s2;
    s2s = s2;
  }
  __syncthreads();
  w1R[(size_t)ch*256 + t] = f2bf(wrow[t]*s2s);
}

// ---------------- pass B (MFMA): attn MLP + softmax + aggregation ----------------
// block: 256 threads = 4 waves; 64 samples (4 pts). LDS: 64 KB arena.
union PBSmem {
  struct { ushortt W[256*64]; ushortt Hc[64*256]; } g;  // 32 KB + 32 KB
  float lgbuf[64*256];                                   // 64 KB (aliases after GEMMs)
};

__global__ __launch_bounds__(256) void passB_mfma(
    const int* __restrict__ idx, const float* __restrict__ U,
    const float* __restrict__ qT, const float* __restrict__ kT, const float* __restrict__ vT,
    const ushortt* __restrict__ w1R, const float* __restrict__ b1eff2,
    const ushortt* __restrict__ w2R, const float* __restrict__ ab2,
    float* __restrict__ aggT)
{
  __shared__ PBSmem sm;
  int t = threadIdx.x;
  int blk = blockIdx.x;            // 1024 blocks
  int w = t >> 6, l = t & 63;
  int lr = l & 15, g4 = l >> 4;    // frag col/row index and k-group
  int s0 = blk*64;

  int myidx = idx[s0 + l];         // lane l holds idx of sample s0+l (for shfl)

  // ---- A-fragments: this wave's 16 U rows, full K=256, bf16 in regs ----
  int srow = s0 + w*16 + lr;
  bf16x8 afr[8];
  #pragma unroll
  for (int kk = 0; kk < 8; kk++){
    const float* src = &U[(size_t)srow*256 + kk*32 + g4*8];
    float4 x0 = *(const float4*)src;
    float4 x1 = *(const float4*)(src+4);
    bf16x8 a;
    a[0]=(short)f2bf(x0.x); a[1]=(short)f2bf(x0.y); a[2]=(short)f2bf(x0.z); a[3]=(short)f2bf(x0.w);
    a[4]=(short)f2bf(x1.x); a[5]=(short)f2bf(x1.y); a[6]=(short)f2bf(x1.z); a[7]=(short)f2bf(x1.w);
    afr[kk] = a;
  }

  f32x4 acc2[16];
  #pragma unroll
  for (int i=0;i<16;i++) acc2[i] = (f32x4){0.f,0.f,0.f,0.f};

  for (int nc = 0; nc < 4; nc++){
    // ================= GEMM1: acc1 = U * W1c =================
    f32x4 acc1[16];
    #pragma unroll
    for (int i=0;i<16;i++) acc1[i] = (f32x4){0.f,0.f,0.f,0.f};
    for (int ks = 0; ks < 4; ks++){
      __syncthreads();   // protect W arena from previous readers
      #pragma unroll
      for (int i = 0; i < 8; i++){
        int e = t + 256*i;
        int row = e >> 3, grp = e & 7;
        uint4 v = *(const uint4*)&w1R[(size_t)(nc*256+row)*256 + ks*64 + grp*8];
        int dstb = row*128 + ((grp*16) ^ ((row&7)<<4));
        *(uint4*)((char*)sm.g.W + dstb) = v;
      }
      __syncthreads();   // publish W
      #pragma unroll
      for (int kk2 = 0; kk2 < 2; kk2++){
        int kfr = ks*2 + kk2;
        #pragma unroll
        for (int ni = 0; ni < 16; ni++){
          int ahrow = ni*16 + lr;
          int kb = kk2*64 + g4*16;
          int srcb = ahrow*128 + (kb ^ ((ahrow&7)<<4));
          bf16x8 bfrag = *(const bf16x8*)((char*)sm.g.W + srcb);
          acc1[ni] = __builtin_amdgcn_mfma_f32_16x16x32_bf16(afr[kfr], bfrag, acc1[ni], 0,0,0);
        }
      }
    }
    // ---- bias + ReLU + write Hc (wave-private rows) ----
    #pragma unroll
    for (int ni = 0; ni < 16; ni++){
      float bias = b1eff2[nc*256 + ni*16 + lr];
      #pragma unroll
      for (int r = 0; r < 4; r++){
        float v = acc1[ni][r] + bias;
        v = v > 0.f ? v : 0.f;
        int sloc = w*16 + g4*4 + r;
        int ahc = ni*16 + lr;
        int byteo = sloc*512 + ((ahc*2) ^ ((sloc&7)<<4));
        *(ushortt*)((char*)sm.g.Hc + byteo) = f2bf(v);
      }
    }
    // ================= GEMM2: acc2 += Hc * W2c =================
    for (int ks2 = 0; ks2 < 4; ks2++){
      __syncthreads();   // protect W arena (GEMM1 readers / prev stage readers done)
      #pragma unroll
      for (int i = 0; i < 8; i++){
        int e = t + 256*i;
        int row = e >> 3, grp = e & 7;
        uint4 v = *(const uint4*)&w2R[(size_t)row*1024 + nc*256 + ks2*64 + grp*8];
        int dstb = row*128 + ((grp*16) ^ ((row&7)<<4));
        *(uint4*)((char*)sm.g.W + dstb) = v;
      }
      __syncthreads();   // publish W2
      #pragma unroll
      for (int kk2 = 0; kk2 < 2; kk2++){
        // A-frag from Hc (this wave's rows)
        int hrow = w*16 + lr;
        int kByte = ks2*128 + kk2*64 + g4*16;
        int srcA = hrow*512 + (kByte ^ ((hrow&7)<<4));
        bf16x8 hfrag = *(const bf16x8*)((char*)sm.g.Hc + srcA);
        #pragma unroll
        for (int ni = 0; ni < 16; ni++){
          int drow = ni*16 + lr;
          int kb = kk2*64 + g4*16;
          int srcb = drow*128 + (kb ^ ((drow&7)<<4));
          bf16x8 bfrag = *(const bf16x8*)((char*)sm.g.W + srcb);
          acc2[ni] = __builtin_amdgcn_mfma_f32_16x16x32_bf16(hfrag, bfrag, acc2[ni], 0,0,0);
        }
      }
    }
  }
  // ---- write logits (+ bias) to lgbuf (aliases W/Hc) ----
  __syncthreads();
  #pragma unroll
  for (int ni = 0; ni < 16; ni++){
    float bias = ab2[ni*16 + lr];
    #pragma unroll
    for (int r = 0; r < 4; r++){
      int sloc = w*16 + g4*4 + r;
      int d = ni*16 + lr;
      sm.lgbuf[sloc*256 + d] = acc2[ni][r] + bias;
    }
  }
  __syncthreads();
  // ---- softmax over k + aggregation ----
  {
    int d = t;   // 0..255
    for (int ptl = 0; ptl < 4; ptl++){
      int pt = blk*4 + ptl;
      int b = pt >> 11;
      float lv[16];
      #pragma unroll
      for (int kk = 0; kk < 16; kk++) lv[kk] = sm.lgbuf[(ptl*16+kk)*256 + d];
      float m = lv[0];
      #pragma unroll
      for (int kk = 1; kk < 16; kk++) m = fmaxf(m, lv[kk]);
      float ev[16], ssum = 0.f;
      #pragma unroll
      for (int kk = 0; kk < 16; kk++){ ev[kk] = __expf(lv[kk]-m); ssum += ev[kk]; }
      float invs = 1.0f/ssum;
      float qv = qT[(size_t)pt*256 + d];
      float vv = vT[(size_t)pt*256 + d];
      float agg = 0.f;
      #pragma unroll
      for (int kk = 0; kk < 16; kk++){
        int j = __shfl(myidx, ptl*16 + kk);
        float kv = kT[(size_t)(b*Nv+j)*256 + d];
        float u = U[(size_t)(s0 + ptl*16 + kk)*256 + d];
        float pe = u - qv + kv;
        agg += ev[kk]*invs * (vv + pe);
      }
      aggT[(size_t)pt*256 + d] = agg;
    }
  }
}

// ---------------- final: out = end_w @ agg + end_b + value ----------------
__global__ __launch_bounds__(256) void final_kernel(
    const float* __restrict__ aggT, const float* __restrict__ endwT,
    const float* __restrict__ endb, const float* __restrict__ value,
    float* __restrict__ out)
{
  __shared__ float ags[32*257];
  int t = threadIdx.x;
  int tile = blockIdx.x & 63, b = blockIdx.x >> 6;
  int n0 = tile*32;
  for (int e = t; e < 32*256; e += 256){
    int nn = e >> 8, d = e & 255;
    ags[nn*257 + d] = aggT[(size_t)(b*Nv + n0 + nn)*256 + d];
  }
  __syncthreads();
  int cg = t >> 2, ng = t & 3;
  int co0 = cg*2, nb = ng*8;
  float acc[2][8];
  for (int i=0;i<2;i++){ float bb = endb[co0+i]; for (int j=0;j<8;j++) acc[i][j]=bb; }
  for (int d = 0; d < 256; d++){
    float w0 = endwT[d*128 + co0], w1 = endwT[d*128 + co0 + 1];
    #pragma unroll
    for (int j=0;j<8;j++){
      float av = ags[(nb+j)*257 + d];
      acc[0][j] += w0*av; acc[1][j] += w1*av;
    }
  }
  for (int i=0;i<2;i++){
    for (int j=0;j<8;j++){
      size_t o = (size_t)(b*128 + co0 + i)*Nv + n0 + nb + j;
      out[o] = acc[i][j] + value[o];
    }
  }
}

extern "C" void kernel_launch(void* const* d_in, const int* in_sizes, int n_in,
                              void* d_out, int out_size, void* d_ws, size_t ws_size,
                              hipStream_t stream)
{
  (void)in_sizes; (void)n_in; (void)out_size; (void)ws_size;
  const float* pos   = (const float*)d_in[0];
  const float* key   = (const float*)d_in[1];
  const float* query = (const float*)d_in[2];
  const float* mw1   = (const float*)d_in[3];
  const float* mb1   = (const float*)d_in[4];
  const float* mw2   = (const float*)d_in[5];
  const float* mb2   = (const float*)d_in[6];
  const float* mwsc  = (const float*)d_in[7];
  const float* mbsc  = (const float*)d_in[8];
  const float* wk    = (const float*)d_in[9];
  const float* bk    = (const float*)d_in[10];
  const float* wq    = (const float*)d_in[11];
  const float* bq    = (const float*)d_in[12];
  const float* wv    = (const float*)d_in[13];
  const float* bv    = (const float*)d_in[14];
  const float* pw1   = (const float*)d_in[15];
  const float* pg    = (const float*)d_in[17];
  const float* pbeta = (const float*)d_in[18];
  const float* pw2   = (const float*)d_in[19];
  const float* pb2   = (const float*)d_in[20];
  const float* aw1   = (const float*)d_in[21];
  const float* ag    = (const float*)d_in[23];
  const float* abeta = (const float*)d_in[24];
  const float* aw2   = (const float*)d_in[25];
  const float* ab2   = (const float*)d_in[26];
  const float* endw  = (const float*)d_in[27];
  const float* endb  = (const float*)d_in[28];
  float* out = (float*)d_out;

  char* wsb = (char*)d_ws;
  size_t off = 0;
  auto take = [&](size_t bytes)->char*{
    char* p = wsb + off; off += (bytes + 255) & ~(size_t)255; return p;
  };
  float* Mm      = (float*)take(65536*4);   // zeroed
  float* mu_sum  = (float*)take(256*4);     // zeroed
  float* rstat   = (float*)take(12*4);      // zeroed
  size_t zero_bytes = off;
  float* w1eff   = (float*)take(192*4);
  float* b1eff   = (float*)take(64*4);
  float* b1eff2  = (float*)take(1024*4);
  float* value   = (float*)take((size_t)524288*4);
  float* qT      = (float*)take((size_t)1048576*4);
  float* kT      = (float*)take((size_t)1048576*4);
  float* vT      = (float*)take((size_t)1048576*4);
  float* aggT    = (float*)take((size_t)1048576*4);
  float* wkT     = (float*)take(32768*4);
  float* wqT     = (float*)take(32768*4);
  float* wvT     = (float*)take(32768*4);
  float* endwT   = (float*)take(32768*4);
  float* mw1T    = (float*)take(32768*4);
  float* mw2T    = (float*)take(16384*4);
  float* mwscT   = (float*)take(32768*4);
  int*   idxb    = (int*)take(65536*4);
  float* U       = (float*)take((size_t)16777216*4);
  ushortt* w1R   = (ushortt*)take((size_t)262144*2);
  ushortt* w2R   = (ushortt*)take((size_t)262144*2);
  ushortt* w2posT= (ushortt*)take(16384*2);

  hipMemsetAsync(d_ws, 0, zero_bytes, stream);
  prep_weights<<<512,256,0,stream>>>(wk,wq,wv,endw,mw1,mw2,mwsc,aw2,pw2,
                                     wkT,wqT,wvT,endwT,mw1T,mw2T,mwscT,w2R,w2posT);
  mlpres_kernel<<<128,256,0,stream>>>(key,query,mw1T,mb1,mw2T,mb2,mwscT,mbsc,value);
  proj_kernel<<<128,256,0,stream>>>(query,wqT,bq,qT);
  proj_kernel<<<128,256,0,stream>>>(key,wkT,bk,kT);
  proj_kernel<<<128,256,0,stream>>>(value,wvT,bv,vT);
  knn_kernel<<<4096,256,0,stream>>>(pos,idxb);
  bn1_stats<<<64,256,0,stream>>>(pos,idxb,rstat);
  bn1_final<<<1,64,0,stream>>>(rstat,pw1,pg,pbeta,w1eff,b1eff);
  passA_kernel<<<1024,256,0,stream>>>(pos,idxb,qT,kT,w1eff,b1eff,w2posT,pb2,U,mu_sum);
  M_kernel<<<512,256,0,stream>>>(U,Mm);
  bn2_final<<<1024,256,0,stream>>>(Mm,mu_sum,aw1,ag,abeta,w1R,b1eff2);
  passB_mfma<<<1024,256,0,stream>>>(idxb,U,qT,kT,vT,w1R,b1eff2,w2R,ab2,aggT);
  final_kernel<<<128,256,0,stream>>>(aggT,endwT,endb,value,out);
}

// Round 5
// 505.904 us; speedup vs baseline: 2.9135x; 1.7378x over previous
//
#include <hip/hip_runtime.h>
#include <hip/hip_bf16.h>
#include <math.h>

#define Bv 2
#define Nv 2048
#define Cv 128
#define Dv 256
#define PHv 64
#define AHv 1024
#define Kv 16
#define NSAMP (Bv*Nv*Kv)   // 65536

typedef unsigned short ushortt;
typedef __attribute__((ext_vector_type(8))) short bf16x8;
typedef __attribute__((ext_vector_type(4))) float f32x4;

__device__ __forceinline__ float bf2f(ushortt h){
  union { unsigned int u; float f; } v; v.u = ((unsigned int)h) << 16; return v.f;
}
__device__ __forceinline__ ushortt f2bf(float f){
  union { unsigned int u; float f; } v; v.f = f;
  unsigned int r = v.u + 0x7FFFu + ((v.u >> 16) & 1u);
  return (ushortt)(r >> 16);
}

__device__ __forceinline__ void gload16(const void* g, void* l){
  __builtin_amdgcn_global_load_lds(
      (const __attribute__((address_space(1))) unsigned int*)g,
      (__attribute__((address_space(3))) unsigned int*)l, 16, 0, 0);
}

// ---------------- weight transposes / casts ----------------
__global__ __launch_bounds__(256) void prep_weights(
    const float* __restrict__ wk, const float* __restrict__ wq,
    const float* __restrict__ wv, const float* __restrict__ endw,
    const float* __restrict__ mw1, const float* __restrict__ mw2,
    const float* __restrict__ mwsc, const float* __restrict__ aw2,
    const float* __restrict__ pw2,
    float* __restrict__ wkT, float* __restrict__ wqT, float* __restrict__ wvT,
    float* __restrict__ endwT, float* __restrict__ mw1T, float* __restrict__ mw2T,
    float* __restrict__ mwscT, ushortt* __restrict__ w2R, ushortt* __restrict__ w2posT)
{
  int tid = blockIdx.x*256 + threadIdx.x;
  int stride = gridDim.x*256;
  for (int i = tid; i < 256*128; i += stride){ int d = i>>7, c = i&127;
    wkT[c*256+d] = wk[i]; wqT[c*256+d] = wq[i]; wvT[c*256+d] = wv[i]; }
  for (int i = tid; i < 128*256; i += stride){ int co = i>>8, d = i&255; endwT[d*128+co] = endw[i]; }
  for (int i = tid; i < 128*256; i += stride){ int h = i>>8, c = i&255; mw1T[c*128+h] = mw1[i]; }
  for (int i = tid; i < 128*128; i += stride){ int o = i>>7, c = i&127; mw2T[c*128+o] = mw2[i]; }
  for (int i = tid; i < 128*256; i += stride){ int o = i>>8, c = i&255; mwscT[c*128+o] = mwsc[i]; }
  // attn_w2 (256,1024) row-major bf16: w2R[d][ah]
  for (int i = tid; i < 256*1024; i += stride) w2R[i] = f2bf(aw2[i]);
  for (int i = tid; i < 256*64; i += stride){ int d = i>>6, c = i&63; w2posT[c*256+d] = f2bf(pw2[i]); }
}

// ---------------- value = MLP_Res(cat(key,query)) ----------------
__global__ __launch_bounds__(256) void mlpres_kernel(
    const float* __restrict__ key, const float* __restrict__ query,
    const float* __restrict__ mw1T, const float* __restrict__ b1,
    const float* __restrict__ mw2T, const float* __restrict__ b2,
    const float* __restrict__ mwscT, const float* __restrict__ bsc,
    float* __restrict__ value)
{
  __shared__ float xs[256*32];
  __shared__ float hs[128*32];
  int t = threadIdx.x;
  int tile = blockIdx.x & 63, b = blockIdx.x >> 6;
  int n0 = tile*32;
  for (int e = t; e < 256*32; e += 256){
    int c = e >> 5, nn = e & 31;
    xs[e] = (c < 128) ? key[(size_t)(b*128+c)*Nv + n0+nn]
                      : query[(size_t)(b*128+(c-128))*Nv + n0+nn];
  }
  __syncthreads();
  int hg = t >> 2, ng = t & 3;
  int hd0 = hg*2, nb = ng*8;
  float acc[2][8];
  for (int i=0;i<2;i++){ float bb = b1[hd0+i]; for(int j=0;j<8;j++) acc[i][j]=bb; }
  for (int c = 0; c < 256; c++){
    float w0 = mw1T[c*128 + hd0], w1 = mw1T[c*128 + hd0+1];
    const float* xr = &xs[c*32 + nb];
    #pragma unroll
    for (int j=0;j<8;j++){ float xv = xr[j]; acc[0][j] += w0*xv; acc[1][j] += w1*xv; }
  }
  for (int i=0;i<2;i++) for (int j=0;j<8;j++){
    float v = acc[i][j]; hs[(hd0+i)*32 + nb + j] = v > 0.f ? v : 0.f;
  }
  __syncthreads();
  float out[2][8];
  for (int i=0;i<2;i++){ float bb = b2[hd0+i] + bsc[hd0+i]; for(int j=0;j<8;j++) out[i][j]=bb; }
  for (int c = 0; c < 128; c++){
    float w0 = mw2T[c*128 + hd0], w1 = mw2T[c*128 + hd0+1];
    const float* hr = &hs[c*32 + nb];
    #pragma unroll
    for (int j=0;j<8;j++){ float hv = hr[j]; out[0][j] += w0*hv; out[1][j] += w1*hv; }
  }
  for (int c = 0; c < 256; c++){
    float w0 = mwscT[c*128 + hd0], w1 = mwscT[c*128 + hd0+1];
    const float* xr = &xs[c*32 + nb];
    #pragma unroll
    for (int j=0;j<8;j++){ float xv = xr[j]; out[0][j] += w0*xv; out[1][j] += w1*xv; }
  }
  for (int i=0;i<2;i++) for (int j=0;j<8;j++)
    value[(size_t)(b*128 + hd0+i)*Nv + n0 + nb + j] = out[i][j];
}

// ---------------- conv1d (Cin=128 -> Dout=256), output transposed (B,N,256) ----------------
__global__ __launch_bounds__(256) void proj_kernel(
    const float* __restrict__ x, const float* __restrict__ wT,
    const float* __restrict__ bias, float* __restrict__ outT)
{
  __shared__ float xs[128*32];
  int t = threadIdx.x;
  int tile = blockIdx.x & 63, b = blockIdx.x >> 6;
  int n0 = tile*32;
  for (int e = t; e < 128*32; e += 256){
    int c = e >> 5, nn = e & 31;
    xs[e] = x[(size_t)(b*128+c)*Nv + n0+nn];
  }
  __syncthreads();
  int dg = t >> 2, ng = t & 3;
  int d0 = dg*4, nb = ng*8;
  float acc[4][8];
  for (int i=0;i<4;i++){ float bb = bias[d0+i]; for(int j=0;j<8;j++) acc[i][j]=bb; }
  for (int c = 0; c < 128; c++){
    float w0 = wT[c*256+d0], w1 = wT[c*256+d0+1], w2 = wT[c*256+d0+2], w3 = wT[c*256+d0+3];
    const float* xr = &xs[c*32+nb];
    #pragma unroll
    for (int j=0;j<8;j++){
      float xv = xr[j];
      acc[0][j] += w0*xv; acc[1][j] += w1*xv; acc[2][j] += w2*xv; acc[3][j] += w3*xv;
    }
  }
  for (int j=0;j<8;j++){
    int n = n0+nb+j;
    float4 v = make_float4(acc[0][j],acc[1][j],acc[2][j],acc[3][j]);
    *(float4*)&outT[(size_t)(b*Nv+n)*256 + d0] = v;
  }
}

// ---------------- KNN: wave-per-point, pure shfl ----------------
__global__ __launch_bounds__(256) void knn_kernel(const float* __restrict__ pos, int* __restrict__ idx)
{
  int t = threadIdx.x;
  int w = t >> 6, l = t & 63;
  int p = blockIdx.x*4 + w;          // 1024 blocks -> 4096 points
  int i = p & (Nv-1), b = p >> 11;
  const float* px = pos + (size_t)b*3*Nv;
  float pix = px[i], piy = px[Nv+i], piz = px[2*Nv+i];
  float sqi = pix*pix + piy*piy + piz*piz;
  float ds[32];
  #pragma unroll
  for (int jj = 0; jj < 32; jj++){
    int j = jj*64 + l;
    float qx = px[j], qy = px[Nv+j], qz = px[2*Nv+j];
    float sqj = qx*qx + qy*qy + qz*qz;
    float dot = pix*qx + piy*qy + piz*qz;
    ds[jj] = (sqi + sqj) - 2.0f*dot;
  }
  #pragma unroll 1
  for (int it = 0; it < 16; it++){
    float bv = 3.4e38f; int bj = 0x7FFFFFFF;
    #pragma unroll
    for (int jj = 0; jj < 32; jj++){
      int j = jj*64 + l;
      bool c = ds[jj] < bv;
      bv = c ? ds[jj] : bv;
      bj = c ? j : bj;
    }
    #pragma unroll
    for (int off = 32; off; off >>= 1){
      float ov = __shfl_xor(bv, off);
      int oj = __shfl_xor(bj, off);
      if (ov < bv || (ov == bv && oj < bj)){ bv = ov; bj = oj; }
    }
    if (l == 0) idx[(size_t)p*16 + it] = bj;
    #pragma unroll
    for (int jj = 0; jj < 32; jj++){
      if (jj*64 + l == bj) ds[jj] = 3.4e38f;
    }
  }
}

// ---------------- pos-BN stats ----------------
__global__ __launch_bounds__(256) void bn1_stats(const float* __restrict__ pos,
    const int* __restrict__ idx, float* __restrict__ rstat)
{
  int tid = blockIdx.x*256 + threadIdx.x;
  int stride = gridDim.x*256;
  float s[9] = {0,0,0,0,0,0,0,0,0};
  for (int e = tid; e < NSAMP; e += stride){
    int b = e >> 15;
    int rem = e & 32767;
    int n = rem >> 4, k = rem & 15;
    int j = idx[(size_t)(b*Nv+n)*16 + k];
    const float* px = pos + (size_t)b*3*Nv;
    float rx = px[n]-px[j], ry = px[Nv+n]-px[Nv+j], rz = px[2*Nv+n]-px[2*Nv+j];
    s[0]+=rx; s[1]+=ry; s[2]+=rz;
    s[3]+=rx*rx; s[4]+=rx*ry; s[5]+=rx*rz; s[6]+=ry*ry; s[7]+=ry*rz; s[8]+=rz*rz;
  }
  for (int off=32; off; off>>=1)
    for (int q=0;q<9;q++) s[q] += __shfl_xor(s[q], off);
  if ((threadIdx.x & 63) == 0)
    for (int q=0;q<9;q++) atomicAdd(&rstat[q], s[q]);
}

// ---------------- fold pos BN ----------------
__global__ void bn1_final(const float* __restrict__ rstat,
    const float* __restrict__ pw1,
    const float* __restrict__ pg, const float* __restrict__ pbeta,
    float* __restrict__ w1eff, float* __restrict__ b1eff)
{
  int c = threadIdx.x; // 64
  float inv = 1.0f/(float)NSAMP;
  float mux = rstat[0]*inv, muy = rstat[1]*inv, muz = rstat[2]*inv;
  float xx = rstat[3]*inv, xy = rstat[4]*inv, xz = rstat[5]*inv;
  float yy = rstat[6]*inv, yz = rstat[7]*inv, zz = rstat[8]*inv;
  float w0 = pw1[c*3], w1 = pw1[c*3+1], w2 = pw1[c*3+2];
  float dot = w0*mux + w1*muy + w2*muz;
  float quad = w0*w0*xx + w1*w1*yy + w2*w2*zz + 2.f*(w0*w1*xy + w0*w2*xz + w1*w2*yz);
  float var = quad - dot*dot;
  float s = pg[c] * rsqrtf(var + 1e-5f);
  w1eff[c*3]   = w0*s;
  w1eff[c*3+1] = w1*s;
  w1eff[c*3+2] = w2*s;
  b1eff[c] = pbeta[c] - dot*s;
}

// ---------------- pass A: u = qk_rel + pos_emb -> U (f32) + U16 (bf16), mu sums ----------------
#define PTSA 4
__global__ __launch_bounds__(256) void passA_kernel(
    const float* __restrict__ pos, const int* __restrict__ idx,
    const float* __restrict__ qT, const float* __restrict__ kT,
    const float* __restrict__ w1eff, const float* __restrict__ b1eff,
    const ushortt* __restrict__ w2posT, const float* __restrict__ pb2,
    float* __restrict__ U, ushortt* __restrict__ U16, float* __restrict__ mu_sum)
{
  __shared__ float hs[64*16];
  __shared__ float rs[3*16];
  __shared__ int idxs[16];
  __shared__ float mpart[256][4];
  int t = threadIdx.x;
  int dg = t >> 2, kg = t & 3;
  int d0 = dg*4, ks = kg*4;
  float msum[4] = {0,0,0,0};
  __align__(16) float pb2v[4];
  *(float4*)pb2v = *(const float4*)&pb2[d0];
  for (int p = 0; p < PTSA; p++){
    int pt = blockIdx.x*PTSA + p;
    int n = pt & (Nv-1), b = pt >> 11;
    if (p) __syncthreads();
    if (t < 16){
      int j = idx[(size_t)pt*16 + t];
      idxs[t] = j;
      const float* px = pos + (size_t)b*3*Nv;
      rs[t]    = px[n]      - px[j];
      rs[16+t] = px[Nv+n]   - px[Nv+j];
      rs[32+t] = px[2*Nv+n] - px[2*Nv+j];
    }
    __syncthreads();
    {
      int c = t & 63, kgr = t >> 6;
      float w0 = w1eff[c*3], w1 = w1eff[c*3+1], w2 = w1eff[c*3+2], bb = b1eff[c];
      #pragma unroll
      for (int kk = 0; kk < 4; kk++){
        int k = kgr*4 + kk;
        float v = bb + w0*rs[k] + w1*rs[16+k] + w2*rs[32+k];
        hs[c*16+k] = v > 0.f ? v : 0.f;
      }
    }
    __syncthreads();
    float pe[4][4];
    for (int i=0;i<4;i++) for(int kk=0;kk<4;kk++) pe[i][kk] = pb2v[i];
    for (int c = 0; c < 64; c++){
      __align__(8) ushortt wraw[4];
      *(uint2*)wraw = *(const uint2*)&w2posT[c*256 + d0];
      __align__(16) float hv[4];
      *(float4*)hv = *(const float4*)&hs[c*16 + ks];
      #pragma unroll
      for (int i=0;i<4;i++){
        float w = bf2f(wraw[i]);
        #pragma unroll
        for (int kk=0;kk<4;kk++) pe[i][kk] += w*hv[kk];
      }
    }
    __align__(16) float qv[4];
    *(float4*)qv = *(const float4*)&qT[(size_t)pt*256 + d0];
    #pragma unroll
    for (int kk = 0; kk < 4; kk++){
      int k = ks + kk;
      int j = idxs[k];
      __align__(16) float kv[4];
      *(float4*)kv = *(const float4*)&kT[(size_t)(b*Nv+j)*256 + d0];
      __align__(16) float ur[4];
      __align__(8) ushortt hr[4];
      #pragma unroll
      for (int i=0;i<4;i++){
        float u = qv[i] - kv[i] + pe[i][kk];
        ur[i] = u;
        hr[i] = f2bf(u);
        msum[i] += u;
      }
      *(float4*)&U[((size_t)pt*16 + k)*256 + d0] = *(float4*)ur;
      *(uint2*)&U16[((size_t)pt*16 + k)*256 + d0] = *(uint2*)hr;
    }
  }
  for (int i=0;i<4;i++) mpart[t][i] = msum[i];
  __syncthreads();
  {
    int d = t;
    float ssum = 0.f;
    for (int kg2 = 0; kg2 < 4; kg2++) ssum += mpart[(d>>2)*4 + kg2][d&3];
    atomicAdd(&mu_sum[d], ssum);
  }
}

// ---------------- M: Mm += sum_s u u^T (MFMA, bf16 U), atomic accumulate ----------------
// grid 64 blocks (1024 samples each), 512 threads = 8 waves (2x4): wave tile 128(c1) x 64(c2)
__global__ __launch_bounds__(512) void mm_kernel(const ushortt* __restrict__ U16, float* __restrict__ Mm)
{
  __shared__ ushortt Us[64*256];   // [s][c], byte(s,c) = s*512 + ((c*2) ^ (((s>>3)&7)<<4))
  int t = threadIdx.x;
  int w = t >> 6, l = t & 63;
  int lr = l & 15, g4 = l >> 4;
  int wm = w >> 2, wn = w & 3;
  int blk = blockIdx.x;
  int sstart = blk*1024;
  f32x4 acc[8][4];
  #pragma unroll
  for (int i=0;i<8;i++) for (int j=0;j<4;j++) acc[i][j] = (f32x4){0.f,0.f,0.f,0.f};
  for (int st = 0; st < 16; st++){
    int sb = sstart + st*64;
    __syncthreads();
    #pragma unroll
    for (int i = 0; i < 4; i++){
      int c = t + i*512;
      int s = c >> 5, db = (c & 31)*16;
      const ushortt* src = U16 + (size_t)(sb+s)*256 + ((db ^ (((s>>3)&7)<<4))>>1);
      gload16(src, Us + c*8);
    }
    __syncthreads();
    #pragma unroll
    for (int kk = 0; kk < 2; kk++){
      bf16x8 af[8];
      #pragma unroll
      for (int ci = 0; ci < 8; ci++){
        int c1 = wm*128 + ci*16 + lr;
        bf16x8 a;
        #pragma unroll
        for (int e = 0; e < 8; e++){
          int s = kk*32 + g4*8 + e;
          a[e] = (short)*(const ushortt*)((const char*)Us + s*512 + ((c1*2) ^ (((s>>3)&7)<<4)));
        }
        af[ci] = a;
      }
      #pragma unroll
      for (int cj = 0; cj < 4; cj++){
        int c2 = wn*64 + cj*16 + lr;
        bf16x8 bfr;
        #pragma unroll
        for (int e = 0; e < 8; e++){
          int s = kk*32 + g4*8 + e;
          bfr[e] = (short)*(const ushortt*)((const char*)Us + s*512 + ((c2*2) ^ (((s>>3)&7)<<4)));
        }
        #pragma unroll
        for (int ci = 0; ci < 8; ci++)
          acc[ci][cj] = __builtin_amdgcn_mfma_f32_16x16x32_bf16(af[ci], bfr, acc[ci][cj], 0,0,0);
      }
    }
  }
  #pragma unroll
  for (int ci = 0; ci < 8; ci++){
    #pragma unroll
    for (int cj = 0; cj < 4; cj++){
      int c2 = wn*64 + cj*16 + lr;
      #pragma unroll
      for (int r = 0; r < 4; r++){
        int c1 = wm*128 + ci*16 + g4*4 + r;
        atomicAdd(&Mm[(size_t)c1*256 + c2], acc[ci][cj][r]);
      }
    }
  }
}

// ---------------- fold attn BN into w1R (bf16, row-major [1024][256]) + b1eff2 ----------------
__global__ __launch_bounds__(256) void bn2_final(
    const float* __restrict__ Mm, const float* __restrict__ mu_sum,
    const float* __restrict__ aw1,
    const float* __restrict__ ag, const float* __restrict__ abeta,
    ushortt* __restrict__ w1R, float* __restrict__ b1eff2)
{
  __shared__ float wrow[256];
  __shared__ float red[8];
  __shared__ float s2s;
  int t = threadIdx.x;
  int ch = blockIdx.x;
  wrow[t] = aw1[(size_t)ch*256 + t];
  __syncthreads();
  float colacc = 0.f;
  for (int r = 0; r < 256; r++) colacc += wrow[r] * Mm[(size_t)r*256 + t];
  float inv = 1.0f/(float)NSAMP;
  float qpart = colacc * wrow[t] * inv;
  float dpart = wrow[t] * mu_sum[t] * inv;
  for (int off=32; off; off>>=1){ qpart += __shfl_xor(qpart, off); dpart += __shfl_xor(dpart, off); }
  if ((t&63)==0){ red[t>>6] = qpart; red[4 + (t>>6)] = dpart; }
  __syncthreads();
  if (t == 0){
    float quad = red[0]+red[1]+red[2]+red[3];
    float dot  = red[4]+red[5]+red[6]+red[7];
    float var = quad - dot*dot;
    float s2 = ag[ch] * rsqrtf(var + 1e-5f);
    b1eff2[ch] = abeta[ch] - dot*s2;
    s2s = s2;
  }
  __syncthreads();
  w1R[(size_t)ch*256 + t] = f2bf(wrow[t]*s2s);
}

// ---------------- GEMM1: H = relu(U16c @ W1^T + b) ; [chunk x 1024] bf16 ----------------
// BM=128, BN=256, BK=64; 512 threads = 8 waves (2M x 4N), wave tile 64x64
// grid: (chunk/128, 4)
__global__ __launch_bounds__(512) void gemm1_kernel(
    const ushortt* __restrict__ U16c, const ushortt* __restrict__ w1R,
    const float* __restrict__ b1eff2, ushortt* __restrict__ H)
{
  __shared__ ushortt As[128*64];   // 16 KB
  __shared__ ushortt Bs[256*64];   // 32 KB
  int t = threadIdx.x;
  int w = t >> 6, l = t & 63;
  int lr = l & 15, g4 = l >> 4;
  int wm = w >> 2, wn = w & 3;
  int s0 = blockIdx.x*128, n0 = blockIdx.y*256;

  f32x4 acc[4][4];
  #pragma unroll
  for (int i=0;i<4;i++) for (int j=0;j<4;j++) acc[i][j] = (f32x4){0.f,0.f,0.f,0.f};

  for (int kt = 0; kt < 4; kt++){
    int k0 = kt*64;
    __syncthreads();
    #pragma unroll
    for (int i = 0; i < 2; i++){
      int c = t + i*512;
      int r = c >> 3, db = (c & 7)*16;
      const ushortt* src = U16c + (size_t)(s0+r)*256 + k0 + ((db ^ ((r&7)<<4))>>1);
      gload16(src, As + c*8);
    }
    #pragma unroll
    for (int i = 0; i < 4; i++){
      int c = t + i*512;
      int r = c >> 3, db = (c & 7)*16;
      const ushortt* src = w1R + (size_t)(n0+r)*256 + k0 + ((db ^ ((r&7)<<4))>>1);
      gload16(src, Bs + c*8);
    }
    __syncthreads();
    #pragma unroll
    for (int kk = 0; kk < 2; kk++){
      int kb = kk*64 + g4*16;
      bf16x8 af[4];
      #pragma unroll
      for (int mi = 0; mi < 4; mi++){
        int row = wm*64 + mi*16 + lr;
        af[mi] = *(const bf16x8*)((const char*)As + row*128 + (kb ^ ((row&7)<<4)));
      }
      #pragma unroll
      for (int ni = 0; ni < 4; ni++){
        int row = wn*64 + ni*16 + lr;
        bf16x8 bfr = *(const bf16x8*)((const char*)Bs + row*128 + (kb ^ ((row&7)<<4)));
        #pragma unroll
        for (int mi = 0; mi < 4; mi++)
          acc[mi][ni] = __builtin_amdgcn_mfma_f32_16x16x32_bf16(af[mi], bfr, acc[mi][ni], 0,0,0);
      }
    }
  }
  #pragma unroll
  for (int ni = 0; ni < 4; ni++){
    int col = n0 + wn*64 + ni*16 + lr;
    float bias = b1eff2[col];
    #pragma unroll
    for (int mi = 0; mi < 4; mi++){
      int rbase = s0 + wm*64 + mi*16 + g4*4;
      #pragma unroll
      for (int r = 0; r < 4; r++){
        float v = acc[mi][ni][r] + bias;
        v = v > 0.f ? v : 0.f;
        H[(size_t)(rbase+r)*1024 + col] = f2bf(v);
      }
    }
  }
}

// ---------------- GEMM2: logits = H @ W2^T ; fused softmax + aggregation ----------------
// BM=128, BN=256(full D), BK=64; 512 threads = 8 waves (2M x 4N); grid: chunk/128
__global__ __launch_bounds__(512) void gemm2_kernel(
    const ushortt* __restrict__ H, const ushortt* __restrict__ w2R,
    const float* __restrict__ ab2, const int* __restrict__ idx,
    const float* __restrict__ U, const float* __restrict__ qT,
    const float* __restrict__ kT, const float* __restrict__ vT,
    float* __restrict__ aggT, int s_off)
{
  __shared__ ushortt As[128*64];
  __shared__ ushortt Bs[256*64];
  int t = threadIdx.x;
  int w = t >> 6, l = t & 63;
  int lr = l & 15, g4 = l >> 4;
  int wm = w >> 2, wn = w & 3;
  int blk = blockIdx.x;
  int s0 = blk*128;               // relative (H rows)

  f32x4 acc[4][4];
  #pragma unroll
  for (int i=0;i<4;i++) for (int j=0;j<4;j++) acc[i][j] = (f32x4){0.f,0.f,0.f,0.f};

  for (int kt = 0; kt < 16; kt++){
    int k0 = kt*64;
    __syncthreads();
    #pragma unroll
    for (int i = 0; i < 2; i++){
      int c = t + i*512;
      int r = c >> 3, db = (c & 7)*16;
      const ushortt* src = H + (size_t)(s0+r)*1024 + k0 + ((db ^ ((r&7)<<4))>>1);
      gload16(src, As + c*8);
    }
    #pragma unroll
    for (int i = 0; i < 4; i++){
      int c = t + i*512;
      int r = c >> 3, db = (c & 7)*16;
      const ushortt* src = w2R + (size_t)r*1024 + k0 + ((db ^ ((r&7)<<4))>>1);
      gload16(src, Bs + c*8);
    }
    __syncthreads();
    #pragma unroll
    for (int kk = 0; kk < 2; kk++){
      int kb = kk*64 + g4*16;
      bf16x8 af[4];
      #pragma unroll
      for (int mi = 0; mi < 4; mi++){
        int row = wm*64 + mi*16 + lr;
        af[mi] = *(const bf16x8*)((const char*)As + row*128 + (kb ^ ((row&7)<<4)));
      }
      #pragma unroll
      for (int ni = 0; ni < 4; ni++){
        int row = wn*64 + ni*16 + lr;
        bf16x8 bfr = *(const bf16x8*)((const char*)Bs + row*128 + (kb ^ ((row&7)<<4)));
        #pragma unroll
        for (int mi = 0; mi < 4; mi++)
          acc[mi][ni] = __builtin_amdgcn_mfma_f32_16x16x32_bf16(af[mi], bfr, acc[mi][ni], 0,0,0);
      }
    }
  }
  // epilogue: per point (16 rows) softmax over k + aggregation (global sample = s_off + ...)
  int ptbase = s_off >> 4;
  #pragma unroll
  for (int mi = 0; mi < 4; mi++){
    int pt = ptbase + blk*8 + wm*4 + mi;
    int b = pt >> 11;
    int sbase = pt*16;
    int jr[4];
    #pragma unroll
    for (int r = 0; r < 4; r++) jr[r] = idx[sbase + g4*4 + r];
    #pragma unroll
    for (int ni = 0; ni < 4; ni++){
      int d = wn*64 + ni*16 + lr;
      float bias = ab2[d];
      float lg[4];
      #pragma unroll
      for (int r = 0; r < 4; r++) lg[r] = acc[mi][ni][r] + bias;
      float mx = fmaxf(fmaxf(lg[0],lg[1]), fmaxf(lg[2],lg[3]));
      mx = fmaxf(mx, __shfl_xor(mx, 16));
      mx = fmaxf(mx, __shfl_xor(mx, 32));
      float ev[4], ss = 0.f;
      #pragma unroll
      for (int r = 0; r < 4; r++){ ev[r] = __expf(lg[r]-mx); ss += ev[r]; }
      ss += __shfl_xor(ss, 16);
      ss += __shfl_xor(ss, 32);
      float inv = 1.0f/ss;
      float qv = qT[(size_t)pt*256 + d];
      float vv = vT[(size_t)pt*256 + d];
      float pa = 0.f;
      #pragma unroll
      for (int r = 0; r < 4; r++){
        int s = sbase + g4*4 + r;
        float kv = kT[(size_t)(b*Nv + jr[r])*256 + d];
        float uu = U[(size_t)s*256 + d];
        pa += ev[r]*inv*(vv + uu - qv + kv);
      }
      pa += __shfl_xor(pa, 16);
      pa += __shfl_xor(pa, 32);
      if (g4 == 0) aggT[(size_t)pt*256 + d] = pa;
    }
  }
}

// ---------------- final: out = end_w @ agg + end_b + value ----------------
__global__ __launch_bounds__(256) void final_kernel(
    const float* __restrict__ aggT, const float* __restrict__ endwT,
    const float* __restrict__ endb, const float* __restrict__ value,
    float* __restrict__ out)
{
  __shared__ float ags[32*257];
  int t = threadIdx.x;
  int tile = blockIdx.x & 63, b = blockIdx.x >> 6;
  int n0 = tile*32;
  for (int e = t; e < 32*256; e += 256){
    int nn = e >> 8, d = e & 255;
    ags[nn*257 + d] = aggT[(size_t)(b*Nv + n0 + nn)*256 + d];
  }
  __syncthreads();
  int cg = t >> 2, ng = t & 3;
  int co0 = cg*2, nb = ng*8;
  float acc[2][8];
  for (int i=0;i<2;i++){ float bb = endb[co0+i]; for (int j=0;j<8;j++) acc[i][j]=bb; }
  for (int d = 0; d < 256; d++){
    float w0 = endwT[d*128 + co0], w1 = endwT[d*128 + co0 + 1];
    #pragma unroll
    for (int j=0;j<8;j++){
      float av = ags[(nb+j)*257 + d];
      acc[0][j] += w0*av; acc[1][j] += w1*av;
    }
  }
  for (int i=0;i<2;i++){
    for (int j=0;j<8;j++){
      size_t o = (size_t)(b*128 + co0 + i)*Nv + n0 + nb + j;
      out[o] = acc[i][j] + value[o];
    }
  }
}

extern "C" void kernel_launch(void* const* d_in, const int* in_sizes, int n_in,
                              void* d_out, int out_size, void* d_ws, size_t ws_size,
                              hipStream_t stream)
{
  (void)in_sizes; (void)n_in; (void)out_size;
  const float* pos   = (const float*)d_in[0];
  const float* key   = (const float*)d_in[1];
  const float* query = (const float*)d_in[2];
  const float* mw1   = (const float*)d_in[3];
  const float* mb1   = (const float*)d_in[4];
  const float* mw2   = (const float*)d_in[5];
  const float* mb2   = (const float*)d_in[6];
  const float* mwsc  = (const float*)d_in[7];
  const float* mbsc  = (const float*)d_in[8];
  const float* wk    = (const float*)d_in[9];
  const float* bk    = (const float*)d_in[10];
  const float* wq    = (const float*)d_in[11];
  const float* bq    = (const float*)d_in[12];
  const float* wv    = (const float*)d_in[13];
  const float* bv    = (const float*)d_in[14];
  const float* pw1   = (const float*)d_in[15];
  const float* pg    = (const float*)d_in[17];
  const float* pbeta = (const float*)d_in[18];
  const float* pw2   = (const float*)d_in[19];
  const float* pb2   = (const float*)d_in[20];
  const float* aw1   = (const float*)d_in[21];
  const float* ag    = (const float*)d_in[23];
  const float* abeta = (const float*)d_in[24];
  const float* aw2   = (const float*)d_in[25];
  const float* ab2   = (const float*)d_in[26];
  const float* endw  = (const float*)d_in[27];
  const float* endb  = (const float*)d_in[28];
  float* out = (float*)d_out;

  char* wsb = (char*)d_ws;
  size_t off = 0;
  auto take = [&](size_t bytes)->char*{
    char* p = wsb + off; off += (bytes + 255) & ~(size_t)255; return p;
  };
  float* Mm      = (float*)take(65536*4);   // zeroed (atomic accumulate)
  float* mu_sum  = (float*)take(256*4);     // zeroed
  float* rstat   = (float*)take(12*4);      // zeroed
  size_t zero_bytes = off;
  float* w1eff   = (float*)take(192*4);
  float* b1eff   = (float*)take(64*4);
  float* b1eff2  = (float*)take(1024*4);
  float* value   = (float*)take((size_t)524288*4);
  float* qT      = (float*)take((size_t)1048576*4);
  float* kT      = (float*)take((size_t)1048576*4);
  float* vT      = (float*)take((size_t)1048576*4);
  float* aggT    = (float*)take((size_t)1048576*4);
  float* wkT     = (float*)take(32768*4);
  float* wqT     = (float*)take(32768*4);
  float* wvT     = (float*)take(32768*4);
  float* endwT   = (float*)take(32768*4);
  float* mw1T    = (float*)take(32768*4);
  float* mw2T    = (float*)take(16384*4);
  float* mwscT   = (float*)take(32768*4);
  int*   idxb    = (int*)take(65536*4);
  float* U       = (float*)take((size_t)16777216*4);   // f32 (exact recovery)
  ushortt* U16   = (ushortt*)take((size_t)16777216*2); // bf16 (MFMA A operand)
  ushortt* w1R   = (ushortt*)take((size_t)262144*2);
  ushortt* w2R   = (ushortt*)take((size_t)262144*2);
  ushortt* w2posT= (ushortt*)take(16384*2);

  // H gets whatever is left; chunk the sample dim to fit.
  size_t avail = (ws_size > off) ? (ws_size - off) : 0;
  int nch = 1;
  while (nch < 64 && ((size_t)(NSAMP/nch))*1024*2 > avail) nch <<= 1;
  int chunk = NSAMP / nch;          // >= 1024, multiple of 128
  ushortt* H = (ushortt*)(wsb + off);

  hipMemsetAsync(d_ws, 0, zero_bytes, stream);
  prep_weights<<<512,256,0,stream>>>(wk,wq,wv,endw,mw1,mw2,mwsc,aw2,pw2,
                                     wkT,wqT,wvT,endwT,mw1T,mw2T,mwscT,w2R,w2posT);
  mlpres_kernel<<<128,256,0,stream>>>(key,query,mw1T,mb1,mw2T,mb2,mwscT,mbsc,value);
  proj_kernel<<<128,256,0,stream>>>(query,wqT,bq,qT);
  proj_kernel<<<128,256,0,stream>>>(key,wkT,bk,kT);
  proj_kernel<<<128,256,0,stream>>>(value,wvT,bv,vT);
  knn_kernel<<<1024,256,0,stream>>>(pos,idxb);
  bn1_stats<<<64,256,0,stream>>>(pos,idxb,rstat);
  bn1_final<<<1,64,0,stream>>>(rstat,pw1,pg,pbeta,w1eff,b1eff);
  passA_kernel<<<1024,256,0,stream>>>(pos,idxb,qT,kT,w1eff,b1eff,w2posT,pb2,U,U16,mu_sum);
  mm_kernel<<<64,512,0,stream>>>(U16,Mm);
  bn2_final<<<1024,256,0,stream>>>(Mm,mu_sum,aw1,ag,abeta,w1R,b1eff2);
  for (int cc = 0; cc < nch; cc++){
    int s_off = cc*chunk;
    gemm1_kernel<<<dim3(chunk/128, 4),512,0,stream>>>(U16 + (size_t)s_off*256, w1R, b1eff2, H);
    gemm2_kernel<<<chunk/128,512,0,stream>>>(H, w2R, ab2, idxb, U, qT, kT, vT, aggT, s_off);
  }
  final_kernel<<<128,256,0,stream>>>(aggT,endwT,endb,value,out);
}

// Round 6
// 437.808 us; speedup vs baseline: 3.3667x; 1.1555x over previous
//
#include <hip/hip_runtime.h>
#include <hip/hip_bf16.h>
#include <math.h>

#define Bv 2
#define Nv 2048
#define Cv 128
#define Dv 256
#define PHv 64
#define AHv 1024
#define Kv 16
#define NSAMP (Bv*Nv*Kv)   // 65536

typedef unsigned short ushortt;
typedef __attribute__((ext_vector_type(8))) short bf16x8;
typedef __attribute__((ext_vector_type(4))) float f32x4;

__device__ __forceinline__ float bf2f(ushortt h){
  union { unsigned int u; float f; } v; v.u = ((unsigned int)h) << 16; return v.f;
}
__device__ __forceinline__ ushortt f2bf(float f){
  union { unsigned int u; float f; } v; v.f = f;
  unsigned int r = v.u + 0x7FFFu + ((v.u >> 16) & 1u);
  return (ushortt)(r >> 16);
}

__device__ __forceinline__ void gload16(const void* g, void* l){
  __builtin_amdgcn_global_load_lds(
      (const __attribute__((address_space(1))) unsigned int*)g,
      (__attribute__((address_space(3))) unsigned int*)l, 16, 0, 0);
}

// ---------------- weight transposes / casts ----------------
__global__ __launch_bounds__(256) void prep_weights(
    const float* __restrict__ wk, const float* __restrict__ wq,
    const float* __restrict__ wv, const float* __restrict__ endw,
    const float* __restrict__ mw1, const float* __restrict__ mw2,
    const float* __restrict__ mwsc, const float* __restrict__ aw2,
    const float* __restrict__ pw2,
    float* __restrict__ wkT, float* __restrict__ wqT, float* __restrict__ wvT,
    float* __restrict__ endwT, float* __restrict__ mw1T, float* __restrict__ mw2T,
    float* __restrict__ mwscT, ushortt* __restrict__ w2R, ushortt* __restrict__ w2posT)
{
  int tid = blockIdx.x*256 + threadIdx.x;
  int stride = gridDim.x*256;
  for (int i = tid; i < 256*128; i += stride){ int d = i>>7, c = i&127;
    wkT[c*256+d] = wk[i]; wqT[c*256+d] = wq[i]; wvT[c*256+d] = wv[i]; }
  for (int i = tid; i < 128*256; i += stride){ int co = i>>8, d = i&255; endwT[d*128+co] = endw[i]; }
  for (int i = tid; i < 128*256; i += stride){ int h = i>>8, c = i&255; mw1T[c*128+h] = mw1[i]; }
  for (int i = tid; i < 128*128; i += stride){ int o = i>>7, c = i&127; mw2T[c*128+o] = mw2[i]; }
  for (int i = tid; i < 128*256; i += stride){ int o = i>>8, c = i&255; mwscT[c*128+o] = mwsc[i]; }
  for (int i = tid; i < 256*1024; i += stride) w2R[i] = f2bf(aw2[i]);
  for (int i = tid; i < 256*64; i += stride){ int d = i>>6, c = i&63; w2posT[c*256+d] = f2bf(pw2[i]); }
}

// ---------------- value = MLP_Res(cat(key,query)) ----------------
__global__ __launch_bounds__(256) void mlpres_kernel(
    const float* __restrict__ key, const float* __restrict__ query,
    const float* __restrict__ mw1T, const float* __restrict__ b1,
    const float* __restrict__ mw2T, const float* __restrict__ b2,
    const float* __restrict__ mwscT, const float* __restrict__ bsc,
    float* __restrict__ value)
{
  __shared__ float xs[256*32];
  __shared__ float hs[128*32];
  int t = threadIdx.x;
  int tile = blockIdx.x & 63, b = blockIdx.x >> 6;
  int n0 = tile*32;
  for (int e = t; e < 256*32; e += 256){
    int c = e >> 5, nn = e & 31;
    xs[e] = (c < 128) ? key[(size_t)(b*128+c)*Nv + n0+nn]
                      : query[(size_t)(b*128+(c-128))*Nv + n0+nn];
  }
  __syncthreads();
  int hg = t >> 2, ng = t & 3;
  int hd0 = hg*2, nb = ng*8;
  float acc[2][8];
  for (int i=0;i<2;i++){ float bb = b1[hd0+i]; for(int j=0;j<8;j++) acc[i][j]=bb; }
  for (int c = 0; c < 256; c++){
    float w0 = mw1T[c*128 + hd0], w1 = mw1T[c*128 + hd0+1];
    const float* xr = &xs[c*32 + nb];
    #pragma unroll
    for (int j=0;j<8;j++){ float xv = xr[j]; acc[0][j] += w0*xv; acc[1][j] += w1*xv; }
  }
  for (int i=0;i<2;i++) for (int j=0;j<8;j++){
    float v = acc[i][j]; hs[(hd0+i)*32 + nb + j] = v > 0.f ? v : 0.f;
  }
  __syncthreads();
  float out[2][8];
  for (int i=0;i<2;i++){ float bb = b2[hd0+i] + bsc[hd0+i]; for(int j=0;j<8;j++) out[i][j]=bb; }
  for (int c = 0; c < 128; c++){
    float w0 = mw2T[c*128 + hd0], w1 = mw2T[c*128 + hd0+1];
    const float* hr = &hs[c*32 + nb];
    #pragma unroll
    for (int j=0;j<8;j++){ float hv = hr[j]; out[0][j] += w0*hv; out[1][j] += w1*hv; }
  }
  for (int c = 0; c < 256; c++){
    float w0 = mwscT[c*128 + hd0], w1 = mwscT[c*128 + hd0+1];
    const float* xr = &xs[c*32 + nb];
    #pragma unroll
    for (int j=0;j<8;j++){ float xv = xr[j]; out[0][j] += w0*xv; out[1][j] += w1*xv; }
  }
  for (int i=0;i<2;i++) for (int j=0;j<8;j++)
    value[(size_t)(b*128 + hd0+i)*Nv + n0 + nb + j] = out[i][j];
}

// ---------------- conv1d (Cin=128 -> Dout=256), output transposed (B,N,256) ----------------
__global__ __launch_bounds__(256) void proj_kernel(
    const float* __restrict__ x, const float* __restrict__ wT,
    const float* __restrict__ bias, float* __restrict__ outT)
{
  __shared__ float xs[128*32];
  int t = threadIdx.x;
  int tile = blockIdx.x & 63, b = blockIdx.x >> 6;
  int n0 = tile*32;
  for (int e = t; e < 128*32; e += 256){
    int c = e >> 5, nn = e & 31;
    xs[e] = x[(size_t)(b*128+c)*Nv + n0+nn];
  }
  __syncthreads();
  int dg = t >> 2, ng = t & 3;
  int d0 = dg*4, nb = ng*8;
  float acc[4][8];
  for (int i=0;i<4;i++){ float bb = bias[d0+i]; for(int j=0;j<8;j++) acc[i][j]=bb; }
  for (int c = 0; c < 128; c++){
    float w0 = wT[c*256+d0], w1 = wT[c*256+d0+1], w2 = wT[c*256+d0+2], w3 = wT[c*256+d0+3];
    const float* xr = &xs[c*32+nb];
    #pragma unroll
    for (int j=0;j<8;j++){
      float xv = xr[j];
      acc[0][j] += w0*xv; acc[1][j] += w1*xv; acc[2][j] += w2*xv; acc[3][j] += w3*xv;
    }
  }
  for (int j=0;j<8;j++){
    int n = n0+nb+j;
    float4 v = make_float4(acc[0][j],acc[1][j],acc[2][j],acc[3][j]);
    *(float4*)&outT[(size_t)(b*Nv+n)*256 + d0] = v;
  }
}

// ---------------- KNN: wave-per-point, pure shfl ----------------
__global__ __launch_bounds__(256) void knn_kernel(const float* __restrict__ pos, int* __restrict__ idx)
{
  int t = threadIdx.x;
  int w = t >> 6, l = t & 63;
  int p = blockIdx.x*4 + w;
  int i = p & (Nv-1), b = p >> 11;
  const float* px = pos + (size_t)b*3*Nv;
  float pix = px[i], piy = px[Nv+i], piz = px[2*Nv+i];
  float sqi = pix*pix + piy*piy + piz*piz;
  float ds[32];
  #pragma unroll
  for (int jj = 0; jj < 32; jj++){
    int j = jj*64 + l;
    float qx = px[j], qy = px[Nv+j], qz = px[2*Nv+j];
    float sqj = qx*qx + qy*qy + qz*qz;
    float dot = pix*qx + piy*qy + piz*qz;
    ds[jj] = (sqi + sqj) - 2.0f*dot;
  }
  #pragma unroll 1
  for (int it = 0; it < 16; it++){
    float bv = 3.4e38f; int bj = 0x7FFFFFFF;
    #pragma unroll
    for (int jj = 0; jj < 32; jj++){
      int j = jj*64 + l;
      bool c = ds[jj] < bv;
      bv = c ? ds[jj] : bv;
      bj = c ? j : bj;
    }
    #pragma unroll
    for (int off = 32; off; off >>= 1){
      float ov = __shfl_xor(bv, off);
      int oj = __shfl_xor(bj, off);
      if (ov < bv || (ov == bv && oj < bj)){ bv = ov; bj = oj; }
    }
    if (l == 0) idx[(size_t)p*16 + it] = bj;
    #pragma unroll
    for (int jj = 0; jj < 32; jj++){
      if (jj*64 + l == bj) ds[jj] = 3.4e38f;
    }
  }
}

// ---------------- pos-BN stats ----------------
__global__ __launch_bounds__(256) void bn1_stats(const float* __restrict__ pos,
    const int* __restrict__ idx, float* __restrict__ rstat)
{
  int tid = blockIdx.x*256 + threadIdx.x;
  int stride = gridDim.x*256;
  float s[9] = {0,0,0,0,0,0,0,0,0};
  for (int e = tid; e < NSAMP; e += stride){
    int b = e >> 15;
    int rem = e & 32767;
    int n = rem >> 4, k = rem & 15;
    int j = idx[(size_t)(b*Nv+n)*16 + k];
    const float* px = pos + (size_t)b*3*Nv;
    float rx = px[n]-px[j], ry = px[Nv+n]-px[Nv+j], rz = px[2*Nv+n]-px[2*Nv+j];
    s[0]+=rx; s[1]+=ry; s[2]+=rz;
    s[3]+=rx*rx; s[4]+=rx*ry; s[5]+=rx*rz; s[6]+=ry*ry; s[7]+=ry*rz; s[8]+=rz*rz;
  }
  for (int off=32; off; off>>=1)
    for (int q=0;q<9;q++) s[q] += __shfl_xor(s[q], off);
  if ((threadIdx.x & 63) == 0)
    for (int q=0;q<9;q++) atomicAdd(&rstat[q], s[q]);
}

// ---------------- fold pos BN ----------------
__global__ void bn1_final(const float* __restrict__ rstat,
    const float* __restrict__ pw1,
    const float* __restrict__ pg, const float* __restrict__ pbeta,
    float* __restrict__ w1eff, float* __restrict__ b1eff)
{
  int c = threadIdx.x; // 64
  float inv = 1.0f/(float)NSAMP;
  float mux = rstat[0]*inv, muy = rstat[1]*inv, muz = rstat[2]*inv;
  float xx = rstat[3]*inv, xy = rstat[4]*inv, xz = rstat[5]*inv;
  float yy = rstat[6]*inv, yz = rstat[7]*inv, zz = rstat[8]*inv;
  float w0 = pw1[c*3], w1 = pw1[c*3+1], w2 = pw1[c*3+2];
  float dot = w0*mux + w1*muy + w2*muz;
  float quad = w0*w0*xx + w1*w1*yy + w2*w2*zz + 2.f*(w0*w1*xy + w0*w2*xz + w1*w2*yz);
  float var = quad - dot*dot;
  float s = pg[c] * rsqrtf(var + 1e-5f);
  w1eff[c*3]   = w0*s;
  w1eff[c*3+1] = w1*s;
  w1eff[c*3+2] = w2*s;
  b1eff[c] = pbeta[c] - dot*s;
}

// ---------------- pass A: u -> U16 (bf16), pos_emb -> pe16 (bf16), mu sums ----------------
#define PTSA 4
__global__ __launch_bounds__(256) void passA_kernel(
    const float* __restrict__ pos, const int* __restrict__ idx,
    const float* __restrict__ qT, const float* __restrict__ kT,
    const float* __restrict__ w1eff, const float* __restrict__ b1eff,
    const ushortt* __restrict__ w2posT, const float* __restrict__ pb2,
    ushortt* __restrict__ U16, ushortt* __restrict__ pe16, float* __restrict__ mu_sum)
{
  __shared__ float hs[64*16];
  __shared__ float rs[3*16];
  __shared__ int idxs[16];
  __shared__ float mpart[256][4];
  int t = threadIdx.x;
  int dg = t >> 2, kg = t & 3;
  int d0 = dg*4, ks = kg*4;
  float msum[4] = {0,0,0,0};
  __align__(16) float pb2v[4];
  *(float4*)pb2v = *(const float4*)&pb2[d0];
  for (int p = 0; p < PTSA; p++){
    int pt = blockIdx.x*PTSA + p;
    int n = pt & (Nv-1), b = pt >> 11;
    if (p) __syncthreads();
    if (t < 16){
      int j = idx[(size_t)pt*16 + t];
      idxs[t] = j;
      const float* px = pos + (size_t)b*3*Nv;
      rs[t]    = px[n]      - px[j];
      rs[16+t] = px[Nv+n]   - px[Nv+j];
      rs[32+t] = px[2*Nv+n] - px[2*Nv+j];
    }
    __syncthreads();
    {
      int c = t & 63, kgr = t >> 6;
      float w0 = w1eff[c*3], w1 = w1eff[c*3+1], w2 = w1eff[c*3+2], bb = b1eff[c];
      #pragma unroll
      for (int kk = 0; kk < 4; kk++){
        int k = kgr*4 + kk;
        float v = bb + w0*rs[k] + w1*rs[16+k] + w2*rs[32+k];
        hs[c*16+k] = v > 0.f ? v : 0.f;
      }
    }
    __syncthreads();
    float pe[4][4];
    for (int i=0;i<4;i++) for(int kk=0;kk<4;kk++) pe[i][kk] = pb2v[i];
    for (int c = 0; c < 64; c++){
      __align__(8) ushortt wraw[4];
      *(uint2*)wraw = *(const uint2*)&w2posT[c*256 + d0];
      __align__(16) float hv[4];
      *(float4*)hv = *(const float4*)&hs[c*16 + ks];
      #pragma unroll
      for (int i=0;i<4;i++){
        float w = bf2f(wraw[i]);
        #pragma unroll
        for (int kk=0;kk<4;kk++) pe[i][kk] += w*hv[kk];
      }
    }
    __align__(16) float qv[4];
    *(float4*)qv = *(const float4*)&qT[(size_t)pt*256 + d0];
    #pragma unroll
    for (int kk = 0; kk < 4; kk++){
      int k = ks + kk;
      int j = idxs[k];
      __align__(16) float kv[4];
      *(float4*)kv = *(const float4*)&kT[(size_t)(b*Nv+j)*256 + d0];
      __align__(8) ushortt hr[4];
      __align__(8) ushortt pr[4];
      #pragma unroll
      for (int i=0;i<4;i++){
        float u = qv[i] - kv[i] + pe[i][kk];
        hr[i] = f2bf(u);
        pr[i] = f2bf(pe[i][kk]);
        msum[i] += u;
      }
      *(uint2*)&U16[((size_t)pt*16 + k)*256 + d0] = *(uint2*)hr;
      *(uint2*)&pe16[((size_t)pt*16 + k)*256 + d0] = *(uint2*)pr;
    }
  }
  for (int i=0;i<4;i++) mpart[t][i] = msum[i];
  __syncthreads();
  {
    int d = t;
    float ssum = 0.f;
    for (int kg2 = 0; kg2 < 4; kg2++) ssum += mpart[(d>>2)*4 + kg2][d&3];
    atomicAdd(&mu_sum[d], ssum);
  }
}

// ---------------- M partials: Mpart[blk] = sum_{s in 256-slice} u u^T (bf16 out) ----------------
// grid 256 blocks, 512 threads = 8 waves (2x4), wave tile 128(c1) x 64(c2)
// LDS: Ut[c][s] bf16, row pitch 128B, swizzle byte_in_row ^= ((c&7)<<4)
__global__ __launch_bounds__(512) void mm_kernel(const ushortt* __restrict__ U16,
                                                 ushortt* __restrict__ Mpart)
{
  __shared__ ushortt Ut[256*64];   // 32 KB
  int t = threadIdx.x;
  int w = t >> 6, l = t & 63;
  int lr = l & 15, g4 = l >> 4;
  int wm = w >> 2, wn = w & 3;
  int c_my = ((w & 3)*64 + l);     // column this thread stages (0..255)
  int sg = w >> 2;                 // 0..1 -> s-half
  int blk = blockIdx.x;
  int sstart = blk*256;

  f32x4 acc[8][4];
  #pragma unroll
  for (int i=0;i<8;i++) for (int j=0;j<4;j++) acc[i][j] = (f32x4){0.f,0.f,0.f,0.f};

  for (int st = 0; st < 4; st++){
    int sb = sstart + st*64;
    __syncthreads();
    // stage: transpose 64 x 256 into Ut
    #pragma unroll
    for (int g = 0; g < 4; g++){
      int s8 = sg*32 + g*8;
      ushortt vals[8];
      #pragma unroll
      for (int e = 0; e < 8; e++)
        vals[e] = U16[(size_t)(sb + s8 + e)*256 + c_my];
      unsigned int p0 = (unsigned int)vals[0] | ((unsigned int)vals[1] << 16);
      unsigned int p1 = (unsigned int)vals[2] | ((unsigned int)vals[3] << 16);
      unsigned int p2 = (unsigned int)vals[4] | ((unsigned int)vals[5] << 16);
      unsigned int p3 = (unsigned int)vals[6] | ((unsigned int)vals[7] << 16);
      uint4 pk = make_uint4(p0,p1,p2,p3);
      *(uint4*)((char*)Ut + c_my*128 + ((s8*2) ^ ((c_my&7)<<4))) = pk;
    }
    __syncthreads();
    #pragma unroll
    for (int kk = 0; kk < 2; kk++){
      int kb = kk*64 + g4*16;
      bf16x8 af[8];
      #pragma unroll
      for (int ci = 0; ci < 8; ci++){
        int row = wm*128 + ci*16 + lr;
        af[ci] = *(const bf16x8*)((const char*)Ut + row*128 + (kb ^ ((row&7)<<4)));
      }
      #pragma unroll
      for (int cj = 0; cj < 4; cj++){
        int row = wn*64 + cj*16 + lr;
        bf16x8 bfr = *(const bf16x8*)((const char*)Ut + row*128 + (kb ^ ((row&7)<<4)));
        #pragma unroll
        for (int ci = 0; ci < 8; ci++)
          acc[ci][cj] = __builtin_amdgcn_mfma_f32_16x16x32_bf16(af[ci], bfr, acc[ci][cj], 0,0,0);
      }
    }
  }
  ushortt* dst = Mpart + (size_t)blk*65536;
  #pragma unroll
  for (int ci = 0; ci < 8; ci++){
    #pragma unroll
    for (int cj = 0; cj < 4; cj++){
      int c2 = wn*64 + cj*16 + lr;
      #pragma unroll
      for (int r = 0; r < 4; r++){
        int c1 = wm*128 + ci*16 + g4*4 + r;
        dst[(size_t)c1*256 + c2] = f2bf(acc[ci][cj][r]);
      }
    }
  }
}

__global__ __launch_bounds__(256) void mreduce_kernel(const ushortt* __restrict__ Mpart,
                                                      float* __restrict__ Mm)
{
  int i = blockIdx.x*256 + threadIdx.x;
  float s = 0.f;
  for (int p = 0; p < 256; p++) s += bf2f(Mpart[(size_t)p*65536 + i]);
  Mm[i] = s;
}

// ---------------- fold attn BN into w1R (bf16, row-major [1024][256]) + b1eff2 ----------------
__global__ __launch_bounds__(256) void bn2_final(
    const float* __restrict__ Mm, const float* __restrict__ mu_sum,
    const float* __restrict__ aw1,
    const float* __restrict__ ag, const float* __restrict__ abeta,
    ushortt* __restrict__ w1R, float* __restrict__ b1eff2)
{
  __shared__ float wrow[256];
  __shared__ float red[8];
  __shared__ float s2s;
  int t = threadIdx.x;
  int ch = blockIdx.x;
  wrow[t] = aw1[(size_t)ch*256 + t];
  __syncthreads();
  float colacc = 0.f;
  for (int r = 0; r < 256; r++) colacc += wrow[r] * Mm[(size_t)r*256 + t];
  float inv = 1.0f/(float)NSAMP;
  float qpart = colacc * wrow[t] * inv;
  float dpart = wrow[t] * mu_sum[t] * inv;
  for (int off=32; off; off>>=1){ qpart += __shfl_xor(qpart, off); dpart += __shfl_xor(dpart, off); }
  if ((t&63)==0){ red[t>>6] = qpart; red[4 + (t>>6)] = dpart; }
  __syncthreads();
  if (t == 0){
    float quad = red[0]+red[1]+red[2]+red[3];
    float dot  = red[4]+red[5]+red[6]+red[7];
    float var = quad - dot*dot;
    float s2 = ag[ch] * rsqrtf(var + 1e-5f);
    b1eff2[ch] = abeta[ch] - dot*s2;
    s2s = s2;
  }
  __syncthreads();
  w1R[(size_t)ch*256 + t] = f2bf(wrow[t]*s2s);
}

// ---------------- GEMM1: H = relu(U16c @ W1^T + b) ; [chunk x 1024] bf16 ----------------
__global__ __launch_bounds__(512) void gemm1_kernel(
    const ushortt* __restrict__ U16c, const ushortt* __restrict__ w1R,
    const float* __restrict__ b1eff2, ushortt* __restrict__ H)
{
  __shared__ ushortt As[128*64];   // 16 KB
  __shared__ ushortt Bs[256*64];   // 32 KB
  int t = threadIdx.x;
  int w = t >> 6, l = t & 63;
  int lr = l & 15, g4 = l >> 4;
  int wm = w >> 2, wn = w & 3;
  int s0 = blockIdx.x*128, n0 = blockIdx.y*256;

  f32x4 acc[4][4];
  #pragma unroll
  for (int i=0;i<4;i++) for (int j=0;j<4;j++) acc[i][j] = (f32x4){0.f,0.f,0.f,0.f};

  for (int kt = 0; kt < 4; kt++){
    int k0 = kt*64;
    __syncthreads();
    #pragma unroll
    for (int i = 0; i < 2; i++){
      int c = t + i*512;
      int r = c >> 3, db = (c & 7)*16;
      const ushortt* src = U16c + (size_t)(s0+r)*256 + k0 + ((db ^ ((r&7)<<4))>>1);
      gload16(src, As + c*8);
    }
    #pragma unroll
    for (int i = 0; i < 4; i++){
      int c = t + i*512;
      int r = c >> 3, db = (c & 7)*16;
      const ushortt* src = w1R + (size_t)(n0+r)*256 + k0 + ((db ^ ((r&7)<<4))>>1);
      gload16(src, Bs + c*8);
    }
    __syncthreads();
    #pragma unroll
    for (int kk = 0; kk < 2; kk++){
      int kb = kk*64 + g4*16;
      bf16x8 af[4];
      #pragma unroll
      for (int mi = 0; mi < 4; mi++){
        int row = wm*64 + mi*16 + lr;
        af[mi] = *(const bf16x8*)((const char*)As + row*128 + (kb ^ ((row&7)<<4)));
      }
      #pragma unroll
      for (int ni = 0; ni < 4; ni++){
        int row = wn*64 + ni*16 + lr;
        bf16x8 bfr = *(const bf16x8*)((const char*)Bs + row*128 + (kb ^ ((row&7)<<4)));
        #pragma unroll
        for (int mi = 0; mi < 4; mi++)
          acc[mi][ni] = __builtin_amdgcn_mfma_f32_16x16x32_bf16(af[mi], bfr, acc[mi][ni], 0,0,0);
      }
    }
  }
  #pragma unroll
  for (int ni = 0; ni < 4; ni++){
    int col = n0 + wn*64 + ni*16 + lr;
    float bias = b1eff2[col];
    #pragma unroll
    for (int mi = 0; mi < 4; mi++){
      int rbase = s0 + wm*64 + mi*16 + g4*4;
      #pragma unroll
      for (int r = 0; r < 4; r++){
        float v = acc[mi][ni][r] + bias;
        v = v > 0.f ? v : 0.f;
        H[(size_t)(rbase+r)*1024 + col] = f2bf(v);
      }
    }
  }
}

// ---------------- GEMM2: logits = H @ W2^T ; fused softmax + aggregation ----------------
__global__ __launch_bounds__(512) void gemm2_kernel(
    const ushortt* __restrict__ H, const ushortt* __restrict__ w2R,
    const float* __restrict__ ab2, const ushortt* __restrict__ pe16,
    const float* __restrict__ vT, float* __restrict__ aggT, int s_off)
{
  __shared__ ushortt As[128*64];
  __shared__ ushortt Bs[256*64];
  int t = threadIdx.x;
  int w = t >> 6, l = t & 63;
  int lr = l & 15, g4 = l >> 4;
  int wm = w >> 2, wn = w & 3;
  int blk = blockIdx.x;
  int s0 = blk*128;               // relative (H rows)

  f32x4 acc[4][4];
  #pragma unroll
  for (int i=0;i<4;i++) for (int j=0;j<4;j++) acc[i][j] = (f32x4){0.f,0.f,0.f,0.f};

  for (int kt = 0; kt < 16; kt++){
    int k0 = kt*64;
    __syncthreads();
    #pragma unroll
    for (int i = 0; i < 2; i++){
      int c = t + i*512;
      int r = c >> 3, db = (c & 7)*16;
      const ushortt* src = H + (size_t)(s0+r)*1024 + k0 + ((db ^ ((r&7)<<4))>>1);
      gload16(src, As + c*8);
    }
    #pragma unroll
    for (int i = 0; i < 4; i++){
      int c = t + i*512;
      int r = c >> 3, db = (c & 7)*16;
      const ushortt* src = w2R + (size_t)r*1024 + k0 + ((db ^ ((r&7)<<4))>>1);
      gload16(src, Bs + c*8);
    }
    __syncthreads();
    #pragma unroll
    for (int kk = 0; kk < 2; kk++){
      int kb = kk*64 + g4*16;
      bf16x8 af[4];
      #pragma unroll
      for (int mi = 0; mi < 4; mi++){
        int row = wm*64 + mi*16 + lr;
        af[mi] = *(const bf16x8*)((const char*)As + row*128 + (kb ^ ((row&7)<<4)));
      }
      #pragma unroll
      for (int ni = 0; ni < 4; ni++){
        int row = wn*64 + ni*16 + lr;
        bf16x8 bfr = *(const bf16x8*)((const char*)Bs + row*128 + (kb ^ ((row&7)<<4)));
        #pragma unroll
        for (int mi = 0; mi < 4; mi++)
          acc[mi][ni] = __builtin_amdgcn_mfma_f32_16x16x32_bf16(af[mi], bfr, acc[mi][ni], 0,0,0);
      }
    }
  }
  // epilogue: per point (16 rows) softmax over k + aggregation
  int ptbase = s_off >> 4;
  #pragma unroll
  for (int mi = 0; mi < 4; mi++){
    int pt = ptbase + blk*8 + wm*4 + mi;
    int sbase = pt*16;
    #pragma unroll
    for (int ni = 0; ni < 4; ni++){
      int d = wn*64 + ni*16 + lr;
      float bias = ab2[d];
      float lg[4];
      #pragma unroll
      for (int r = 0; r < 4; r++) lg[r] = acc[mi][ni][r] + bias;
      float mx = fmaxf(fmaxf(lg[0],lg[1]), fmaxf(lg[2],lg[3]));
      mx = fmaxf(mx, __shfl_xor(mx, 16));
      mx = fmaxf(mx, __shfl_xor(mx, 32));
      float ev[4], ss = 0.f;
      #pragma unroll
      for (int r = 0; r < 4; r++){ ev[r] = __expf(lg[r]-mx); ss += ev[r]; }
      ss += __shfl_xor(ss, 16);
      ss += __shfl_xor(ss, 32);
      float inv = 1.0f/ss;
      float vv = vT[(size_t)pt*256 + d];
      float pa = 0.f;
      #pragma unroll
      for (int r = 0; r < 4; r++){
        int s = sbase + g4*4 + r;
        float pe = bf2f(pe16[(size_t)s*256 + d]);
        pa += ev[r]*inv*(vv + pe);
      }
      pa += __shfl_xor(pa, 16);
      pa += __shfl_xor(pa, 32);
      if (g4 == 0) aggT[(size_t)pt*256 + d] = pa;
    }
  }
}

// ---------------- final: out = end_w @ agg + end_b + value ----------------
__global__ __launch_bounds__(256) void final_kernel(
    const float* __restrict__ aggT, const float* __restrict__ endwT,
    const float* __restrict__ endb, const float* __restrict__ value,
    float* __restrict__ out)
{
  __shared__ float ags[32*257];
  int t = threadIdx.x;
  int tile = blockIdx.x & 63, b = blockIdx.x >> 6;
  int n0 = tile*32;
  for (int e = t; e < 32*256; e += 256){
    int nn = e >> 8, d = e & 255;
    ags[nn*257 + d] = aggT[(size_t)(b*Nv + n0 + nn)*256 + d];
  }
  __syncthreads();
  int cg = t >> 2, ng = t & 3;
  int co0 = cg*2, nb = ng*8;
  float acc[2][8];
  for (int i=0;i<2;i++){ float bb = endb[co0+i]; for (int j=0;j<8;j++) acc[i][j]=bb; }
  for (int d = 0; d < 256; d++){
    float w0 = endwT[d*128 + co0], w1 = endwT[d*128 + co0 + 1];
    #pragma unroll
    for (int j=0;j<8;j++){
      float av = ags[(nb+j)*257 + d];
      acc[0][j] += w0*av; acc[1][j] += w1*av;
    }
  }
  for (int i=0;i<2;i++){
    for (int j=0;j<8;j++){
      size_t o = (size_t)(b*128 + co0 + i)*Nv + n0 + nb + j;
      out[o] = acc[i][j] + value[o];
    }
  }
}

extern "C" void kernel_launch(void* const* d_in, const int* in_sizes, int n_in,
                              void* d_out, int out_size, void* d_ws, size_t ws_size,
                              hipStream_t stream)
{
  (void)in_sizes; (void)n_in; (void)out_size;
  const float* pos   = (const float*)d_in[0];
  const float* key   = (const float*)d_in[1];
  const float* query = (const float*)d_in[2];
  const float* mw1   = (const float*)d_in[3];
  const float* mb1   = (const float*)d_in[4];
  const float* mw2   = (const float*)d_in[5];
  const float* mb2   = (const float*)d_in[6];
  const float* mwsc  = (const float*)d_in[7];
  const float* mbsc  = (const float*)d_in[8];
  const float* wk    = (const float*)d_in[9];
  const float* bk    = (const float*)d_in[10];
  const float* wq    = (const float*)d_in[11];
  const float* bq    = (const float*)d_in[12];
  const float* wv    = (const float*)d_in[13];
  const float* bv    = (const float*)d_in[14];
  const float* pw1   = (const float*)d_in[15];
  const float* pg    = (const float*)d_in[17];
  const float* pbeta = (const float*)d_in[18];
  const float* pw2   = (const float*)d_in[19];
  const float* pb2   = (const float*)d_in[20];
  const float* aw1   = (const float*)d_in[21];
  const float* ag    = (const float*)d_in[23];
  const float* abeta = (const float*)d_in[24];
  const float* aw2   = (const float*)d_in[25];
  const float* ab2   = (const float*)d_in[26];
  const float* endw  = (const float*)d_in[27];
  const float* endb  = (const float*)d_in[28];
  float* out = (float*)d_out;

  char* wsb = (char*)d_ws;
  size_t off = 0;
  auto take = [&](size_t bytes)->char*{
    char* p = wsb + off; off += (bytes + 255) & ~(size_t)255; return p;
  };
  float* Mm      = (float*)take(65536*4);
  float* mu_sum  = (float*)take(256*4);     // zeroed
  float* rstat   = (float*)take(12*4);      // zeroed
  size_t zero_bytes = off;
  float* w1eff   = (float*)take(192*4);
  float* b1eff   = (float*)take(64*4);
  float* b1eff2  = (float*)take(1024*4);
  float* value   = (float*)take((size_t)524288*4);
  float* qT      = (float*)take((size_t)1048576*4);
  float* kT      = (float*)take((size_t)1048576*4);
  float* vT      = (float*)take((size_t)1048576*4);
  float* aggT    = (float*)take((size_t)1048576*4);
  float* wkT     = (float*)take(32768*4);
  float* wqT     = (float*)take(32768*4);
  float* wvT     = (float*)take(32768*4);
  float* endwT   = (float*)take(32768*4);
  float* mw1T    = (float*)take(32768*4);
  float* mw2T    = (float*)take(16384*4);
  float* mwscT   = (float*)take(32768*4);
  int*   idxb    = (int*)take(65536*4);
  ushortt* U16   = (ushortt*)take((size_t)16777216*2); // bf16 u
  ushortt* pe16  = (ushortt*)take((size_t)16777216*2); // bf16 pos_emb
  ushortt* Mpart = (ushortt*)take((size_t)256*65536*2);// bf16 M partials (32 MB)
  ushortt* w1R   = (ushortt*)take((size_t)262144*2);
  ushortt* w2R   = (ushortt*)take((size_t)262144*2);
  ushortt* w2posT= (ushortt*)take(16384*2);

  // H gets whatever is left; chunk the sample dim to fit.
  size_t avail = (ws_size > off) ? (ws_size - off) : 0;
  int nch = 1;
  while (nch < 64 && ((size_t)(NSAMP/nch))*1024*2 > avail) nch <<= 1;
  int chunk = NSAMP / nch;          // >= 1024, multiple of 128
  ushortt* H = (ushortt*)(wsb + off);

  hipMemsetAsync(d_ws, 0, zero_bytes, stream);
  prep_weights<<<512,256,0,stream>>>(wk,wq,wv,endw,mw1,mw2,mwsc,aw2,pw2,
                                     wkT,wqT,wvT,endwT,mw1T,mw2T,mwscT,w2R,w2posT);
  mlpres_kernel<<<128,256,0,stream>>>(key,query,mw1T,mb1,mw2T,mb2,mwscT,mbsc,value);
  proj_kernel<<<128,256,0,stream>>>(query,wqT,bq,qT);
  proj_kernel<<<128,256,0,stream>>>(key,wkT,bk,kT);
  proj_kernel<<<128,256,0,stream>>>(value,wvT,bv,vT);
  knn_kernel<<<1024,256,0,stream>>>(pos,idxb);
  bn1_stats<<<64,256,0,stream>>>(pos,idxb,rstat);
  bn1_final<<<1,64,0,stream>>>(rstat,pw1,pg,pbeta,w1eff,b1eff);
  passA_kernel<<<1024,256,0,stream>>>(pos,idxb,qT,kT,w1eff,b1eff,w2posT,pb2,U16,pe16,mu_sum);
  mm_kernel<<<256,512,0,stream>>>(U16,Mpart);
  mreduce_kernel<<<256,256,0,stream>>>(Mpart,Mm);
  bn2_final<<<1024,256,0,stream>>>(Mm,mu_sum,aw1,ag,abeta,w1R,b1eff2);
  for (int cc = 0; cc < nch; cc++){
    int s_off = cc*chunk;
    gemm1_kernel<<<dim3(chunk/128, 4),512,0,stream>>>(U16 + (size_t)s_off*256, w1R, b1eff2, H);
    gemm2_kernel<<<chunk/128,512,0,stream>>>(H, w2R, ab2, pe16, vT, aggT, s_off);
  }
  final_kernel<<<128,256,0,stream>>>(aggT,endwT,endb,value,out);
}

// Round 7
// 407.966 us; speedup vs baseline: 3.6130x; 1.0731x over previous
//
#include <hip/hip_runtime.h>
#include <hip/hip_bf16.h>
#include <math.h>

#define Bv 2
#define Nv 2048
#define Cv 128
#define Dv 256
#define PHv 64
#define AHv 1024
#define Kv 16
#define NSAMP (Bv*Nv*Kv)   // 65536

typedef unsigned short ushortt;
typedef __attribute__((ext_vector_type(8))) short bf16x8;
typedef __attribute__((ext_vector_type(4))) float f32x4;

__device__ __forceinline__ float bf2f(ushortt h){
  union { unsigned int u; float f; } v; v.u = ((unsigned int)h) << 16; return v.f;
}
__device__ __forceinline__ ushortt f2bf(float f){
  union { unsigned int u; float f; } v; v.f = f;
  unsigned int r = v.u + 0x7FFFu + ((v.u >> 16) & 1u);
  return (ushortt)(r >> 16);
}

__device__ __forceinline__ void gload16(const void* g, void* l){
  __builtin_amdgcn_global_load_lds(
      (const __attribute__((address_space(1))) unsigned int*)g,
      (__attribute__((address_space(3))) unsigned int*)l, 16, 0, 0);
}

// ---------------- weight transposes / casts ----------------
__global__ __launch_bounds__(256) void prep_weights(
    const float* __restrict__ wk, const float* __restrict__ wq,
    const float* __restrict__ wv, const float* __restrict__ endw,
    const float* __restrict__ mw1, const float* __restrict__ mw2,
    const float* __restrict__ mwsc, const float* __restrict__ aw2,
    const float* __restrict__ pw2,
    float* __restrict__ wkT, float* __restrict__ wqT, float* __restrict__ wvT,
    float* __restrict__ endwT, float* __restrict__ mw1T, float* __restrict__ mw2T,
    float* __restrict__ mwscT, ushortt* __restrict__ w2R, ushortt* __restrict__ pw2R)
{
  int tid = blockIdx.x*256 + threadIdx.x;
  int stride = gridDim.x*256;
  for (int i = tid; i < 256*128; i += stride){ int d = i>>7, c = i&127;
    wkT[c*256+d] = wk[i]; wqT[c*256+d] = wq[i]; wvT[c*256+d] = wv[i]; }
  for (int i = tid; i < 128*256; i += stride){ int co = i>>8, d = i&255; endwT[d*128+co] = endw[i]; }
  for (int i = tid; i < 128*256; i += stride){ int h = i>>8, c = i&255; mw1T[c*128+h] = mw1[i]; }
  for (int i = tid; i < 128*128; i += stride){ int o = i>>7, c = i&127; mw2T[c*128+o] = mw2[i]; }
  for (int i = tid; i < 128*256; i += stride){ int o = i>>8, c = i&255; mwscT[c*128+o] = mwsc[i]; }
  for (int i = tid; i < 256*1024; i += stride) w2R[i] = f2bf(aw2[i]);
  // pos_w2 (256,64) row-major -> bf16 linear
  for (int i = tid; i < 256*64; i += stride) pw2R[i] = f2bf(pw2[i]);
}

// ---------------- value = MLP_Res(cat(key,query)) ----------------
__global__ __launch_bounds__(256) void mlpres_kernel(
    const float* __restrict__ key, const float* __restrict__ query,
    const float* __restrict__ mw1T, const float* __restrict__ b1,
    const float* __restrict__ mw2T, const float* __restrict__ b2,
    const float* __restrict__ mwscT, const float* __restrict__ bsc,
    float* __restrict__ value)
{
  __shared__ float xs[256*32];
  __shared__ float hs[128*32];
  int t = threadIdx.x;
  int tile = blockIdx.x & 63, b = blockIdx.x >> 6;
  int n0 = tile*32;
  for (int e = t; e < 256*32; e += 256){
    int c = e >> 5, nn = e & 31;
    xs[e] = (c < 128) ? key[(size_t)(b*128+c)*Nv + n0+nn]
                      : query[(size_t)(b*128+(c-128))*Nv + n0+nn];
  }
  __syncthreads();
  int hg = t >> 2, ng = t & 3;
  int hd0 = hg*2, nb = ng*8;
  float acc[2][8];
  for (int i=0;i<2;i++){ float bb = b1[hd0+i]; for(int j=0;j<8;j++) acc[i][j]=bb; }
  for (int c = 0; c < 256; c++){
    float w0 = mw1T[c*128 + hd0], w1 = mw1T[c*128 + hd0+1];
    const float* xr = &xs[c*32 + nb];
    #pragma unroll
    for (int j=0;j<8;j++){ float xv = xr[j]; acc[0][j] += w0*xv; acc[1][j] += w1*xv; }
  }
  for (int i=0;i<2;i++) for (int j=0;j<8;j++){
    float v = acc[i][j]; hs[(hd0+i)*32 + nb + j] = v > 0.f ? v : 0.f;
  }
  __syncthreads();
  float out[2][8];
  for (int i=0;i<2;i++){ float bb = b2[hd0+i] + bsc[hd0+i]; for(int j=0;j<8;j++) out[i][j]=bb; }
  for (int c = 0; c < 128; c++){
    float w0 = mw2T[c*128 + hd0], w1 = mw2T[c*128 + hd0+1];
    const float* hr = &hs[c*32 + nb];
    #pragma unroll
    for (int j=0;j<8;j++){ float hv = hr[j]; out[0][j] += w0*hv; out[1][j] += w1*hv; }
  }
  for (int c = 0; c < 256; c++){
    float w0 = mwscT[c*128 + hd0], w1 = mwscT[c*128 + hd0+1];
    const float* xr = &xs[c*32 + nb];
    #pragma unroll
    for (int j=0;j<8;j++){ float xv = xr[j]; out[0][j] += w0*xv; out[1][j] += w1*xv; }
  }
  for (int i=0;i<2;i++) for (int j=0;j<8;j++)
    value[(size_t)(b*128 + hd0+i)*Nv + n0 + nb + j] = out[i][j];
}

// ---------------- conv1d (Cin=128 -> Dout=256), output transposed (B,N,256) ----------------
__global__ __launch_bounds__(256) void proj_kernel(
    const float* __restrict__ x, const float* __restrict__ wT,
    const float* __restrict__ bias, float* __restrict__ outT)
{
  __shared__ float xs[128*32];
  int t = threadIdx.x;
  int tile = blockIdx.x & 63, b = blockIdx.x >> 6;
  int n0 = tile*32;
  for (int e = t; e < 128*32; e += 256){
    int c = e >> 5, nn = e & 31;
    xs[e] = x[(size_t)(b*128+c)*Nv + n0+nn];
  }
  __syncthreads();
  int dg = t >> 2, ng = t & 3;
  int d0 = dg*4, nb = ng*8;
  float acc[4][8];
  for (int i=0;i<4;i++){ float bb = bias[d0+i]; for(int j=0;j<8;j++) acc[i][j]=bb; }
  for (int c = 0; c < 128; c++){
    float w0 = wT[c*256+d0], w1 = wT[c*256+d0+1], w2 = wT[c*256+d0+2], w3 = wT[c*256+d0+3];
    const float* xr = &xs[c*32+nb];
    #pragma unroll
    for (int j=0;j<8;j++){
      float xv = xr[j];
      acc[0][j] += w0*xv; acc[1][j] += w1*xv; acc[2][j] += w2*xv; acc[3][j] += w3*xv;
    }
  }
  for (int j=0;j<8;j++){
    int n = n0+nb+j;
    float4 v = make_float4(acc[0][j],acc[1][j],acc[2][j],acc[3][j]);
    *(float4*)&outT[(size_t)(b*Nv+n)*256 + d0] = v;
  }
}

// ---------------- KNN: wave-per-point, pure shfl ----------------
__global__ __launch_bounds__(256) void knn_kernel(const float* __restrict__ pos, int* __restrict__ idx)
{
  int t = threadIdx.x;
  int w = t >> 6, l = t & 63;
  int p = blockIdx.x*4 + w;
  int i = p & (Nv-1), b = p >> 11;
  const float* px = pos + (size_t)b*3*Nv;
  float pix = px[i], piy = px[Nv+i], piz = px[2*Nv+i];
  float sqi = pix*pix + piy*piy + piz*piz;
  float ds[32];
  #pragma unroll
  for (int jj = 0; jj < 32; jj++){
    int j = jj*64 + l;
    float qx = px[j], qy = px[Nv+j], qz = px[2*Nv+j];
    float sqj = qx*qx + qy*qy + qz*qz;
    float dot = pix*qx + piy*qy + piz*qz;
    ds[jj] = (sqi + sqj) - 2.0f*dot;
  }
  #pragma unroll 1
  for (int it = 0; it < 16; it++){
    float bv = 3.4e38f; int bj = 0x7FFFFFFF;
    #pragma unroll
    for (int jj = 0; jj < 32; jj++){
      int j = jj*64 + l;
      bool c = ds[jj] < bv;
      bv = c ? ds[jj] : bv;
      bj = c ? j : bj;
    }
    #pragma unroll
    for (int off = 32; off; off >>= 1){
      float ov = __shfl_xor(bv, off);
      int oj = __shfl_xor(bj, off);
      if (ov < bv || (ov == bv && oj < bj)){ bv = ov; bj = oj; }
    }
    if (l == 0) idx[(size_t)p*16 + it] = bj;
    #pragma unroll
    for (int jj = 0; jj < 32; jj++){
      if (jj*64 + l == bj) ds[jj] = 3.4e38f;
    }
  }
}

// ---------------- pos-BN stats ----------------
__global__ __launch_bounds__(256) void bn1_stats(const float* __restrict__ pos,
    const int* __restrict__ idx, float* __restrict__ rstat)
{
  int tid = blockIdx.x*256 + threadIdx.x;
  int stride = gridDim.x*256;
  float s[9] = {0,0,0,0,0,0,0,0,0};
  for (int e = tid; e < NSAMP; e += stride){
    int b = e >> 15;
    int rem = e & 32767;
    int n = rem >> 4, k = rem & 15;
    int j = idx[(size_t)(b*Nv+n)*16 + k];
    const float* px = pos + (size_t)b*3*Nv;
    float rx = px[n]-px[j], ry = px[Nv+n]-px[Nv+j], rz = px[2*Nv+n]-px[2*Nv+j];
    s[0]+=rx; s[1]+=ry; s[2]+=rz;
    s[3]+=rx*rx; s[4]+=rx*ry; s[5]+=rx*rz; s[6]+=ry*ry; s[7]+=ry*rz; s[8]+=rz*rz;
  }
  for (int off=32; off; off>>=1)
    for (int q=0;q<9;q++) s[q] += __shfl_xor(s[q], off);
  if ((threadIdx.x & 63) == 0)
    for (int q=0;q<9;q++) atomicAdd(&rstat[q], s[q]);
}

// ---------------- fold pos BN ----------------
__global__ void bn1_final(const float* __restrict__ rstat,
    const float* __restrict__ pw1,
    const float* __restrict__ pg, const float* __restrict__ pbeta,
    float* __restrict__ w1eff, float* __restrict__ b1eff)
{
  int c = threadIdx.x; // 64
  float inv = 1.0f/(float)NSAMP;
  float mux = rstat[0]*inv, muy = rstat[1]*inv, muz = rstat[2]*inv;
  float xx = rstat[3]*inv, xy = rstat[4]*inv, xz = rstat[5]*inv;
  float yy = rstat[6]*inv, yz = rstat[7]*inv, zz = rstat[8]*inv;
  float w0 = pw1[c*3], w1 = pw1[c*3+1], w2 = pw1[c*3+2];
  float dot = w0*mux + w1*muy + w2*muz;
  float quad = w0*w0*xx + w1*w1*yy + w2*w2*zz + 2.f*(w0*w1*xy + w0*w2*xz + w1*w2*yz);
  float var = quad - dot*dot;
  float s = pg[c] * rsqrtf(var + 1e-5f);
  w1eff[c*3]   = w0*s;
  w1eff[c*3+1] = w1*s;
  w1eff[c*3+2] = w2*s;
  b1eff[c] = pbeta[c] - dot*s;
}

// ---------------- Hpos = relu(BN(W1 r)) -> bf16 [65536 x 64] ----------------
__global__ __launch_bounds__(256) void hpos_kernel(
    const float* __restrict__ pos, const int* __restrict__ idx,
    const float* __restrict__ w1eff, const float* __restrict__ b1eff,
    ushortt* __restrict__ hposR)
{
  int t = threadIdx.x;
  int s = blockIdx.x*32 + (t>>3);
  int c0 = (t&7)*8;
  int ptv = s >> 4;
  int n = ptv & (Nv-1), b = ptv >> 11;
  int j = idx[s];
  const float* px = pos + (size_t)b*3*Nv;
  float rx = px[n]-px[j], ry = px[Nv+n]-px[Nv+j], rz = px[2*Nv+n]-px[2*Nv+j];
  ushortt outv[8];
  #pragma unroll
  for (int e = 0; e < 8; e++){
    int c = c0+e;
    float v = b1eff[c] + w1eff[c*3]*rx + w1eff[c*3+1]*ry + w1eff[c*3+2]*rz;
    outv[e] = f2bf(v > 0.f ? v : 0.f);
  }
  *(uint4*)&hposR[(size_t)s*64 + c0] = *(uint4*)outv;
}

// ---------------- GEMM0: pe = Hpos @ pw2^T + pb2; epilogue: U16, val16, mu ----------------
// BM=128, BN=256, K=64; 512 threads = 8 waves (2M x 4N); grid 512 blocks
__global__ __launch_bounds__(512) void gemm0_kernel(
    const ushortt* __restrict__ hposR, const ushortt* __restrict__ pw2R,
    const float* __restrict__ pb2, const int* __restrict__ idx,
    const float* __restrict__ qT, const float* __restrict__ kT, const float* __restrict__ vT,
    ushortt* __restrict__ U16, ushortt* __restrict__ val16, float* __restrict__ mu_sum)
{
  __shared__ ushortt As[128*64];   // 16 KB
  __shared__ ushortt Bs[256*64];   // 32 KB
  __shared__ float mured[8*256];   // 8 KB
  int t = threadIdx.x;
  int w = t >> 6, l = t & 63;
  int lr = l & 15, g4 = l >> 4;
  int wm = w >> 2, wn = w & 3;
  int s0 = blockIdx.x*128;

  #pragma unroll
  for (int i = 0; i < 2; i++){
    int c = t + i*512;
    int r = c >> 3, db = (c & 7)*16;
    const ushortt* src = hposR + (size_t)(s0+r)*64 + ((db ^ ((r&7)<<4))>>1);
    gload16(src, As + c*8);
  }
  #pragma unroll
  for (int i = 0; i < 4; i++){
    int c = t + i*512;
    int r = c >> 3, db = (c & 7)*16;
    const ushortt* src = pw2R + (size_t)r*64 + ((db ^ ((r&7)<<4))>>1);
    gload16(src, Bs + c*8);
  }
  __syncthreads();

  f32x4 acc[4][4];
  #pragma unroll
  for (int i=0;i<4;i++) for (int j=0;j<4;j++) acc[i][j] = (f32x4){0.f,0.f,0.f,0.f};
  #pragma unroll
  for (int kk = 0; kk < 2; kk++){
    int kb = kk*64 + g4*16;
    bf16x8 af[4];
    #pragma unroll
    for (int mi = 0; mi < 4; mi++){
      int row = wm*64 + mi*16 + lr;
      af[mi] = *(const bf16x8*)((const char*)As + row*128 + (kb ^ ((row&7)<<4)));
    }
    #pragma unroll
    for (int ni = 0; ni < 4; ni++){
      int row = wn*64 + ni*16 + lr;
      bf16x8 bfr = *(const bf16x8*)((const char*)Bs + row*128 + (kb ^ ((row&7)<<4)));
      #pragma unroll
      for (int mi = 0; mi < 4; mi++)
        acc[mi][ni] = __builtin_amdgcn_mfma_f32_16x16x32_bf16(af[mi], bfr, acc[mi][ni], 0,0,0);
    }
  }

  // epilogue: u = q - k + pe ; val = v + pe
  float musum[4] = {0.f,0.f,0.f,0.f};
  __align__(16) float pb2v[4];
  #pragma unroll
  for (int ni = 0; ni < 4; ni++) pb2v[ni] = pb2[wn*64 + ni*16 + lr];
  #pragma unroll
  for (int mi = 0; mi < 4; mi++){
    #pragma unroll
    for (int r4 = 0; r4 < 4; r4++){
      int s = s0 + wm*64 + mi*16 + g4*4 + r4;
      int ptv = s >> 4;
      int b = s >> 15;
      int j = idx[s];
      const float* krow = kT + (size_t)(b*Nv + j)*256;
      const float* qrow = qT + (size_t)ptv*256;
      const float* vrow = vT + (size_t)ptv*256;
      #pragma unroll
      for (int ni = 0; ni < 4; ni++){
        int d = wn*64 + ni*16 + lr;
        float pe = acc[mi][ni][r4] + pb2v[ni];
        float u = qrow[d] - krow[d] + pe;
        U16[(size_t)s*256 + d] = f2bf(u);
        val16[(size_t)s*256 + d] = f2bf(vrow[d] + pe);
        musum[ni] += u;
      }
    }
  }
  #pragma unroll
  for (int ni = 0; ni < 4; ni++)
    mured[(wm*4+g4)*256 + wn*64 + ni*16 + lr] = musum[ni];
  __syncthreads();
  if (t < 256){
    float ssum = 0.f;
    #pragma unroll
    for (int q = 0; q < 8; q++) ssum += mured[q*256 + t];
    atomicAdd(&mu_sum[t], ssum);
  }
}

// ---------------- M partials: Mpart[blk] = sum_{s in 256-slice} u u^T (bf16 out) ----------------
__global__ __launch_bounds__(512) void mm_kernel(const ushortt* __restrict__ U16,
                                                 ushortt* __restrict__ Mpart)
{
  __shared__ ushortt Ut[256*64];   // 32 KB
  int t = threadIdx.x;
  int w = t >> 6, l = t & 63;
  int lr = l & 15, g4 = l >> 4;
  int wm = w >> 2, wn = w & 3;
  int c_my = ((w & 3)*64 + l);
  int sg = w >> 2;
  int blk = blockIdx.x;
  int sstart = blk*256;

  f32x4 acc[8][4];
  #pragma unroll
  for (int i=0;i<8;i++) for (int j=0;j<4;j++) acc[i][j] = (f32x4){0.f,0.f,0.f,0.f};

  for (int st = 0; st < 4; st++){
    int sb = sstart + st*64;
    __syncthreads();
    #pragma unroll
    for (int g = 0; g < 4; g++){
      int s8 = sg*32 + g*8;
      ushortt vals[8];
      #pragma unroll
      for (int e = 0; e < 8; e++)
        vals[e] = U16[(size_t)(sb + s8 + e)*256 + c_my];
      unsigned int p0 = (unsigned int)vals[0] | ((unsigned int)vals[1] << 16);
      unsigned int p1 = (unsigned int)vals[2] | ((unsigned int)vals[3] << 16);
      unsigned int p2 = (unsigned int)vals[4] | ((unsigned int)vals[5] << 16);
      unsigned int p3 = (unsigned int)vals[6] | ((unsigned int)vals[7] << 16);
      uint4 pk = make_uint4(p0,p1,p2,p3);
      *(uint4*)((char*)Ut + c_my*128 + ((s8*2) ^ ((c_my&7)<<4))) = pk;
    }
    __syncthreads();
    #pragma unroll
    for (int kk = 0; kk < 2; kk++){
      int kb = kk*64 + g4*16;
      bf16x8 af[8];
      #pragma unroll
      for (int ci = 0; ci < 8; ci++){
        int row = wm*128 + ci*16 + lr;
        af[ci] = *(const bf16x8*)((const char*)Ut + row*128 + (kb ^ ((row&7)<<4)));
      }
      #pragma unroll
      for (int cj = 0; cj < 4; cj++){
        int row = wn*64 + cj*16 + lr;
        bf16x8 bfr = *(const bf16x8*)((const char*)Ut + row*128 + (kb ^ ((row&7)<<4)));
        #pragma unroll
        for (int ci = 0; ci < 8; ci++)
          acc[ci][cj] = __builtin_amdgcn_mfma_f32_16x16x32_bf16(af[ci], bfr, acc[ci][cj], 0,0,0);
      }
    }
  }
  ushortt* dst = Mpart + (size_t)blk*65536;
  #pragma unroll
  for (int ci = 0; ci < 8; ci++){
    #pragma unroll
    for (int cj = 0; cj < 4; cj++){
      int c2 = wn*64 + cj*16 + lr;
      #pragma unroll
      for (int r = 0; r < 4; r++){
        int c1 = wm*128 + ci*16 + g4*4 + r;
        dst[(size_t)c1*256 + c2] = f2bf(acc[ci][cj][r]);
      }
    }
  }
}

__global__ __launch_bounds__(256) void mreduce_kernel(const ushortt* __restrict__ Mpart,
                                                      float* __restrict__ Mm)
{
  int i = blockIdx.x*256 + threadIdx.x;
  float s = 0.f;
  for (int p = 0; p < 256; p++) s += bf2f(Mpart[(size_t)p*65536 + i]);
  Mm[i] = s;
}

// ---------------- fold attn BN into w1R (bf16, row-major [1024][256]) + b1eff2 ----------------
__global__ __launch_bounds__(256) void bn2_final(
    const float* __restrict__ Mm, const float* __restrict__ mu_sum,
    const float* __restrict__ aw1,
    const float* __restrict__ ag, const float* __restrict__ abeta,
    ushortt* __restrict__ w1R, float* __restrict__ b1eff2)
{
  __shared__ float wrow[256];
  __shared__ float red[8];
  __shared__ float s2s;
  int t = threadIdx.x;
  int ch = blockIdx.x;
  wrow[t] = aw1[(size_t)ch*256 + t];
  __syncthreads();
  float colacc = 0.f;
  for (int r = 0; r < 256; r++) colacc += wrow[r] * Mm[(size_t)r*256 + t];
  float inv = 1.0f/(float)NSAMP;
  float qpart = colacc * wrow[t] * inv;
  float dpart = wrow[t] * mu_sum[t] * inv;
  for (int off=32; off; off>>=1){ qpart += __shfl_xor(qpart, off); dpart += __shfl_xor(dpart, off); }
  if ((t&63)==0){ red[t>>6] = qpart; red[4 + (t>>6)] = dpart; }
  __syncthreads();
  if (t == 0){
    float quad = red[0]+red[1]+red[2]+red[3];
    float dot  = red[4]+red[5]+red[6]+red[7];
    float var = quad - dot*dot;
    float s2 = ag[ch] * rsqrtf(var + 1e-5f);
    b1eff2[ch] = abeta[ch] - dot*s2;
    s2s = s2;
  }
  __syncthreads();
  w1R[(size_t)ch*256 + t] = f2bf(wrow[t]*s2s);
}

// ---------------- GEMM1: H = relu(U16c @ W1^T + b) ; [chunk x 1024] bf16 ----------------
__global__ __launch_bounds__(512) void gemm1_kernel(
    const ushortt* __restrict__ U16c, const ushortt* __restrict__ w1R,
    const float* __restrict__ b1eff2, ushortt* __restrict__ H)
{
  __shared__ ushortt As[128*64];
  __shared__ ushortt Bs[256*64];
  int t = threadIdx.x;
  int w = t >> 6, l = t & 63;
  int lr = l & 15, g4 = l >> 4;
  int wm = w >> 2, wn = w & 3;
  int s0 = blockIdx.x*128, n0 = blockIdx.y*256;

  f32x4 acc[4][4];
  #pragma unroll
  for (int i=0;i<4;i++) for (int j=0;j<4;j++) acc[i][j] = (f32x4){0.f,0.f,0.f,0.f};

  for (int kt = 0; kt < 4; kt++){
    int k0 = kt*64;
    __syncthreads();
    #pragma unroll
    for (int i = 0; i < 2; i++){
      int c = t + i*512;
      int r = c >> 3, db = (c & 7)*16;
      const ushortt* src = U16c + (size_t)(s0+r)*256 + k0 + ((db ^ ((r&7)<<4))>>1);
      gload16(src, As + c*8);
    }
    #pragma unroll
    for (int i = 0; i < 4; i++){
      int c = t + i*512;
      int r = c >> 3, db = (c & 7)*16;
      const ushortt* src = w1R + (size_t)(n0+r)*256 + k0 + ((db ^ ((r&7)<<4))>>1);
      gload16(src, Bs + c*8);
    }
    __syncthreads();
    #pragma unroll
    for (int kk = 0; kk < 2; kk++){
      int kb = kk*64 + g4*16;
      bf16x8 af[4];
      #pragma unroll
      for (int mi = 0; mi < 4; mi++){
        int row = wm*64 + mi*16 + lr;
        af[mi] = *(const bf16x8*)((const char*)As + row*128 + (kb ^ ((row&7)<<4)));
      }
      #pragma unroll
      for (int ni = 0; ni < 4; ni++){
        int row = wn*64 + ni*16 + lr;
        bf16x8 bfr = *(const bf16x8*)((const char*)Bs + row*128 + (kb ^ ((row&7)<<4)));
        #pragma unroll
        for (int mi = 0; mi < 4; mi++)
          acc[mi][ni] = __builtin_amdgcn_mfma_f32_16x16x32_bf16(af[mi], bfr, acc[mi][ni], 0,0,0);
      }
    }
  }
  #pragma unroll
  for (int ni = 0; ni < 4; ni++){
    int col = n0 + wn*64 + ni*16 + lr;
    float bias = b1eff2[col];
    #pragma unroll
    for (int mi = 0; mi < 4; mi++){
      int rbase = s0 + wm*64 + mi*16 + g4*4;
      #pragma unroll
      for (int r = 0; r < 4; r++){
        float v = acc[mi][ni][r] + bias;
        v = v > 0.f ? v : 0.f;
        H[(size_t)(rbase+r)*1024 + col] = f2bf(v);
      }
    }
  }
}

// ---------------- GEMM2: logits = H @ W2^T ; fused softmax + aggregation ----------------
__global__ __launch_bounds__(512) void gemm2_kernel(
    const ushortt* __restrict__ H, const ushortt* __restrict__ w2R,
    const float* __restrict__ ab2, const ushortt* __restrict__ val16,
    float* __restrict__ aggT, int s_off)
{
  __shared__ ushortt As[128*64];
  __shared__ ushortt Bs[256*64];
  int t = threadIdx.x;
  int w = t >> 6, l = t & 63;
  int lr = l & 15, g4 = l >> 4;
  int wm = w >> 2, wn = w & 3;
  int blk = blockIdx.x;
  int s0 = blk*128;

  f32x4 acc[4][4];
  #pragma unroll
  for (int i=0;i<4;i++) for (int j=0;j<4;j++) acc[i][j] = (f32x4){0.f,0.f,0.f,0.f};

  for (int kt = 0; kt < 16; kt++){
    int k0 = kt*64;
    __syncthreads();
    #pragma unroll
    for (int i = 0; i < 2; i++){
      int c = t + i*512;
      int r = c >> 3, db = (c & 7)*16;
      const ushortt* src = H + (size_t)(s0+r)*1024 + k0 + ((db ^ ((r&7)<<4))>>1);
      gload16(src, As + c*8);
    }
    #pragma unroll
    for (int i = 0; i < 4; i++){
      int c = t + i*512;
      int r = c >> 3, db = (c & 7)*16;
      const ushortt* src = w2R + (size_t)r*1024 + k0 + ((db ^ ((r&7)<<4))>>1);
      gload16(src, Bs + c*8);
    }
    __syncthreads();
    #pragma unroll
    for (int kk = 0; kk < 2; kk++){
      int kb = kk*64 + g4*16;
      bf16x8 af[4];
      #pragma unroll
      for (int mi = 0; mi < 4; mi++){
        int row = wm*64 + mi*16 + lr;
        af[mi] = *(const bf16x8*)((const char*)As + row*128 + (kb ^ ((row&7)<<4)));
      }
      #pragma unroll
      for (int ni = 0; ni < 4; ni++){
        int row = wn*64 + ni*16 + lr;
        bf16x8 bfr = *(const bf16x8*)((const char*)Bs + row*128 + (kb ^ ((row&7)<<4)));
        #pragma unroll
        for (int mi = 0; mi < 4; mi++)
          acc[mi][ni] = __builtin_amdgcn_mfma_f32_16x16x32_bf16(af[mi], bfr, acc[mi][ni], 0,0,0);
      }
    }
  }
  int ptbase = s_off >> 4;
  #pragma unroll
  for (int mi = 0; mi < 4; mi++){
    int pt = ptbase + blk*8 + wm*4 + mi;
    int sbase = pt*16;
    #pragma unroll
    for (int ni = 0; ni < 4; ni++){
      int d = wn*64 + ni*16 + lr;
      float bias = ab2[d];
      float lg[4];
      #pragma unroll
      for (int r = 0; r < 4; r++) lg[r] = acc[mi][ni][r] + bias;
      float mx = fmaxf(fmaxf(lg[0],lg[1]), fmaxf(lg[2],lg[3]));
      mx = fmaxf(mx, __shfl_xor(mx, 16));
      mx = fmaxf(mx, __shfl_xor(mx, 32));
      float ev[4], ss = 0.f;
      #pragma unroll
      for (int r = 0; r < 4; r++){ ev[r] = __expf(lg[r]-mx); ss += ev[r]; }
      ss += __shfl_xor(ss, 16);
      ss += __shfl_xor(ss, 32);
      float inv = 1.0f/ss;
      float pa = 0.f;
      #pragma unroll
      for (int r = 0; r < 4; r++){
        int s = sbase + g4*4 + r;
        pa += ev[r]*inv*bf2f(val16[(size_t)s*256 + d]);
      }
      pa += __shfl_xor(pa, 16);
      pa += __shfl_xor(pa, 32);
      if (g4 == 0) aggT[(size_t)pt*256 + d] = pa;
    }
  }
}

// ---------------- final: out = end_w @ agg + end_b + value ----------------
__global__ __launch_bounds__(256) void final_kernel(
    const float* __restrict__ aggT, const float* __restrict__ endwT,
    const float* __restrict__ endb, const float* __restrict__ value,
    float* __restrict__ out)
{
  __shared__ float ags[32*257];
  int t = threadIdx.x;
  int tile = blockIdx.x & 63, b = blockIdx.x >> 6;
  int n0 = tile*32;
  for (int e = t; e < 32*256; e += 256){
    int nn = e >> 8, d = e & 255;
    ags[nn*257 + d] = aggT[(size_t)(b*Nv + n0 + nn)*256 + d];
  }
  __syncthreads();
  int cg = t >> 2, ng = t & 3;
  int co0 = cg*2, nb = ng*8;
  float acc[2][8];
  for (int i=0;i<2;i++){ float bb = endb[co0+i]; for (int j=0;j<8;j++) acc[i][j]=bb; }
  for (int d = 0; d < 256; d++){
    float w0 = endwT[d*128 + co0], w1 = endwT[d*128 + co0 + 1];
    #pragma unroll
    for (int j=0;j<8;j++){
      float av = ags[(nb+j)*257 + d];
      acc[0][j] += w0*av; acc[1][j] += w1*av;
    }
  }
  for (int i=0;i<2;i++){
    for (int j=0;j<8;j++){
      size_t o = (size_t)(b*128 + co0 + i)*Nv + n0 + nb + j;
      out[o] = acc[i][j] + value[o];
    }
  }
}

extern "C" void kernel_launch(void* const* d_in, const int* in_sizes, int n_in,
                              void* d_out, int out_size, void* d_ws, size_t ws_size,
                              hipStream_t stream)
{
  (void)in_sizes; (void)n_in; (void)out_size;
  const float* pos   = (const float*)d_in[0];
  const float* key   = (const float*)d_in[1];
  const float* query = (const float*)d_in[2];
  const float* mw1   = (const float*)d_in[3];
  const float* mb1   = (const float*)d_in[4];
  const float* mw2   = (const float*)d_in[5];
  const float* mb2   = (const float*)d_in[6];
  const float* mwsc  = (const float*)d_in[7];
  const float* mbsc  = (const float*)d_in[8];
  const float* wk    = (const float*)d_in[9];
  const float* bk    = (const float*)d_in[10];
  const float* wq    = (const float*)d_in[11];
  const float* bq    = (const float*)d_in[12];
  const float* wv    = (const float*)d_in[13];
  const float* bv    = (const float*)d_in[14];
  const float* pw1   = (const float*)d_in[15];
  const float* pg    = (const float*)d_in[17];
  const float* pbeta = (const float*)d_in[18];
  const float* pw2   = (const float*)d_in[19];
  const float* pb2   = (const float*)d_in[20];
  const float* aw1   = (const float*)d_in[21];
  const float* ag    = (const float*)d_in[23];
  const float* abeta = (const float*)d_in[24];
  const float* aw2   = (const float*)d_in[25];
  const float* ab2   = (const float*)d_in[26];
  const float* endw  = (const float*)d_in[27];
  const float* endb  = (const float*)d_in[28];
  float* out = (float*)d_out;

  char* wsb = (char*)d_ws;
  size_t off = 0;
  auto take = [&](size_t bytes)->char*{
    char* p = wsb + off; off += (bytes + 255) & ~(size_t)255; return p;
  };
  float* Mm      = (float*)take(65536*4);
  float* mu_sum  = (float*)take(256*4);     // zeroed
  float* rstat   = (float*)take(12*4);      // zeroed
  size_t zero_bytes = off;
  float* w1eff   = (float*)take(192*4);
  float* b1eff   = (float*)take(64*4);
  float* b1eff2  = (float*)take(1024*4);
  float* value   = (float*)take((size_t)524288*4);
  float* qT      = (float*)take((size_t)1048576*4);
  float* kT      = (float*)take((size_t)1048576*4);
  float* vT      = (float*)take((size_t)1048576*4);
  float* aggT    = (float*)take((size_t)1048576*4);
  float* wkT     = (float*)take(32768*4);
  float* wqT     = (float*)take(32768*4);
  float* wvT     = (float*)take(32768*4);
  float* endwT   = (float*)take(32768*4);
  float* mw1T    = (float*)take(32768*4);
  float* mw2T    = (float*)take(16384*4);
  float* mwscT   = (float*)take(32768*4);
  int*   idxb    = (int*)take(65536*4);
  ushortt* U16   = (ushortt*)take((size_t)16777216*2); // bf16 u
  ushortt* val16 = (ushortt*)take((size_t)16777216*2); // bf16 (v + pos_emb)
  ushortt* hposR = (ushortt*)take((size_t)4194304*2);  // bf16 Hpos [65536x64]
  ushortt* Mpart = (ushortt*)take((size_t)256*65536*2);// bf16 M partials (32 MB)
  ushortt* w1R   = (ushortt*)take((size_t)262144*2);
  ushortt* w2R   = (ushortt*)take((size_t)262144*2);
  ushortt* pw2R  = (ushortt*)take(16384*2);

  // H gets whatever is left; chunk the sample dim to fit.
  size_t avail = (ws_size > off) ? (ws_size - off) : 0;
  int nch = 1;
  while (nch < 64 && ((size_t)(NSAMP/nch))*1024*2 > avail) nch <<= 1;
  int chunk = NSAMP / nch;          // >= 1024, multiple of 128
  ushortt* H = (ushortt*)(wsb + off);

  hipMemsetAsync(d_ws, 0, zero_bytes, stream);
  prep_weights<<<512,256,0,stream>>>(wk,wq,wv,endw,mw1,mw2,mwsc,aw2,pw2,
                                     wkT,wqT,wvT,endwT,mw1T,mw2T,mwscT,w2R,pw2R);
  mlpres_kernel<<<128,256,0,stream>>>(key,query,mw1T,mb1,mw2T,mb2,mwscT,mbsc,value);
  proj_kernel<<<128,256,0,stream>>>(query,wqT,bq,qT);
  proj_kernel<<<128,256,0,stream>>>(key,wkT,bk,kT);
  proj_kernel<<<128,256,0,stream>>>(value,wvT,bv,vT);
  knn_kernel<<<1024,256,0,stream>>>(pos,idxb);
  bn1_stats<<<64,256,0,stream>>>(pos,idxb,rstat);
  bn1_final<<<1,64,0,stream>>>(rstat,pw1,pg,pbeta,w1eff,b1eff);
  hpos_kernel<<<2048,256,0,stream>>>(pos,idxb,w1eff,b1eff,hposR);
  gemm0_kernel<<<512,512,0,stream>>>(hposR,pw2R,pb2,idxb,qT,kT,vT,U16,val16,mu_sum);
  mm_kernel<<<256,512,0,stream>>>(U16,Mpart);
  mreduce_kernel<<<256,256,0,stream>>>(Mpart,Mm);
  bn2_final<<<1024,256,0,stream>>>(Mm,mu_sum,aw1,ag,abeta,w1R,b1eff2);
  for (int cc = 0; cc < nch; cc++){
    int s_off = cc*chunk;
    gemm1_kernel<<<dim3(chunk/128, 4),512,0,stream>>>(U16 + (size_t)s_off*256, w1R, b1eff2, H);
    gemm2_kernel<<<chunk/128,512,0,stream>>>(H, w2R, ab2, val16, aggT, s_off);
  }
  final_kernel<<<128,256,0,stream>>>(aggT,endwT,endb,value,out);
}

// Round 8
// 392.575 us; speedup vs baseline: 3.7546x; 1.0392x over previous
//
#include <hip/hip_runtime.h>
#include <hip/hip_bf16.h>
#include <math.h>

#define Bv 2
#define Nv 2048
#define Cv 128
#define Dv 256
#define PHv 64
#define AHv 1024
#define Kv 16
#define NSAMP (Bv*Nv*Kv)   // 65536

typedef unsigned short ushortt;
typedef unsigned char u8;
typedef __attribute__((ext_vector_type(8))) short bf16x8;
typedef __attribute__((ext_vector_type(4))) float f32x4;

__device__ __forceinline__ float bf2f(ushortt h){
  union { unsigned int u; float f; } v; v.u = ((unsigned int)h) << 16; return v.f;
}
__device__ __forceinline__ ushortt f2bf(float f){
  union { unsigned int u; float f; } v; v.f = f;
  unsigned int r = v.u + 0x7FFFu + ((v.u >> 16) & 1u);
  return (ushortt)(r >> 16);
}
// f32 -> fp8 e4m3fn (OCP), RNE, clamp to 448, FTZ subnormals
__device__ __forceinline__ u8 f2fp8(float f){
  union { float f; unsigned int u; } v; v.f = f;
  unsigned int s = (v.u >> 24) & 0x80u;
  unsigned int a = v.u & 0x7FFFFFFFu;
  if (a > 0x43E00000u) a = 0x43E00000u;           // 448.0
  unsigned int r = a + 0x7FFFFu + ((a >> 20) & 1u);
  int e = (int)((r >> 23) & 0xFF) - 120;          // -127 + 7
  unsigned int m = (r >> 20) & 7u;
  if (e <= 0) return (u8)s;
  return (u8)(s | ((unsigned)e << 3) | m);
}

__device__ __forceinline__ void gload16(const void* g, void* l){
  __builtin_amdgcn_global_load_lds(
      (const __attribute__((address_space(1))) unsigned int*)g,
      (__attribute__((address_space(3))) unsigned int*)l, 16, 0, 0);
}

// ---------------- weight transposes / casts ----------------
__global__ __launch_bounds__(256) void prep_weights(
    const float* __restrict__ wk, const float* __restrict__ wq,
    const float* __restrict__ wv, const float* __restrict__ endw,
    const float* __restrict__ mw1, const float* __restrict__ mw2,
    const float* __restrict__ mwsc, const float* __restrict__ aw2,
    const float* __restrict__ pw2,
    float* __restrict__ wkT, float* __restrict__ wqT, float* __restrict__ wvT,
    float* __restrict__ endwT, float* __restrict__ mw1T, float* __restrict__ mw2T,
    float* __restrict__ mwscT, u8* __restrict__ w2f8, ushortt* __restrict__ pw2R)
{
  int tid = blockIdx.x*256 + threadIdx.x;
  int stride = gridDim.x*256;
  for (int i = tid; i < 256*128; i += stride){ int d = i>>7, c = i&127;
    wkT[c*256+d] = wk[i]; wqT[c*256+d] = wq[i]; wvT[c*256+d] = wv[i]; }
  for (int i = tid; i < 128*256; i += stride){ int co = i>>8, d = i&255; endwT[d*128+co] = endw[i]; }
  for (int i = tid; i < 128*256; i += stride){ int h = i>>8, c = i&255; mw1T[c*128+h] = mw1[i]; }
  for (int i = tid; i < 128*128; i += stride){ int o = i>>7, c = i&127; mw2T[c*128+o] = mw2[i]; }
  for (int i = tid; i < 128*256; i += stride){ int o = i>>8, c = i&255; mwscT[c*128+o] = mwsc[i]; }
  // attn_w2 (256,1024) row-major fp8, scaled by 256
  for (int i = tid; i < 256*1024; i += stride) w2f8[i] = f2fp8(aw2[i]*256.f);
  // pos_w2 (256,64) row-major bf16
  for (int i = tid; i < 256*64; i += stride) pw2R[i] = f2bf(pw2[i]);
}

// ---------------- value = MLP_Res(cat(key,query)) ----------------
__global__ __launch_bounds__(256) void mlpres_kernel(
    const float* __restrict__ key, const float* __restrict__ query,
    const float* __restrict__ mw1T, const float* __restrict__ b1,
    const float* __restrict__ mw2T, const float* __restrict__ b2,
    const float* __restrict__ mwscT, const float* __restrict__ bsc,
    float* __restrict__ value)
{
  __shared__ float xs[256*32];
  __shared__ float hs[128*32];
  int t = threadIdx.x;
  int tile = blockIdx.x & 63, b = blockIdx.x >> 6;
  int n0 = tile*32;
  for (int e = t; e < 256*32; e += 256){
    int c = e >> 5, nn = e & 31;
    xs[e] = (c < 128) ? key[(size_t)(b*128+c)*Nv + n0+nn]
                      : query[(size_t)(b*128+(c-128))*Nv + n0+nn];
  }
  __syncthreads();
  int hg = t >> 2, ng = t & 3;
  int hd0 = hg*2, nb = ng*8;
  float acc[2][8];
  for (int i=0;i<2;i++){ float bb = b1[hd0+i]; for(int j=0;j<8;j++) acc[i][j]=bb; }
  for (int c = 0; c < 256; c++){
    float w0 = mw1T[c*128 + hd0], w1 = mw1T[c*128 + hd0+1];
    const float* xr = &xs[c*32 + nb];
    #pragma unroll
    for (int j=0;j<8;j++){ float xv = xr[j]; acc[0][j] += w0*xv; acc[1][j] += w1*xv; }
  }
  for (int i=0;i<2;i++) for (int j=0;j<8;j++){
    float v = acc[i][j]; hs[(hd0+i)*32 + nb + j] = v > 0.f ? v : 0.f;
  }
  __syncthreads();
  float out[2][8];
  for (int i=0;i<2;i++){ float bb = b2[hd0+i] + bsc[hd0+i]; for(int j=0;j<8;j++) out[i][j]=bb; }
  for (int c = 0; c < 128; c++){
    float w0 = mw2T[c*128 + hd0], w1 = mw2T[c*128 + hd0+1];
    const float* hr = &hs[c*32 + nb];
    #pragma unroll
    for (int j=0;j<8;j++){ float hv = hr[j]; out[0][j] += w0*hv; out[1][j] += w1*hv; }
  }
  for (int c = 0; c < 256; c++){
    float w0 = mwscT[c*128 + hd0], w1 = mwscT[c*128 + hd0+1];
    const float* xr = &xs[c*32 + nb];
    #pragma unroll
    for (int j=0;j<8;j++){ float xv = xr[j]; out[0][j] += w0*xv; out[1][j] += w1*xv; }
  }
  for (int i=0;i<2;i++) for (int j=0;j<8;j++)
    value[(size_t)(b*128 + hd0+i)*Nv + n0 + nb + j] = out[i][j];
}

// ---------------- conv1d (Cin=128 -> Dout=256), output transposed (B,N,256) ----------------
__global__ __launch_bounds__(256) void proj_kernel(
    const float* __restrict__ x, const float* __restrict__ wT,
    const float* __restrict__ bias, float* __restrict__ outT)
{
  __shared__ float xs[128*32];
  int t = threadIdx.x;
  int tile = blockIdx.x & 63, b = blockIdx.x >> 6;
  int n0 = tile*32;
  for (int e = t; e < 128*32; e += 256){
    int c = e >> 5, nn = e & 31;
    xs[e] = x[(size_t)(b*128+c)*Nv + n0+nn];
  }
  __syncthreads();
  int dg = t >> 2, ng = t & 3;
  int d0 = dg*4, nb = ng*8;
  float acc[4][8];
  for (int i=0;i<4;i++){ float bb = bias[d0+i]; for(int j=0;j<8;j++) acc[i][j]=bb; }
  for (int c = 0; c < 128; c++){
    float w0 = wT[c*256+d0], w1 = wT[c*256+d0+1], w2 = wT[c*256+d0+2], w3 = wT[c*256+d0+3];
    const float* xr = &xs[c*32+nb];
    #pragma unroll
    for (int j=0;j<8;j++){
      float xv = xr[j];
      acc[0][j] += w0*xv; acc[1][j] += w1*xv; acc[2][j] += w2*xv; acc[3][j] += w3*xv;
    }
  }
  for (int j=0;j<8;j++){
    int n = n0+nb+j;
    float4 v = make_float4(acc[0][j],acc[1][j],acc[2][j],acc[3][j]);
    *(float4*)&outT[(size_t)(b*Nv+n)*256 + d0] = v;
  }
}

// ---------------- KNN: wave-per-point, pure shfl ----------------
__global__ __launch_bounds__(256) void knn_kernel(const float* __restrict__ pos, int* __restrict__ idx)
{
  int t = threadIdx.x;
  int w = t >> 6, l = t & 63;
  int p = blockIdx.x*4 + w;
  int i = p & (Nv-1), b = p >> 11;
  const float* px = pos + (size_t)b*3*Nv;
  float pix = px[i], piy = px[Nv+i], piz = px[2*Nv+i];
  float sqi = pix*pix + piy*piy + piz*piz;
  float ds[32];
  #pragma unroll
  for (int jj = 0; jj < 32; jj++){
    int j = jj*64 + l;
    float qx = px[j], qy = px[Nv+j], qz = px[2*Nv+j];
    float sqj = qx*qx + qy*qy + qz*qz;
    float dot = pix*qx + piy*qy + piz*qz;
    ds[jj] = (sqi + sqj) - 2.0f*dot;
  }
  #pragma unroll 1
  for (int it = 0; it < 16; it++){
    float bv = 3.4e38f; int bj = 0x7FFFFFFF;
    #pragma unroll
    for (int jj = 0; jj < 32; jj++){
      int j = jj*64 + l;
      bool c = ds[jj] < bv;
      bv = c ? ds[jj] : bv;
      bj = c ? j : bj;
    }
    #pragma unroll
    for (int off = 32; off; off >>= 1){
      float ov = __shfl_xor(bv, off);
      int oj = __shfl_xor(bj, off);
      if (ov < bv || (ov == bv && oj < bj)){ bv = ov; bj = oj; }
    }
    if (l == 0) idx[(size_t)p*16 + it] = bj;
    #pragma unroll
    for (int jj = 0; jj < 32; jj++){
      if (jj*64 + l == bj) ds[jj] = 3.4e38f;
    }
  }
}

// ---------------- pos-BN stats ----------------
__global__ __launch_bounds__(256) void bn1_stats(const float* __restrict__ pos,
    const int* __restrict__ idx, float* __restrict__ rstat)
{
  int tid = blockIdx.x*256 + threadIdx.x;
  int stride = gridDim.x*256;
  float s[9] = {0,0,0,0,0,0,0,0,0};
  for (int e = tid; e < NSAMP; e += stride){
    int b = e >> 15;
    int rem = e & 32767;
    int n = rem >> 4, k = rem & 15;
    int j = idx[(size_t)(b*Nv+n)*16 + k];
    const float* px = pos + (size_t)b*3*Nv;
    float rx = px[n]-px[j], ry = px[Nv+n]-px[Nv+j], rz = px[2*Nv+n]-px[2*Nv+j];
    s[0]+=rx; s[1]+=ry; s[2]+=rz;
    s[3]+=rx*rx; s[4]+=rx*ry; s[5]+=rx*rz; s[6]+=ry*ry; s[7]+=ry*rz; s[8]+=rz*rz;
  }
  for (int off=32; off; off>>=1)
    for (int q=0;q<9;q++) s[q] += __shfl_xor(s[q], off);
  if ((threadIdx.x & 63) == 0)
    for (int q=0;q<9;q++) atomicAdd(&rstat[q], s[q]);
}

// ---------------- fold pos BN ----------------
__global__ void bn1_final(const float* __restrict__ rstat,
    const float* __restrict__ pw1,
    const float* __restrict__ pg, const float* __restrict__ pbeta,
    float* __restrict__ w1eff, float* __restrict__ b1eff)
{
  int c = threadIdx.x; // 64
  float inv = 1.0f/(float)NSAMP;
  float mux = rstat[0]*inv, muy = rstat[1]*inv, muz = rstat[2]*inv;
  float xx = rstat[3]*inv, xy = rstat[4]*inv, xz = rstat[5]*inv;
  float yy = rstat[6]*inv, yz = rstat[7]*inv, zz = rstat[8]*inv;
  float w0 = pw1[c*3], w1 = pw1[c*3+1], w2 = pw1[c*3+2];
  float dot = w0*mux + w1*muy + w2*muz;
  float quad = w0*w0*xx + w1*w1*yy + w2*w2*zz + 2.f*(w0*w1*xy + w0*w2*xz + w1*w2*yz);
  float var = quad - dot*dot;
  float s = pg[c] * rsqrtf(var + 1e-5f);
  w1eff[c*3]   = w0*s;
  w1eff[c*3+1] = w1*s;
  w1eff[c*3+2] = w2*s;
  b1eff[c] = pbeta[c] - dot*s;
}

// ---------------- Hpos = relu(BN(W1 r)) -> bf16 [65536 x 64] ----------------
__global__ __launch_bounds__(256) void hpos_kernel(
    const float* __restrict__ pos, const int* __restrict__ idx,
    const float* __restrict__ w1eff, const float* __restrict__ b1eff,
    ushortt* __restrict__ hposR)
{
  int t = threadIdx.x;
  int s = blockIdx.x*32 + (t>>3);
  int c0 = (t&7)*8;
  int ptv = s >> 4;
  int n = ptv & (Nv-1), b = ptv >> 11;
  int j = idx[s];
  const float* px = pos + (size_t)b*3*Nv;
  float rx = px[n]-px[j], ry = px[Nv+n]-px[Nv+j], rz = px[2*Nv+n]-px[2*Nv+j];
  ushortt outv[8];
  #pragma unroll
  for (int e = 0; e < 8; e++){
    int c = c0+e;
    float v = b1eff[c] + w1eff[c*3]*rx + w1eff[c*3+1]*ry + w1eff[c*3+2]*rz;
    outv[e] = f2bf(v > 0.f ? v : 0.f);
  }
  *(uint4*)&hposR[(size_t)s*64 + c0] = *(uint4*)outv;
}

// ---------------- GEMM0: pe = Hpos @ pw2^T + pb2; epilogue: U16, val16, mu ----------------
__global__ __launch_bounds__(512) void gemm0_kernel(
    const ushortt* __restrict__ hposR, const ushortt* __restrict__ pw2R,
    const float* __restrict__ pb2, const int* __restrict__ idx,
    const float* __restrict__ qT, const float* __restrict__ kT, const float* __restrict__ vT,
    ushortt* __restrict__ U16, ushortt* __restrict__ val16, float* __restrict__ mu_sum)
{
  __shared__ ushortt As[128*64];   // 16 KB
  __shared__ ushortt Bs[256*64];   // 32 KB
  __shared__ float mured[8*256];   // 8 KB
  int t = threadIdx.x;
  int w = t >> 6, l = t & 63;
  int lr = l & 15, g4 = l >> 4;
  int wm = w >> 2, wn = w & 3;
  int s0 = blockIdx.x*128;

  #pragma unroll
  for (int i = 0; i < 2; i++){
    int c = t + i*512;
    int r = c >> 3, db = (c & 7)*16;
    const ushortt* src = hposR + (size_t)(s0+r)*64 + ((db ^ ((r&7)<<4))>>1);
    gload16(src, As + c*8);
  }
  #pragma unroll
  for (int i = 0; i < 4; i++){
    int c = t + i*512;
    int r = c >> 3, db = (c & 7)*16;
    const ushortt* src = pw2R + (size_t)r*64 + ((db ^ ((r&7)<<4))>>1);
    gload16(src, Bs + c*8);
  }
  __syncthreads();

  f32x4 acc[4][4];
  #pragma unroll
  for (int i=0;i<4;i++) for (int j=0;j<4;j++) acc[i][j] = (f32x4){0.f,0.f,0.f,0.f};
  #pragma unroll
  for (int kk = 0; kk < 2; kk++){
    int kb = kk*64 + g4*16;
    bf16x8 af[4];
    #pragma unroll
    for (int mi = 0; mi < 4; mi++){
      int row = wm*64 + mi*16 + lr;
      af[mi] = *(const bf16x8*)((const char*)As + row*128 + (kb ^ ((row&7)<<4)));
    }
    #pragma unroll
    for (int ni = 0; ni < 4; ni++){
      int row = wn*64 + ni*16 + lr;
      bf16x8 bfr = *(const bf16x8*)((const char*)Bs + row*128 + (kb ^ ((row&7)<<4)));
      #pragma unroll
      for (int mi = 0; mi < 4; mi++)
        acc[mi][ni] = __builtin_amdgcn_mfma_f32_16x16x32_bf16(af[mi], bfr, acc[mi][ni], 0,0,0);
    }
  }

  float musum[4] = {0.f,0.f,0.f,0.f};
  __align__(16) float pb2v[4];
  #pragma unroll
  for (int ni = 0; ni < 4; ni++) pb2v[ni] = pb2[wn*64 + ni*16 + lr];
  #pragma unroll
  for (int mi = 0; mi < 4; mi++){
    #pragma unroll
    for (int r4 = 0; r4 < 4; r4++){
      int s = s0 + wm*64 + mi*16 + g4*4 + r4;
      int ptv = s >> 4;
      int b = s >> 15;
      int j = idx[s];
      const float* krow = kT + (size_t)(b*Nv + j)*256;
      const float* qrow = qT + (size_t)ptv*256;
      const float* vrow = vT + (size_t)ptv*256;
      #pragma unroll
      for (int ni = 0; ni < 4; ni++){
        int d = wn*64 + ni*16 + lr;
        float pe = acc[mi][ni][r4] + pb2v[ni];
        float u = qrow[d] - krow[d] + pe;
        U16[(size_t)s*256 + d] = f2bf(u);
        val16[(size_t)s*256 + d] = f2bf(vrow[d] + pe);
        musum[ni] += u;
      }
    }
  }
  #pragma unroll
  for (int ni = 0; ni < 4; ni++)
    mured[(wm*4+g4)*256 + wn*64 + ni*16 + lr] = musum[ni];
  __syncthreads();
  if (t < 256){
    float ssum = 0.f;
    #pragma unroll
    for (int q = 0; q < 8; q++) ssum += mured[q*256 + t];
    atomicAdd(&mu_sum[t], ssum);
  }
}

// ---------------- M partials ----------------
__global__ __launch_bounds__(512) void mm_kernel(const ushortt* __restrict__ U16,
                                                 ushortt* __restrict__ Mpart)
{
  __shared__ ushortt Ut[256*64];   // 32 KB
  int t = threadIdx.x;
  int w = t >> 6, l = t & 63;
  int lr = l & 15, g4 = l >> 4;
  int wm = w >> 2, wn = w & 3;
  int c_my = ((w & 3)*64 + l);
  int sg = w >> 2;
  int blk = blockIdx.x;
  int sstart = blk*256;

  f32x4 acc[8][4];
  #pragma unroll
  for (int i=0;i<8;i++) for (int j=0;j<4;j++) acc[i][j] = (f32x4){0.f,0.f,0.f,0.f};

  for (int st = 0; st < 4; st++){
    int sb = sstart + st*64;
    __syncthreads();
    #pragma unroll
    for (int g = 0; g < 4; g++){
      int s8 = sg*32 + g*8;
      ushortt vals[8];
      #pragma unroll
      for (int e = 0; e < 8; e++)
        vals[e] = U16[(size_t)(sb + s8 + e)*256 + c_my];
      unsigned int p0 = (unsigned int)vals[0] | ((unsigned int)vals[1] << 16);
      unsigned int p1 = (unsigned int)vals[2] | ((unsigned int)vals[3] << 16);
      unsigned int p2 = (unsigned int)vals[4] | ((unsigned int)vals[5] << 16);
      unsigned int p3 = (unsigned int)vals[6] | ((unsigned int)vals[7] << 16);
      uint4 pk = make_uint4(p0,p1,p2,p3);
      *(uint4*)((char*)Ut + c_my*128 + ((s8*2) ^ ((c_my&7)<<4))) = pk;
    }
    __syncthreads();
    #pragma unroll
    for (int kk = 0; kk < 2; kk++){
      int kb = kk*64 + g4*16;
      bf16x8 af[8];
      #pragma unroll
      for (int ci = 0; ci < 8; ci++){
        int row = wm*128 + ci*16 + lr;
        af[ci] = *(const bf16x8*)((const char*)Ut + row*128 + (kb ^ ((row&7)<<4)));
      }
      #pragma unroll
      for (int cj = 0; cj < 4; cj++){
        int row = wn*64 + cj*16 + lr;
        bf16x8 bfr = *(const bf16x8*)((const char*)Ut + row*128 + (kb ^ ((row&7)<<4)));
        #pragma unroll
        for (int ci = 0; ci < 8; ci++)
          acc[ci][cj] = __builtin_amdgcn_mfma_f32_16x16x32_bf16(af[ci], bfr, acc[ci][cj], 0,0,0);
      }
    }
  }
  ushortt* dst = Mpart + (size_t)blk*65536;
  #pragma unroll
  for (int ci = 0; ci < 8; ci++){
    #pragma unroll
    for (int cj = 0; cj < 4; cj++){
      int c2 = wn*64 + cj*16 + lr;
      #pragma unroll
      for (int r = 0; r < 4; r++){
        int c1 = wm*128 + ci*16 + g4*4 + r;
        dst[(size_t)c1*256 + c2] = f2bf(acc[ci][cj][r]);
      }
    }
  }
}

__global__ __launch_bounds__(256) void mreduce_kernel(const ushortt* __restrict__ Mpart,
                                                      float* __restrict__ Mm)
{
  int i = blockIdx.x*256 + threadIdx.x;
  float s = 0.f;
  for (int p = 0; p < 256; p++) s += bf2f(Mpart[(size_t)p*65536 + i]);
  Mm[i] = s;
}

// ---------------- fold attn BN into w1R (bf16) + b1eff2 ----------------
__global__ __launch_bounds__(256) void bn2_final(
    const float* __restrict__ Mm, const float* __restrict__ mu_sum,
    const float* __restrict__ aw1,
    const float* __restrict__ ag, const float* __restrict__ abeta,
    ushortt* __restrict__ w1R, float* __restrict__ b1eff2)
{
  __shared__ float wrow[256];
  __shared__ float red[8];
  __shared__ float s2s;
  int t = threadIdx.x;
  int ch = blockIdx.x;
  wrow[t] = aw1[(size_t)ch*256 + t];
  __syncthreads();
  float colacc = 0.f;
  for (int r = 0; r < 256; r++) colacc += wrow[r] * Mm[(size_t)r*256 + t];
  float inv = 1.0f/(float)NSAMP;
  float qpart = colacc * wrow[t] * inv;
  float dpart = wrow[t] * mu_sum[t] * inv;
  for (int off=32; off; off>>=1){ qpart += __shfl_xor(qpart, off); dpart += __shfl_xor(dpart, off); }
  if ((t&63)==0){ red[t>>6] = qpart; red[4 + (t>>6)] = dpart; }
  __syncthreads();
  if (t == 0){
    float quad = red[0]+red[1]+red[2]+red[3];
    float dot  = red[4]+red[5]+red[6]+red[7];
    float var = quad - dot*dot;
    float s2 = ag[ch] * rsqrtf(var + 1e-5f);
    b1eff2[ch] = abeta[ch] - dot*s2;
    s2s = s2;
  }
  __syncthreads();
  w1R[(size_t)ch*256 + t] = f2bf(wrow[t]*s2s);
}

// ---------------- GEMM1: H = fp8(4*relu(U16 @ W1^T + b)) ; [chunk x 1024] fp8 ----------------
__global__ __launch_bounds__(512) void gemm1_kernel(
    const ushortt* __restrict__ U16c, const ushortt* __restrict__ w1R,
    const float* __restrict__ b1eff2, u8* __restrict__ H)
{
  __shared__ ushortt As[128*64];   // 16 KB
  __shared__ ushortt Bs[256*64];   // 32 KB (reused as fp8 repack buffer)
  int t = threadIdx.x;
  int w = t >> 6, l = t & 63;
  int lr = l & 15, g4 = l >> 4;
  int wm = w >> 2, wn = w & 3;
  int s0 = blockIdx.x*128, n0 = blockIdx.y*256;

  f32x4 acc[4][4];
  #pragma unroll
  for (int i=0;i<4;i++) for (int j=0;j<4;j++) acc[i][j] = (f32x4){0.f,0.f,0.f,0.f};

  for (int kt = 0; kt < 4; kt++){
    int k0 = kt*64;
    __syncthreads();
    #pragma unroll
    for (int i = 0; i < 2; i++){
      int c = t + i*512;
      int r = c >> 3, db = (c & 7)*16;
      const ushortt* src = U16c + (size_t)(s0+r)*256 + k0 + ((db ^ ((r&7)<<4))>>1);
      gload16(src, As + c*8);
    }
    #pragma unroll
    for (int i = 0; i < 4; i++){
      int c = t + i*512;
      int r = c >> 3, db = (c & 7)*16;
      const ushortt* src = w1R + (size_t)(n0+r)*256 + k0 + ((db ^ ((r&7)<<4))>>1);
      gload16(src, Bs + c*8);
    }
    __syncthreads();
    #pragma unroll
    for (int kk = 0; kk < 2; kk++){
      int kb = kk*64 + g4*16;
      bf16x8 af[4];
      #pragma unroll
      for (int mi = 0; mi < 4; mi++){
        int row = wm*64 + mi*16 + lr;
        af[mi] = *(const bf16x8*)((const char*)As + row*128 + (kb ^ ((row&7)<<4)));
      }
      #pragma unroll
      for (int ni = 0; ni < 4; ni++){
        int row = wn*64 + ni*16 + lr;
        bf16x8 bfr = *(const bf16x8*)((const char*)Bs + row*128 + (kb ^ ((row&7)<<4)));
        #pragma unroll
        for (int mi = 0; mi < 4; mi++)
          acc[mi][ni] = __builtin_amdgcn_mfma_f32_16x16x32_bf16(af[mi], bfr, acc[mi][ni], 0,0,0);
      }
    }
  }
  // epilogue: relu -> fp8(4x) -> LDS repack (reuse Bs) -> coalesced 16B stores
  __syncthreads();
  u8* rep = (u8*)Bs;               // 128 x 256 fp8 = 32 KB
  #pragma unroll
  for (int ni = 0; ni < 4; ni++){
    int colc = wn*64 + ni*16 + lr;
    float bias = b1eff2[n0 + colc];
    #pragma unroll
    for (int mi = 0; mi < 4; mi++){
      int sloc = wm*64 + mi*16 + g4*4;
      #pragma unroll
      for (int r = 0; r < 4; r++){
        float v = acc[mi][ni][r] + bias;
        v = v > 0.f ? v : 0.f;
        rep[(sloc+r)*256 + colc] = f2fp8(4.f*v);
      }
    }
  }
  __syncthreads();
  #pragma unroll
  for (int i = 0; i < 4; i++){
    int e = t + i*512;
    int row = e >> 4, off = (e & 15)*16;
    *(uint4*)&H[(size_t)(s0+row)*1024 + n0 + off] = *(const uint4*)(rep + e*16);
  }
}

// ---------------- GEMM2 (fp8): logits = (H @ W2f8^T)/1024 + ab2 ; fused softmax + agg ----------------
__global__ __launch_bounds__(512) void gemm2_kernel(
    const u8* __restrict__ H, const u8* __restrict__ w2f8,
    const float* __restrict__ ab2, const ushortt* __restrict__ val16,
    float* __restrict__ aggT, int s_off)
{
  __shared__ u8 As8[128*64];   // 8 KB
  __shared__ u8 Bs8[256*64];   // 16 KB
  int t = threadIdx.x;
  int w = t >> 6, l = t & 63;
  int lr = l & 15, g4 = l >> 4;
  int wm = w >> 2, wn = w & 3;
  int blk = blockIdx.x;
  int s0 = blk*128;

  f32x4 acc[4][4];
  #pragma unroll
  for (int i=0;i<4;i++) for (int j=0;j<4;j++) acc[i][j] = (f32x4){0.f,0.f,0.f,0.f};

  for (int kt = 0; kt < 16; kt++){
    int k0 = kt*64;
    __syncthreads();
    {
      int c = t;                    // 512 granules of 16B
      int r = c >> 2, db = (c & 3)*16;
      const u8* src = H + (size_t)(s0+r)*1024 + k0 + (db ^ ((r&3)<<4));
      gload16(src, As8 + c*16);
    }
    #pragma unroll
    for (int i = 0; i < 2; i++){
      int c = t + i*512;
      int r = c >> 2, db = (c & 3)*16;
      const u8* src = w2f8 + (size_t)r*1024 + k0 + (db ^ ((r&3)<<4));
      gload16(src, Bs8 + c*16);
    }
    __syncthreads();
    #pragma unroll
    for (int kk = 0; kk < 2; kk++){
      int kb = kk*32 + g4*8;
      long af[4];
      #pragma unroll
      for (int mi = 0; mi < 4; mi++){
        int row = wm*64 + mi*16 + lr;
        af[mi] = *(const long*)((const u8*)As8 + row*64 + (kb ^ ((row&3)<<4)));
      }
      #pragma unroll
      for (int ni = 0; ni < 4; ni++){
        int row = wn*64 + ni*16 + lr;
        long bfr = *(const long*)((const u8*)Bs8 + row*64 + (kb ^ ((row&3)<<4)));
        #pragma unroll
        for (int mi = 0; mi < 4; mi++)
          acc[mi][ni] = __builtin_amdgcn_mfma_f32_16x16x32_fp8_fp8(af[mi], bfr, acc[mi][ni], 0,0,0);
      }
    }
  }
  const float sc = 1.0f/1024.0f;   // undo W2*256 and H*4
  int ptbase = s_off >> 4;
  #pragma unroll
  for (int mi = 0; mi < 4; mi++){
    int pt = ptbase + blk*8 + wm*4 + mi;
    int sbase = pt*16;
    #pragma unroll
    for (int ni = 0; ni < 4; ni++){
      int d = wn*64 + ni*16 + lr;
      float bias = ab2[d];
      float lg[4];
      #pragma unroll
      for (int r = 0; r < 4; r++) lg[r] = acc[mi][ni][r]*sc + bias;
      float mx = fmaxf(fmaxf(lg[0],lg[1]), fmaxf(lg[2],lg[3]));
      mx = fmaxf(mx, __shfl_xor(mx, 16));
      mx = fmaxf(mx, __shfl_xor(mx, 32));
      float ev[4], ss = 0.f;
      #pragma unroll
      for (int r = 0; r < 4; r++){ ev[r] = __expf(lg[r]-mx); ss += ev[r]; }
      ss += __shfl_xor(ss, 16);
      ss += __shfl_xor(ss, 32);
      float inv = 1.0f/ss;
      float pa = 0.f;
      #pragma unroll
      for (int r = 0; r < 4; r++){
        int s = sbase + g4*4 + r;
        pa += ev[r]*inv*bf2f(val16[(size_t)s*256 + d]);
      }
      pa += __shfl_xor(pa, 16);
      pa += __shfl_xor(pa, 32);
      if (g4 == 0) aggT[(size_t)pt*256 + d] = pa;
    }
  }
}

// ---------------- final: out = end_w @ agg + end_b + value ----------------
__global__ __launch_bounds__(256) void final_kernel(
    const float* __restrict__ aggT, const float* __restrict__ endwT,
    const float* __restrict__ endb, const float* __restrict__ value,
    float* __restrict__ out)
{
  __shared__ float ags[32*257];
  int t = threadIdx.x;
  int tile = blockIdx.x & 63, b = blockIdx.x >> 6;
  int n0 = tile*32;
  for (int e = t; e < 32*256; e += 256){
    int nn = e >> 8, d = e & 255;
    ags[nn*257 + d] = aggT[(size_t)(b*Nv + n0 + nn)*256 + d];
  }
  __syncthreads();
  int cg = t >> 2, ng = t & 3;
  int co0 = cg*2, nb = ng*8;
  float acc[2][8];
  for (int i=0;i<2;i++){ float bb = endb[co0+i]; for (int j=0;j<8;j++) acc[i][j]=bb; }
  for (int d = 0; d < 256; d++){
    float w0 = endwT[d*128 + co0], w1 = endwT[d*128 + co0 + 1];
    #pragma unroll
    for (int j=0;j<8;j++){
      float av = ags[(nb+j)*257 + d];
      acc[0][j] += w0*av; acc[1][j] += w1*av;
    }
  }
  for (int i=0;i<2;i++){
    for (int j=0;j<8;j++){
      size_t o = (size_t)(b*128 + co0 + i)*Nv + n0 + nb + j;
      out[o] = acc[i][j] + value[o];
    }
  }
}

extern "C" void kernel_launch(void* const* d_in, const int* in_sizes, int n_in,
                              void* d_out, int out_size, void* d_ws, size_t ws_size,
                              hipStream_t stream)
{
  (void)in_sizes; (void)n_in; (void)out_size;
  const float* pos   = (const float*)d_in[0];
  const float* key   = (const float*)d_in[1];
  const float* query = (const float*)d_in[2];
  const float* mw1   = (const float*)d_in[3];
  const float* mb1   = (const float*)d_in[4];
  const float* mw2   = (const float*)d_in[5];
  const float* mb2   = (const float*)d_in[6];
  const float* mwsc  = (const float*)d_in[7];
  const float* mbsc  = (const float*)d_in[8];
  const float* wk    = (const float*)d_in[9];
  const float* bk    = (const float*)d_in[10];
  const float* wq    = (const float*)d_in[11];
  const float* bq    = (const float*)d_in[12];
  const float* wv    = (const float*)d_in[13];
  const float* bv    = (const float*)d_in[14];
  const float* pw1   = (const float*)d_in[15];
  const float* pg    = (const float*)d_in[17];
  const float* pbeta = (const float*)d_in[18];
  const float* pw2   = (const float*)d_in[19];
  const float* pb2   = (const float*)d_in[20];
  const float* aw1   = (const float*)d_in[21];
  const float* ag    = (const float*)d_in[23];
  const float* abeta = (const float*)d_in[24];
  const float* aw2   = (const float*)d_in[25];
  const float* ab2   = (const float*)d_in[26];
  const float* endw  = (const float*)d_in[27];
  const float* endb  = (const float*)d_in[28];
  float* out = (float*)d_out;

  char* wsb = (char*)d_ws;
  size_t off = 0;
  auto take = [&](size_t bytes)->char*{
    char* p = wsb + off; off += (bytes + 255) & ~(size_t)255; return p;
  };
  float* Mm      = (float*)take(65536*4);
  float* mu_sum  = (float*)take(256*4);     // zeroed
  float* rstat   = (float*)take(12*4);      // zeroed
  size_t zero_bytes = off;
  float* w1eff   = (float*)take(192*4);
  float* b1eff   = (float*)take(64*4);
  float* b1eff2  = (float*)take(1024*4);
  float* value   = (float*)take((size_t)524288*4);
  float* qT      = (float*)take((size_t)1048576*4);
  float* kT      = (float*)take((size_t)1048576*4);
  float* vT      = (float*)take((size_t)1048576*4);
  float* aggT    = (float*)take((size_t)1048576*4);
  float* wkT     = (float*)take(32768*4);
  float* wqT     = (float*)take(32768*4);
  float* wvT     = (float*)take(32768*4);
  float* endwT   = (float*)take(32768*4);
  float* mw1T    = (float*)take(32768*4);
  float* mw2T    = (float*)take(16384*4);
  float* mwscT   = (float*)take(32768*4);
  int*   idxb    = (int*)take(65536*4);
  ushortt* U16   = (ushortt*)take((size_t)16777216*2); // bf16 u
  ushortt* val16 = (ushortt*)take((size_t)16777216*2); // bf16 (v + pos_emb)
  ushortt* hposR = (ushortt*)take((size_t)4194304*2);  // bf16 Hpos [65536x64]
  ushortt* Mpart = (ushortt*)take((size_t)256*65536*2);// bf16 M partials (32 MB)
  ushortt* w1R   = (ushortt*)take((size_t)262144*2);
  u8*      w2f8  = (u8*)take((size_t)262144);          // fp8 W2 (scaled x256)
  ushortt* pw2R  = (ushortt*)take(16384*2);

  // H (fp8) gets whatever is left; chunk the sample dim to fit.
  size_t avail = (ws_size > off) ? (ws_size - off) : 0;
  int nch = 1;
  while (nch < 64 && ((size_t)(NSAMP/nch))*1024 > avail) nch <<= 1;
  int chunk = NSAMP / nch;          // >= 1024, multiple of 128
  u8* H = (u8*)(wsb + off);

  hipMemsetAsync(d_ws, 0, zero_bytes, stream);
  prep_weights<<<512,256,0,stream>>>(wk,wq,wv,endw,mw1,mw2,mwsc,aw2,pw2,
                                     wkT,wqT,wvT,endwT,mw1T,mw2T,mwscT,w2f8,pw2R);
  mlpres_kernel<<<128,256,0,stream>>>(key,query,mw1T,mb1,mw2T,mb2,mwscT,mbsc,value);
  proj_kernel<<<128,256,0,stream>>>(query,wqT,bq,qT);
  proj_kernel<<<128,256,0,stream>>>(key,wkT,bk,kT);
  proj_kernel<<<128,256,0,stream>>>(value,wvT,bv,vT);
  knn_kernel<<<1024,256,0,stream>>>(pos,idxb);
  bn1_stats<<<64,256,0,stream>>>(pos,idxb,rstat);
  bn1_final<<<1,64,0,stream>>>(rstat,pw1,pg,pbeta,w1eff,b1eff);
  hpos_kernel<<<2048,256,0,stream>>>(pos,idxb,w1eff,b1eff,hposR);
  gemm0_kernel<<<512,512,0,stream>>>(hposR,pw2R,pb2,idxb,qT,kT,vT,U16,val16,mu_sum);
  mm_kernel<<<256,512,0,stream>>>(U16,Mpart);
  mreduce_kernel<<<256,256,0,stream>>>(Mpart,Mm);
  bn2_final<<<1024,256,0,stream>>>(Mm,mu_sum,aw1,ag,abeta,w1R,b1eff2);
  for (int cc = 0; cc < nch; cc++){
    int s_off = cc*chunk;
    gemm1_kernel<<<dim3(chunk/128, 4),512,0,stream>>>(U16 + (size_t)s_off*256, w1R, b1eff2, H);
    gemm2_kernel<<<chunk/128,512,0,stream>>>(H, w2f8, ab2, val16, aggT, s_off);
  }
  final_kernel<<<128,256,0,stream>>>(aggT,endwT,endb,value,out);
}

// Round 9
// 310.841 us; speedup vs baseline: 4.7419x; 1.2629x over previous
//
#include <hip/hip_runtime.h>
#include <hip/hip_bf16.h>
#include <math.h>

#define Bv 2
#define Nv 2048
#define Cv 128
#define Dv 256
#define PHv 64
#define AHv 1024
#define Kv 16
#define NSAMP (Bv*Nv*Kv)   // 65536

typedef unsigned short ushortt;
typedef unsigned char u8;
typedef __attribute__((ext_vector_type(8))) short bf16x8;
typedef __attribute__((ext_vector_type(4))) float f32x4;

__device__ __forceinline__ float bf2f(ushortt h){
  union { unsigned int u; float f; } v; v.u = ((unsigned int)h) << 16; return v.f;
}
__device__ __forceinline__ ushortt f2bf(float f){
  union { unsigned int u; float f; } v; v.f = f;
  unsigned int r = v.u + 0x7FFFu + ((v.u >> 16) & 1u);
  return (ushortt)(r >> 16);
}
// f32 -> fp8 e4m3fn (OCP), RNE, clamp to 448, FTZ subnormals
__device__ __forceinline__ u8 f2fp8(float f){
  union { float f; unsigned int u; } v; v.f = f;
  unsigned int s = (v.u >> 24) & 0x80u;
  unsigned int a = v.u & 0x7FFFFFFFu;
  if (a > 0x43E00000u) a = 0x43E00000u;           // 448.0
  unsigned int r = a + 0x7FFFFu + ((a >> 20) & 1u);
  int e = (int)((r >> 23) & 0xFF) - 120;          // -127 + 7
  unsigned int m = (r >> 20) & 7u;
  if (e <= 0) return (u8)s;
  return (u8)(s | ((unsigned)e << 3) | m);
}

__device__ __forceinline__ void gload16(const void* g, void* l){
  __builtin_amdgcn_global_load_lds(
      (const __attribute__((address_space(1))) unsigned int*)g,
      (__attribute__((address_space(3))) unsigned int*)l, 16, 0, 0);
}

// ---------------- weight packs / casts ----------------
__global__ __launch_bounds__(256) void prep_weights(
    const float* __restrict__ wk, const float* __restrict__ wq,
    const float* __restrict__ wv, const float* __restrict__ endw,
    const float* __restrict__ mw1, const float* __restrict__ mw2,
    const float* __restrict__ mwsc, const float* __restrict__ aw2,
    const float* __restrict__ pw2,
    ushortt* __restrict__ wA16, ushortt* __restrict__ wB16, ushortt* __restrict__ wv16,
    float* __restrict__ endwT, u8* __restrict__ w2f8, ushortt* __restrict__ pw2R)
{
  int tid = blockIdx.x*256 + threadIdx.x;
  int stride = gridDim.x*256;
  // wA16 [768][256]: rows 0-127 mlp_w1; 128-383 wk (key half); 384-639 wq (query half); 640-767 zero
  for (int i = tid; i < 768*256; i += stride){
    int r = i >> 8, c = i & 255;
    float v;
    if (r < 128) v = mw1[r*256 + c];
    else if (r < 384) v = (c < 128) ? wk[(r-128)*128 + c] : 0.f;
    else if (r < 640) v = (c >= 128) ? wq[(r-384)*128 + (c-128)] : 0.f;
    else v = 0.f;
    wA16[i] = f2bf(v);
  }
  // wB16 [128][384]: cols 0-127 mlp_w2; 128-383 mlp_wsc
  for (int i = tid; i < 128*384; i += stride){
    int r = i / 384, c = i - r*384;
    float v = (c < 128) ? mw2[r*128 + c] : mwsc[r*256 + (c-128)];
    wB16[i] = f2bf(v);
  }
  // wv16 [256][128]
  for (int i = tid; i < 256*128; i += stride) wv16[i] = f2bf(wv[i]);
  // end_w (128,256) -> endwT[d*128+co]
  for (int i = tid; i < 128*256; i += stride){ int co = i>>8, d = i&255; endwT[d*128+co] = endw[i]; }
  // attn_w2 (256,1024) row-major fp8, scaled by 256
  for (int i = tid; i < 256*1024; i += stride) w2f8[i] = f2fp8(aw2[i]*256.f);
  // pos_w2 (256,64) row-major bf16
  for (int i = tid; i < 256*64; i += stride) pw2R[i] = f2bf(pw2[i]);
}

// ---------------- xcat: hx16[s][128..383] = bf16(cat(key,query)) ----------------
__global__ __launch_bounds__(256) void xcat_kernel(
    const float* __restrict__ key, const float* __restrict__ query,
    ushortt* __restrict__ hx16)
{
  __shared__ float xs[256*33];
  int t = threadIdx.x;
  int tile = blockIdx.x & 63, b = blockIdx.x >> 6;
  int n0 = tile*32;
  for (int e = t; e < 256*32; e += 256){
    int c = e >> 5, nn = e & 31;
    xs[c*33+nn] = (c < 128) ? key[(size_t)(b*128+c)*Nv + n0+nn]
                            : query[(size_t)(b*128+(c-128))*Nv + n0+nn];
  }
  __syncthreads();
  int nn = t & 31, cg = t >> 5;    // cg 0..7
  size_t s = (size_t)b*Nv + n0 + nn;
  __align__(16) ushortt tmp[32];
  #pragma unroll
  for (int cc = 0; cc < 32; cc++) tmp[cc] = f2bf(xs[(cg*32+cc)*33 + nn]);
  uint4* dst = (uint4*)&hx16[s*384 + 128 + cg*32];
  #pragma unroll
  for (int q = 0; q < 4; q++) dst[q] = ((uint4*)tmp)[q];
}

// ---------------- gemmA: [4096 x 768 x K=256] -> h(relu,bf16), kT, qT ----------------
__global__ __launch_bounds__(512) void gemmA_kernel(
    ushortt* __restrict__ hx16, const ushortt* __restrict__ wA16,
    const float* __restrict__ mb1, const float* __restrict__ bk, const float* __restrict__ bq,
    float* __restrict__ kT, float* __restrict__ qT)
{
  __shared__ ushortt As[128*64];   // 16 KB
  __shared__ ushortt Bs[256*64];   // 32 KB
  int t = threadIdx.x;
  int w = t >> 6, l = t & 63;
  int lr = l & 15, g4 = l >> 4;
  int wm = w >> 2, wn = w & 3;
  int s0 = blockIdx.x*128, n0 = blockIdx.y*256;

  f32x4 acc[4][4];
  #pragma unroll
  for (int i=0;i<4;i++) for (int j=0;j<4;j++) acc[i][j] = (f32x4){0.f,0.f,0.f,0.f};

  for (int kt = 0; kt < 4; kt++){
    int k0 = kt*64;
    __syncthreads();
    #pragma unroll
    for (int i = 0; i < 2; i++){
      int c = t + i*512;
      int r = c >> 3, db = (c & 7)*16;
      const ushortt* src = hx16 + (size_t)(s0+r)*384 + 128 + k0 + ((db ^ ((r&7)<<4))>>1);
      gload16(src, As + c*8);
    }
    #pragma unroll
    for (int i = 0; i < 4; i++){
      int c = t + i*512;
      int r = c >> 3, db = (c & 7)*16;
      const ushortt* src = wA16 + (size_t)(n0+r)*256 + k0 + ((db ^ ((r&7)<<4))>>1);
      gload16(src, Bs + c*8);
    }
    __syncthreads();
    #pragma unroll
    for (int kk = 0; kk < 2; kk++){
      int kb = kk*64 + g4*16;
      bf16x8 af[4];
      #pragma unroll
      for (int mi = 0; mi < 4; mi++){
        int row = wm*64 + mi*16 + lr;
        af[mi] = *(const bf16x8*)((const char*)As + row*128 + (kb ^ ((row&7)<<4)));
      }
      #pragma unroll
      for (int ni = 0; ni < 4; ni++){
        int row = wn*64 + ni*16 + lr;
        bf16x8 bfr = *(const bf16x8*)((const char*)Bs + row*128 + (kb ^ ((row&7)<<4)));
        #pragma unroll
        for (int mi = 0; mi < 4; mi++)
          acc[mi][ni] = __builtin_amdgcn_mfma_f32_16x16x32_bf16(af[mi], bfr, acc[mi][ni], 0,0,0);
      }
    }
  }
  #pragma unroll
  for (int ni = 0; ni < 4; ni++){
    int col = n0 + wn*64 + ni*16 + lr;
    if (col < 128){
      float bias = mb1[col];
      #pragma unroll
      for (int mi = 0; mi < 4; mi++){
        int rbase = s0 + wm*64 + mi*16 + g4*4;
        #pragma unroll
        for (int r = 0; r < 4; r++){
          float v = acc[mi][ni][r] + bias;
          v = v > 0.f ? v : 0.f;
          hx16[(size_t)(rbase+r)*384 + col] = f2bf(v);
        }
      }
    } else if (col < 384){
      float bias = bk[col-128];
      #pragma unroll
      for (int mi = 0; mi < 4; mi++){
        int rbase = s0 + wm*64 + mi*16 + g4*4;
        #pragma unroll
        for (int r = 0; r < 4; r++)
          kT[(size_t)(rbase+r)*256 + (col-128)] = acc[mi][ni][r] + bias;
      }
    } else if (col < 640){
      float bias = bq[col-384];
      #pragma unroll
      for (int mi = 0; mi < 4; mi++){
        int rbase = s0 + wm*64 + mi*16 + g4*4;
        #pragma unroll
        for (int r = 0; r < 4; r++)
          qT[(size_t)(rbase+r)*256 + (col-384)] = acc[mi][ni][r] + bias;
      }
    }
  }
}

// ---------------- gemmB: valueT = hx16 @ wB16^T + (b2+bsc) ; [4096 x 128 x K=384] ----------------
__global__ __launch_bounds__(512) void gemmB_kernel(
    const ushortt* __restrict__ hx16, const ushortt* __restrict__ wB16,
    const float* __restrict__ mb2, const float* __restrict__ mbsc,
    float* __restrict__ valueT, ushortt* __restrict__ value16)
{
  __shared__ ushortt As[128*64];   // 16 KB
  __shared__ ushortt Bs[128*64];   // 16 KB
  int t = threadIdx.x;
  int w = t >> 6, l = t & 63;
  int lr = l & 15, g4 = l >> 4;
  int wm = w >> 2, wn = w & 3;   // wm 0..1, wn 0..3
  int s0 = blockIdx.x*128;

  f32x4 acc[4][2];
  #pragma unroll
  for (int i=0;i<4;i++) for (int j=0;j<2;j++) acc[i][j] = (f32x4){0.f,0.f,0.f,0.f};

  for (int kt = 0; kt < 6; kt++){
    int k0 = kt*64;
    __syncthreads();
    #pragma unroll
    for (int i = 0; i < 2; i++){
      int c = t + i*512;
      int r = c >> 3, db = (c & 7)*16;
      const ushortt* src = hx16 + (size_t)(s0+r)*384 + k0 + ((db ^ ((r&7)<<4))>>1);
      gload16(src, As + c*8);
    }
    #pragma unroll
    for (int i = 0; i < 2; i++){
      int c = t + i*512;
      int r = c >> 3, db = (c & 7)*16;
      const ushortt* src = wB16 + (size_t)r*384 + k0 + ((db ^ ((r&7)<<4))>>1);
      gload16(src, Bs + c*8);
    }
    __syncthreads();
    #pragma unroll
    for (int kk = 0; kk < 2; kk++){
      int kb = kk*64 + g4*16;
      bf16x8 af[4];
      #pragma unroll
      for (int mi = 0; mi < 4; mi++){
        int row = wm*64 + mi*16 + lr;
        af[mi] = *(const bf16x8*)((const char*)As + row*128 + (kb ^ ((row&7)<<4)));
      }
      #pragma unroll
      for (int ni = 0; ni < 2; ni++){
        int row = wn*32 + ni*16 + lr;
        bf16x8 bfr = *(const bf16x8*)((const char*)Bs + row*128 + (kb ^ ((row&7)<<4)));
        #pragma unroll
        for (int mi = 0; mi < 4; mi++)
          acc[mi][ni] = __builtin_amdgcn_mfma_f32_16x16x32_bf16(af[mi], bfr, acc[mi][ni], 0,0,0);
      }
    }
  }
  #pragma unroll
  for (int ni = 0; ni < 2; ni++){
    int col = wn*32 + ni*16 + lr;
    float bias = mb2[col] + mbsc[col];
    #pragma unroll
    for (int mi = 0; mi < 4; mi++){
      int rbase = s0 + wm*64 + mi*16 + g4*4;
      #pragma unroll
      for (int r = 0; r < 4; r++){
        float v = acc[mi][ni][r] + bias;
        valueT[(size_t)(rbase+r)*128 + col] = v;
        value16[(size_t)(rbase+r)*128 + col] = f2bf(v);
      }
    }
  }
}

// ---------------- gemmC: vT = value16 @ wv16^T + bv ; [4096 x 256 x K=128] ----------------
__global__ __launch_bounds__(512) void gemmC_kernel(
    const ushortt* __restrict__ value16, const ushortt* __restrict__ wv16,
    const float* __restrict__ bv, float* __restrict__ vT)
{
  __shared__ ushortt As[128*64];
  __shared__ ushortt Bs[256*64];
  int t = threadIdx.x;
  int w = t >> 6, l = t & 63;
  int lr = l & 15, g4 = l >> 4;
  int wm = w >> 2, wn = w & 3;
  int s0 = blockIdx.x*128;

  f32x4 acc[4][4];
  #pragma unroll
  for (int i=0;i<4;i++) for (int j=0;j<4;j++) acc[i][j] = (f32x4){0.f,0.f,0.f,0.f};

  for (int kt = 0; kt < 2; kt++){
    int k0 = kt*64;
    __syncthreads();
    #pragma unroll
    for (int i = 0; i < 2; i++){
      int c = t + i*512;
      int r = c >> 3, db = (c & 7)*16;
      const ushortt* src = value16 + (size_t)(s0+r)*128 + k0 + ((db ^ ((r&7)<<4))>>1);
      gload16(src, As + c*8);
    }
    #pragma unroll
    for (int i = 0; i < 4; i++){
      int c = t + i*512;
      int r = c >> 3, db = (c & 7)*16;
      const ushortt* src = wv16 + (size_t)r*128 + k0 + ((db ^ ((r&7)<<4))>>1);
      gload16(src, Bs + c*8);
    }
    __syncthreads();
    #pragma unroll
    for (int kk = 0; kk < 2; kk++){
      int kb = kk*64 + g4*16;
      bf16x8 af[4];
      #pragma unroll
      for (int mi = 0; mi < 4; mi++){
        int row = wm*64 + mi*16 + lr;
        af[mi] = *(const bf16x8*)((const char*)As + row*128 + (kb ^ ((row&7)<<4)));
      }
      #pragma unroll
      for (int ni = 0; ni < 4; ni++){
        int row = wn*64 + ni*16 + lr;
        bf16x8 bfr = *(const bf16x8*)((const char*)Bs + row*128 + (kb ^ ((row&7)<<4)));
        #pragma unroll
        for (int mi = 0; mi < 4; mi++)
          acc[mi][ni] = __builtin_amdgcn_mfma_f32_16x16x32_bf16(af[mi], bfr, acc[mi][ni], 0,0,0);
      }
    }
  }
  #pragma unroll
  for (int ni = 0; ni < 4; ni++){
    int col = wn*64 + ni*16 + lr;
    float bias = bv[col];
    #pragma unroll
    for (int mi = 0; mi < 4; mi++){
      int rbase = s0 + wm*64 + mi*16 + g4*4;
      #pragma unroll
      for (int r = 0; r < 4; r++)
        vT[(size_t)(rbase+r)*256 + col] = acc[mi][ni][r] + bias;
    }
  }
}

// ---------------- KNN: wave-per-point, pure shfl ----------------
__global__ __launch_bounds__(256) void knn_kernel(const float* __restrict__ pos, int* __restrict__ idx)
{
  int t = threadIdx.x;
  int w = t >> 6, l = t & 63;
  int p = blockIdx.x*4 + w;
  int i = p & (Nv-1), b = p >> 11;
  const float* px = pos + (size_t)b*3*Nv;
  float pix = px[i], piy = px[Nv+i], piz = px[2*Nv+i];
  float sqi = pix*pix + piy*piy + piz*piz;
  float ds[32];
  #pragma unroll
  for (int jj = 0; jj < 32; jj++){
    int j = jj*64 + l;
    float qx = px[j], qy = px[Nv+j], qz = px[2*Nv+j];
    float sqj = qx*qx + qy*qy + qz*qz;
    float dot = pix*qx + piy*qy + piz*qz;
    ds[jj] = (sqi + sqj) - 2.0f*dot;
  }
  #pragma unroll 1
  for (int it = 0; it < 16; it++){
    float bv = 3.4e38f; int bj = 0x7FFFFFFF;
    #pragma unroll
    for (int jj = 0; jj < 32; jj++){
      int j = jj*64 + l;
      bool c = ds[jj] < bv;
      bv = c ? ds[jj] : bv;
      bj = c ? j : bj;
    }
    #pragma unroll
    for (int off = 32; off; off >>= 1){
      float ov = __shfl_xor(bv, off);
      int oj = __shfl_xor(bj, off);
      if (ov < bv || (ov == bv && oj < bj)){ bv = ov; bj = oj; }
    }
    if (l == 0) idx[(size_t)p*16 + it] = bj;
    #pragma unroll
    for (int jj = 0; jj < 32; jj++){
      if (jj*64 + l == bj) ds[jj] = 3.4e38f;
    }
  }
}

// ---------------- pos-BN stats ----------------
__global__ __launch_bounds__(256) void bn1_stats(const float* __restrict__ pos,
    const int* __restrict__ idx, float* __restrict__ rstat)
{
  int tid = blockIdx.x*256 + threadIdx.x;
  int stride = gridDim.x*256;
  float s[9] = {0,0,0,0,0,0,0,0,0};
  for (int e = tid; e < NSAMP; e += stride){
    int b = e >> 15;
    int rem = e & 32767;
    int n = rem >> 4, k = rem & 15;
    int j = idx[(size_t)(b*Nv+n)*16 + k];
    const float* px = pos + (size_t)b*3*Nv;
    float rx = px[n]-px[j], ry = px[Nv+n]-px[Nv+j], rz = px[2*Nv+n]-px[2*Nv+j];
    s[0]+=rx; s[1]+=ry; s[2]+=rz;
    s[3]+=rx*rx; s[4]+=rx*ry; s[5]+=rx*rz; s[6]+=ry*ry; s[7]+=ry*rz; s[8]+=rz*rz;
  }
  for (int off=32; off; off>>=1)
    for (int q=0;q<9;q++) s[q] += __shfl_xor(s[q], off);
  if ((threadIdx.x & 63) == 0)
    for (int q=0;q<9;q++) atomicAdd(&rstat[q], s[q]);
}

// ---------------- fold pos BN ----------------
__global__ void bn1_final(const float* __restrict__ rstat,
    const float* __restrict__ pw1,
    const float* __restrict__ pg, const float* __restrict__ pbeta,
    float* __restrict__ w1eff, float* __restrict__ b1eff)
{
  int c = threadIdx.x; // 64
  float inv = 1.0f/(float)NSAMP;
  float mux = rstat[0]*inv, muy = rstat[1]*inv, muz = rstat[2]*inv;
  float xx = rstat[3]*inv, xy = rstat[4]*inv, xz = rstat[5]*inv;
  float yy = rstat[6]*inv, yz = rstat[7]*inv, zz = rstat[8]*inv;
  float w0 = pw1[c*3], w1 = pw1[c*3+1], w2 = pw1[c*3+2];
  float dot = w0*mux + w1*muy + w2*muz;
  float quad = w0*w0*xx + w1*w1*yy + w2*w2*zz + 2.f*(w0*w1*xy + w0*w2*xz + w1*w2*yz);
  float var = quad - dot*dot;
  float s = pg[c] * rsqrtf(var + 1e-5f);
  w1eff[c*3]   = w0*s;
  w1eff[c*3+1] = w1*s;
  w1eff[c*3+2] = w2*s;
  b1eff[c] = pbeta[c] - dot*s;
}

// ---------------- Hpos = relu(BN(W1 r)) -> bf16 [65536 x 64] ----------------
__global__ __launch_bounds__(256) void hpos_kernel(
    const float* __restrict__ pos, const int* __restrict__ idx,
    const float* __restrict__ w1eff, const float* __restrict__ b1eff,
    ushortt* __restrict__ hposR)
{
  int t = threadIdx.x;
  int s = blockIdx.x*32 + (t>>3);
  int c0 = (t&7)*8;
  int ptv = s >> 4;
  int n = ptv & (Nv-1), b = ptv >> 11;
  int j = idx[s];
  const float* px = pos + (size_t)b*3*Nv;
  float rx = px[n]-px[j], ry = px[Nv+n]-px[Nv+j], rz = px[2*Nv+n]-px[2*Nv+j];
  ushortt outv[8];
  #pragma unroll
  for (int e = 0; e < 8; e++){
    int c = c0+e;
    float v = b1eff[c] + w1eff[c*3]*rx + w1eff[c*3+1]*ry + w1eff[c*3+2]*rz;
    outv[e] = f2bf(v > 0.f ? v : 0.f);
  }
  *(uint4*)&hposR[(size_t)s*64 + c0] = *(uint4*)outv;
}

// ---------------- GEMM0: pe = Hpos @ pw2^T + pb2; epilogue: U16, val16, mu ----------------
__global__ __launch_bounds__(512) void gemm0_kernel(
    const ushortt* __restrict__ hposR, const ushortt* __restrict__ pw2R,
    const float* __restrict__ pb2, const int* __restrict__ idx,
    const float* __restrict__ qT, const float* __restrict__ kT, const float* __restrict__ vT,
    ushortt* __restrict__ U16, ushortt* __restrict__ val16, float* __restrict__ mu_sum)
{
  __shared__ ushortt As[128*64];   // 16 KB
  __shared__ ushortt Bs[256*64];   // 32 KB
  __shared__ float mured[8*256];   // 8 KB
  int t = threadIdx.x;
  int w = t >> 6, l = t & 63;
  int lr = l & 15, g4 = l >> 4;
  int wm = w >> 2, wn = w & 3;
  int s0 = blockIdx.x*128;

  #pragma unroll
  for (int i = 0; i < 2; i++){
    int c = t + i*512;
    int r = c >> 3, db = (c & 7)*16;
    const ushortt* src = hposR + (size_t)(s0+r)*64 + ((db ^ ((r&7)<<4))>>1);
    gload16(src, As + c*8);
  }
  #pragma unroll
  for (int i = 0; i < 4; i++){
    int c = t + i*512;
    int r = c >> 3, db = (c & 7)*16;
    const ushortt* src = pw2R + (size_t)r*64 + ((db ^ ((r&7)<<4))>>1);
    gload16(src, Bs + c*8);
  }
  __syncthreads();

  f32x4 acc[4][4];
  #pragma unroll
  for (int i=0;i<4;i++) for (int j=0;j<4;j++) acc[i][j] = (f32x4){0.f,0.f,0.f,0.f};
  #pragma unroll
  for (int kk = 0; kk < 2; kk++){
    int kb = kk*64 + g4*16;
    bf16x8 af[4];
    #pragma unroll
    for (int mi = 0; mi < 4; mi++){
      int row = wm*64 + mi*16 + lr;
      af[mi] = *(const bf16x8*)((const char*)As + row*128 + (kb ^ ((row&7)<<4)));
    }
    #pragma unroll
    for (int ni = 0; ni < 4; ni++){
      int row = wn*64 + ni*16 + lr;
      bf16x8 bfr = *(const bf16x8*)((const char*)Bs + row*128 + (kb ^ ((row&7)<<4)));
      #pragma unroll
      for (int mi = 0; mi < 4; mi++)
        acc[mi][ni] = __builtin_amdgcn_mfma_f32_16x16x32_bf16(af[mi], bfr, acc[mi][ni], 0,0,0);
    }
  }

  float musum[4] = {0.f,0.f,0.f,0.f};
  __align__(16) float pb2v[4];
  #pragma unroll
  for (int ni = 0; ni < 4; ni++) pb2v[ni] = pb2[wn*64 + ni*16 + lr];
  #pragma unroll
  for (int mi = 0; mi < 4; mi++){
    #pragma unroll
    for (int r4 = 0; r4 < 4; r4++){
      int s = s0 + wm*64 + mi*16 + g4*4 + r4;
      int ptv = s >> 4;
      int b = s >> 15;
      int j = idx[s];
      const float* krow = kT + (size_t)(b*Nv + j)*256;
      const float* qrow = qT + (size_t)ptv*256;
      const float* vrow = vT + (size_t)ptv*256;
      #pragma unroll
      for (int ni = 0; ni < 4; ni++){
        int d = wn*64 + ni*16 + lr;
        float pe = acc[mi][ni][r4] + pb2v[ni];
        float u = qrow[d] - krow[d] + pe;
        U16[(size_t)s*256 + d] = f2bf(u);
        val16[(size_t)s*256 + d] = f2bf(vrow[d] + pe);
        musum[ni] += u;
      }
    }
  }
  #pragma unroll
  for (int ni = 0; ni < 4; ni++)
    mured[(wm*4+g4)*256 + wn*64 + ni*16 + lr] = musum[ni];
  __syncthreads();
  if (t < 256){
    float ssum = 0.f;
    #pragma unroll
    for (int q = 0; q < 8; q++) ssum += mured[q*256 + t];
    atomicAdd(&mu_sum[t], ssum);
  }
}

// ---------------- M partials ----------------
__global__ __launch_bounds__(512) void mm_kernel(const ushortt* __restrict__ U16,
                                                 ushortt* __restrict__ Mpart)
{
  __shared__ ushortt Ut[256*64];   // 32 KB
  int t = threadIdx.x;
  int w = t >> 6, l = t & 63;
  int lr = l & 15, g4 = l >> 4;
  int wm = w >> 2, wn = w & 3;
  int c_my = ((w & 3)*64 + l);
  int sg = w >> 2;
  int blk = blockIdx.x;
  int sstart = blk*256;

  f32x4 acc[8][4];
  #pragma unroll
  for (int i=0;i<8;i++) for (int j=0;j<4;j++) acc[i][j] = (f32x4){0.f,0.f,0.f,0.f};

  for (int st = 0; st < 4; st++){
    int sb = sstart + st*64;
    __syncthreads();
    #pragma unroll
    for (int g = 0; g < 4; g++){
      int s8 = sg*32 + g*8;
      ushortt vals[8];
      #pragma unroll
      for (int e = 0; e < 8; e++)
        vals[e] = U16[(size_t)(sb + s8 + e)*256 + c_my];
      unsigned int p0 = (unsigned int)vals[0] | ((unsigned int)vals[1] << 16);
      unsigned int p1 = (unsigned int)vals[2] | ((unsigned int)vals[3] << 16);
      unsigned int p2 = (unsigned int)vals[4] | ((unsigned int)vals[5] << 16);
      unsigned int p3 = (unsigned int)vals[6] | ((unsigned int)vals[7] << 16);
      uint4 pk = make_uint4(p0,p1,p2,p3);
      *(uint4*)((char*)Ut + c_my*128 + ((s8*2) ^ ((c_my&7)<<4))) = pk;
    }
    __syncthreads();
    #pragma unroll
    for (int kk = 0; kk < 2; kk++){
      int kb = kk*64 + g4*16;
      bf16x8 af[8];
      #pragma unroll
      for (int ci = 0; ci < 8; ci++){
        int row = wm*128 + ci*16 + lr;
        af[ci] = *(const bf16x8*)((const char*)Ut + row*128 + (kb ^ ((row&7)<<4)));
      }
      #pragma unroll
      for (int cj = 0; cj < 4; cj++){
        int row = wn*64 + cj*16 + lr;
        bf16x8 bfr = *(const bf16x8*)((const char*)Ut + row*128 + (kb ^ ((row&7)<<4)));
        #pragma unroll
        for (int ci = 0; ci < 8; ci++)
          acc[ci][cj] = __builtin_amdgcn_mfma_f32_16x16x32_bf16(af[ci], bfr, acc[ci][cj], 0,0,0);
      }
    }
  }
  ushortt* dst = Mpart + (size_t)blk*65536;
  #pragma unroll
  for (int ci = 0; ci < 8; ci++){
    #pragma unroll
    for (int cj = 0; cj < 4; cj++){
      int c2 = wn*64 + cj*16 + lr;
      #pragma unroll
      for (int r = 0; r < 4; r++){
        int c1 = wm*128 + ci*16 + g4*4 + r;
        dst[(size_t)c1*256 + c2] = f2bf(acc[ci][cj][r]);
      }
    }
  }
}

__global__ __launch_bounds__(256) void mreduce_kernel(const ushortt* __restrict__ Mpart,
                                                      float* __restrict__ Mm)
{
  int i = blockIdx.x*256 + threadIdx.x;
  float s = 0.f;
  for (int p = 0; p < 256; p++) s += bf2f(Mpart[(size_t)p*65536 + i]);
  Mm[i] = s;
}

// ---------------- fold attn BN into w1R (bf16) + b1eff2 ----------------
__global__ __launch_bounds__(256) void bn2_final(
    const float* __restrict__ Mm, const float* __restrict__ mu_sum,
    const float* __restrict__ aw1,
    const float* __restrict__ ag, const float* __restrict__ abeta,
    ushortt* __restrict__ w1R, float* __restrict__ b1eff2)
{
  __shared__ float wrow[256];
  __shared__ float red[8];
  __shared__ float s2s;
  int t = threadIdx.x;
  int ch = blockIdx.x;
  wrow[t] = aw1[(size_t)ch*256 + t];
  __syncthreads();
  float colacc = 0.f;
  for (int r = 0; r < 256; r++) colacc += wrow[r] * Mm[(size_t)r*256 + t];
  float inv = 1.0f/(float)NSAMP;
  float qpart = colacc * wrow[t] * inv;
  float dpart = wrow[t] * mu_sum[t] * inv;
  for (int off=32; off; off>>=1){ qpart += __shfl_xor(qpart, off); dpart += __shfl_xor(dpart, off); }
  if ((t&63)==0){ red[t>>6] = qpart; red[4 + (t>>6)] = dpart; }
  __syncthreads();
  if (t == 0){
    float quad = red[0]+red[1]+red[2]+red[3];
    float dot  = red[4]+red[5]+red[6]+red[7];
    float var = quad - dot*dot;
    float s2 = ag[ch] * rsqrtf(var + 1e-5f);
    b1eff2[ch] = abeta[ch] - dot*s2;
    s2s = s2;
  }
  __syncthreads();
  w1R[(size_t)ch*256 + t] = f2bf(wrow[t]*s2s);
}

// ---------------- GEMM1: H = fp8(4*relu(U16 @ W1^T + b)) ; [chunk x 1024] fp8 ----------------
__global__ __launch_bounds__(512) void gemm1_kernel(
    const ushortt* __restrict__ U16c, const ushortt* __restrict__ w1R,
    const float* __restrict__ b1eff2, u8* __restrict__ H)
{
  __shared__ ushortt As[128*64];   // 16 KB
  __shared__ ushortt Bs[256*64];   // 32 KB (reused as fp8 repack buffer)
  int t = threadIdx.x;
  int w = t >> 6, l = t & 63;
  int lr = l & 15, g4 = l >> 4;
  int wm = w >> 2, wn = w & 3;
  int s0 = blockIdx.x*128, n0 = blockIdx.y*256;

  f32x4 acc[4][4];
  #pragma unroll
  for (int i=0;i<4;i++) for (int j=0;j<4;j++) acc[i][j] = (f32x4){0.f,0.f,0.f,0.f};

  for (int kt = 0; kt < 4; kt++){
    int k0 = kt*64;
    __syncthreads();
    #pragma unroll
    for (int i = 0; i < 2; i++){
      int c = t + i*512;
      int r = c >> 3, db = (c & 7)*16;
      const ushortt* src = U16c + (size_t)(s0+r)*256 + k0 + ((db ^ ((r&7)<<4))>>1);
      gload16(src, As + c*8);
    }
    #pragma unroll
    for (int i = 0; i < 4; i++){
      int c = t + i*512;
      int r = c >> 3, db = (c & 7)*16;
      const ushortt* src = w1R + (size_t)(n0+r)*256 + k0 + ((db ^ ((r&7)<<4))>>1);
      gload16(src, Bs + c*8);
    }
    __syncthreads();
    #pragma unroll
    for (int kk = 0; kk < 2; kk++){
      int kb = kk*64 + g4*16;
      bf16x8 af[4];
      #pragma unroll
      for (int mi = 0; mi < 4; mi++){
        int row = wm*64 + mi*16 + lr;
        af[mi] = *(const bf16x8*)((const char*)As + row*128 + (kb ^ ((row&7)<<4)));
      }
      #pragma unroll
      for (int ni = 0; ni < 4; ni++){
        int row = wn*64 + ni*16 + lr;
        bf16x8 bfr = *(const bf16x8*)((const char*)Bs + row*128 + (kb ^ ((row&7)<<4)));
        #pragma unroll
        for (int mi = 0; mi < 4; mi++)
          acc[mi][ni] = __builtin_amdgcn_mfma_f32_16x16x32_bf16(af[mi], bfr, acc[mi][ni], 0,0,0);
      }
    }
  }
  // epilogue: relu -> fp8(4x) -> LDS repack (reuse Bs) -> coalesced 16B stores
  __syncthreads();
  u8* rep = (u8*)Bs;               // 128 x 256 fp8 = 32 KB
  #pragma unroll
  for (int ni = 0; ni < 4; ni++){
    int colc = wn*64 + ni*16 + lr;
    float bias = b1eff2[n0 + colc];
    #pragma unroll
    for (int mi = 0; mi < 4; mi++){
      int sloc = wm*64 + mi*16 + g4*4;
      #pragma unroll
      for (int r = 0; r < 4; r++){
        float v = acc[mi][ni][r] + bias;
        v = v > 0.f ? v : 0.f;
        rep[(sloc+r)*256 + colc] = f2fp8(4.f*v);
      }
    }
  }
  __syncthreads();
  #pragma unroll
  for (int i = 0; i < 4; i++){
    int e = t + i*512;
    int row = e >> 4, off = (e & 15)*16;
    *(uint4*)&H[(size_t)(s0+row)*1024 + n0 + off] = *(const uint4*)(rep + e*16);
  }
}

// ---------------- GEMM2 (fp8): logits = (H @ W2f8^T)/1024 + ab2 ; fused softmax + agg ----------------
__global__ __launch_bounds__(512) void gemm2_kernel(
    const u8* __restrict__ H, const u8* __restrict__ w2f8,
    const float* __restrict__ ab2, const ushortt* __restrict__ val16,
    float* __restrict__ aggT, int s_off)
{
  __shared__ u8 As8[128*64];   // 8 KB
  __shared__ u8 Bs8[256*64];   // 16 KB
  int t = threadIdx.x;
  int w = t >> 6, l = t & 63;
  int lr = l & 15, g4 = l >> 4;
  int wm = w >> 2, wn = w & 3;
  int blk = blockIdx.x;
  int s0 = blk*128;

  f32x4 acc[4][4];
  #pragma unroll
  for (int i=0;i<4;i++) for (int j=0;j<4;j++) acc[i][j] = (f32x4){0.f,0.f,0.f,0.f};

  for (int kt = 0; kt < 16; kt++){
    int k0 = kt*64;
    __syncthreads();
    {
      int c = t;                    // 512 granules of 16B
      int r = c >> 2, db = (c & 3)*16;
      const u8* src = H + (size_t)(s0+r)*1024 + k0 + (db ^ ((r&3)<<4));
      gload16(src, As8 + c*16);
    }
    #pragma unroll
    for (int i = 0; i < 2; i++){
      int c = t + i*512;
      int r = c >> 2, db = (c & 3)*16;
      const u8* src = w2f8 + (size_t)r*1024 + k0 + (db ^ ((r&3)<<4));
      gload16(src, Bs8 + c*16);
    }
    __syncthreads();
    #pragma unroll
    for (int kk = 0; kk < 2; kk++){
      int kb = kk*32 + g4*8;
      long af[4];
      #pragma unroll
      for (int mi = 0; mi < 4; mi++){
        int row = wm*64 + mi*16 + lr;
        af[mi] = *(const long*)((const u8*)As8 + row*64 + (kb ^ ((row&3)<<4)));
      }
      #pragma unroll
      for (int ni = 0; ni < 4; ni++){
        int row = wn*64 + ni*16 + lr;
        long bfr = *(const long*)((const u8*)Bs8 + row*64 + (kb ^ ((row&3)<<4)));
        #pragma unroll
        for (int mi = 0; mi < 4; mi++)
          acc[mi][ni] = __builtin_amdgcn_mfma_f32_16x16x32_fp8_fp8(af[mi], bfr, acc[mi][ni], 0,0,0);
      }
    }
  }
  const float sc = 1.0f/1024.0f;   // undo W2*256 and H*4
  int ptbase = s_off >> 4;
  #pragma unroll
  for (int mi = 0; mi < 4; mi++){
    int pt = ptbase + blk*8 + wm*4 + mi;
    int sbase = pt*16;
    #pragma unroll
    for (int ni = 0; ni < 4; ni++){
      int d = wn*64 + ni*16 + lr;
      float bias = ab2[d];
      float lg[4];
      #pragma unroll
      for (int r = 0; r < 4; r++) lg[r] = acc[mi][ni][r]*sc + bias;
      float mx = fmaxf(fmaxf(lg[0],lg[1]), fmaxf(lg[2],lg[3]));
      mx = fmaxf(mx, __shfl_xor(mx, 16));
      mx = fmaxf(mx, __shfl_xor(mx, 32));
      float ev[4], ss = 0.f;
      #pragma unroll
      for (int r = 0; r < 4; r++){ ev[r] = __expf(lg[r]-mx); ss += ev[r]; }
      ss += __shfl_xor(ss, 16);
      ss += __shfl_xor(ss, 32);
      float inv = 1.0f/ss;
      float pa = 0.f;
      #pragma unroll
      for (int r = 0; r < 4; r++){
        int s = sbase + g4*4 + r;
        pa += ev[r]*inv*bf2f(val16[(size_t)s*256 + d]);
      }
      pa += __shfl_xor(pa, 16);
      pa += __shfl_xor(pa, 32);
      if (g4 == 0) aggT[(size_t)pt*256 + d] = pa;
    }
  }
}

// ---------------- final: out = end_w @ agg + end_b + valueT ----------------
__global__ __launch_bounds__(256) void final_kernel(
    const float* __restrict__ aggT, const float* __restrict__ endwT,
    const float* __restrict__ endb, const float* __restrict__ valueT,
    float* __restrict__ out)
{
  __shared__ float ags[32*257];
  int t = threadIdx.x;
  int tile = blockIdx.x & 63, b = blockIdx.x >> 6;
  int n0 = tile*32;
  for (int e = t; e < 32*256; e += 256){
    int nn = e >> 8, d = e & 255;
    ags[nn*257 + d] = aggT[(size_t)(b*Nv + n0 + nn)*256 + d];
  }
  __syncthreads();
  int cg = t >> 2, ng = t & 3;
  int co0 = cg*2, nb = ng*8;
  float acc[2][8];
  for (int i=0;i<2;i++){ float bb = endb[co0+i]; for (int j=0;j<8;j++) acc[i][j]=bb; }
  for (int d = 0; d < 256; d++){
    float w0 = endwT[d*128 + co0], w1 = endwT[d*128 + co0 + 1];
    #pragma unroll
    for (int j=0;j<8;j++){
      float av = ags[(nb+j)*257 + d];
      acc[0][j] += w0*av; acc[1][j] += w1*av;
    }
  }
  for (int i=0;i<2;i++){
    for (int j=0;j<8;j++){
      int n = n0 + nb + j;
      size_t o = (size_t)(b*128 + co0 + i)*Nv + n;
      out[o] = acc[i][j] + valueT[(size_t)(b*Nv + n)*128 + co0 + i];
    }
  }
}

extern "C" void kernel_launch(void* const* d_in, const int* in_sizes, int n_in,
                              void* d_out, int out_size, void* d_ws, size_t ws_size,
                              hipStream_t stream)
{
  (void)in_sizes; (void)n_in; (void)out_size;
  const float* pos   = (const float*)d_in[0];
  const float* key   = (const float*)d_in[1];
  const float* query = (const float*)d_in[2];
  const float* mw1   = (const float*)d_in[3];
  const float* mb1   = (const float*)d_in[4];
  const float* mw2   = (const float*)d_in[5];
  const float* mb2   = (const float*)d_in[6];
  const float* mwsc  = (const float*)d_in[7];
  const float* mbsc  = (const float*)d_in[8];
  const float* wk    = (const float*)d_in[9];
  const float* bk    = (const float*)d_in[10];
  const float* wq    = (const float*)d_in[11];
  const float* bq    = (const float*)d_in[12];
  const float* wv    = (const float*)d_in[13];
  const float* bv    = (const float*)d_in[14];
  const float* pw1   = (const float*)d_in[15];
  const float* pg    = (const float*)d_in[17];
  const float* pbeta = (const float*)d_in[18];
  const float* pw2   = (const float*)d_in[19];
  const float* pb2   = (const float*)d_in[20];
  const float* aw1   = (const float*)d_in[21];
  const float* ag    = (const float*)d_in[23];
  const float* abeta = (const float*)d_in[24];
  const float* aw2   = (const float*)d_in[25];
  const float* ab2   = (const float*)d_in[26];
  const float* endw  = (const float*)d_in[27];
  const float* endb  = (const float*)d_in[28];
  float* out = (float*)d_out;

  char* wsb = (char*)d_ws;
  size_t off = 0;
  auto take = [&](size_t bytes)->char*{
    char* p = wsb + off; off += (bytes + 255) & ~(size_t)255; return p;
  };
  float* Mm      = (float*)take(65536*4);
  float* mu_sum  = (float*)take(256*4);     // zeroed
  float* rstat   = (float*)take(12*4);      // zeroed
  size_t zero_bytes = off;
  float* w1eff   = (float*)take(192*4);
  float* b1eff   = (float*)take(64*4);
  float* b1eff2  = (float*)take(1024*4);
  float* valueT  = (float*)take((size_t)524288*4);     // [4096 x 128] f32
  float* qT      = (float*)take((size_t)1048576*4);
  float* kT      = (float*)take((size_t)1048576*4);
  float* vT      = (float*)take((size_t)1048576*4);
  float* aggT    = (float*)take((size_t)1048576*4);
  float* endwT   = (float*)take(32768*4);
  int*   idxb    = (int*)take(65536*4);
  ushortt* hx16  = (ushortt*)take((size_t)4096*384*2); // [4096 x 384] bf16 (h | x)
  ushortt* value16=(ushortt*)take((size_t)524288*2);   // [4096 x 128] bf16
  ushortt* wA16  = (ushortt*)take((size_t)768*256*2);
  ushortt* wB16  = (ushortt*)take((size_t)128*384*2);
  ushortt* wv16  = (ushortt*)take((size_t)256*128*2);
  ushortt* U16   = (ushortt*)take((size_t)16777216*2); // bf16 u
  ushortt* val16 = (ushortt*)take((size_t)16777216*2); // bf16 (v + pos_emb)
  ushortt* hposR = (ushortt*)take((size_t)4194304*2);  // bf16 Hpos [65536x64]
  ushortt* Mpart = (ushortt*)take((size_t)256*65536*2);// bf16 M partials (32 MB)
  ushortt* w1R   = (ushortt*)take((size_t)262144*2);
  u8*      w2f8  = (u8*)take((size_t)262144);          // fp8 W2 (scaled x256)
  ushortt* pw2R  = (ushortt*)take(16384*2);

  // H (fp8) gets whatever is left; chunk the sample dim to fit.
  size_t avail = (ws_size > off) ? (ws_size - off) : 0;
  int nch = 1;
  while (nch < 64 && ((size_t)(NSAMP/nch))*1024 > avail) nch <<= 1;
  int chunk = NSAMP / nch;          // >= 1024, multiple of 128
  u8* H = (u8*)(wsb + off);

  hipMemsetAsync(d_ws, 0, zero_bytes, stream);
  prep_weights<<<512,256,0,stream>>>(wk,wq,wv,endw,mw1,mw2,mwsc,aw2,pw2,
                                     wA16,wB16,wv16,endwT,w2f8,pw2R);
  xcat_kernel<<<128,256,0,stream>>>(key,query,hx16);
  knn_kernel<<<1024,256,0,stream>>>(pos,idxb);
  gemmA_kernel<<<dim3(32,3),512,0,stream>>>(hx16,wA16,mb1,bk,bq,kT,qT);
  gemmB_kernel<<<32,512,0,stream>>>(hx16,wB16,mb2,mbsc,valueT,value16);
  gemmC_kernel<<<32,512,0,stream>>>(value16,wv16,bv,vT);
  bn1_stats<<<64,256,0,stream>>>(pos,idxb,rstat);
  bn1_final<<<1,64,0,stream>>>(rstat,pw1,pg,pbeta,w1eff,b1eff);
  hpos_kernel<<<2048,256,0,stream>>>(pos,idxb,w1eff,b1eff,hposR);
  gemm0_kernel<<<512,512,0,stream>>>(hposR,pw2R,pb2,idxb,qT,kT,vT,U16,val16,mu_sum);
  mm_kernel<<<256,512,0,stream>>>(U16,Mpart);
  mreduce_kernel<<<256,256,0,stream>>>(Mpart,Mm);
  bn2_final<<<1024,256,0,stream>>>(Mm,mu_sum,aw1,ag,abeta,w1R,b1eff2);
  for (int cc = 0; cc < nch; cc++){
    int s_off = cc*chunk;
    gemm1_kernel<<<dim3(chunk/128, 4),512,0,stream>>>(U16 + (size_t)s_off*256, w1R, b1eff2, H);
    gemm2_kernel<<<chunk/128,512,0,stream>>>(H, w2f8, ab2, val16, aggT, s_off);
  }
  final_kernel<<<128,256,0,stream>>>(aggT,endwT,endb,valueT,out);
}